// Round 1
// 635.218 us; speedup vs baseline: 1.1375x; 1.1375x over previous
//
#include <hip/hip_runtime.h>
#include <math.h>

#define B_ 16
#define C_ 512
#define Nn 3136
#define HEADS 8
#define HD 64
#define AG 49
#define Mrows (B_ * Nn)   // 50176

typedef unsigned short ushortT;
typedef __attribute__((ext_vector_type(8))) short bf16x8;
typedef __attribute__((ext_vector_type(4))) float f32x4;

#define MFMA16(a, b, c) __builtin_amdgcn_mfma_f32_16x16x32_bf16((a), (b), (c), 0, 0, 0)

__device__ inline float bf2f(ushortT u) { return __uint_as_float(((unsigned)u) << 16); }
__device__ inline ushortT f2bf(float f) {
    unsigned x = __float_as_uint(f);
    unsigned r = (x + 0x7fffu + ((x >> 16) & 1u)) >> 16;   // RNE
    return (ushortT)r;
}
__device__ inline f32x4 fzero4() { f32x4 z = {0.f, 0.f, 0.f, 0.f}; return z; }

// async global->LDS, 16B per lane; lds dest = wave-uniform base + lane*16
__device__ inline void gl_lds16(const ushortT* g, ushortT* l) {
    __builtin_amdgcn_global_load_lds(
        (const __attribute__((address_space(1))) void*)g,
        (__attribute__((address_space(3))) void*)l, 16, 0, 0);
}

// ============ fp32 -> bf16 elementwise (x, weights) ============
__global__ void cvt_f2b4(const float* __restrict__ src, ushortT* __restrict__ dst, int n4) {
    int g = blockIdx.x * 256 + threadIdx.x;
    if (g >= n4) return;
    float4 v = *(const float4*)&src[(size_t)g * 4];
    ushort4 o = make_ushort4(f2bf(v.x), f2bf(v.y), f2bf(v.z), f2bf(v.w));
    *(ushort4*)&dst[(size_t)g * 4] = o;
}

// dwc_w [c][3][3] -> wT [tap][c] fp32
__global__ void repack_w(const float* __restrict__ w, float* __restrict__ wT) {
    int g = blockIdx.x * 256 + threadIdx.x;
    if (g >= 9 * 512) return;
    int c = g % 512, tap = g / 512;
    wT[g] = w[c * 9 + tap];
}

// ============ MFMA GEMM: out[m,n] = sum_k A[m,k]*Bw[n,k] (+bias) ============
// 256x256 tile, BK=64, 8 waves (2Mx4N), double-buffered LDS (128 KiB),
// 2-phase prefetch (issue kt+1 stage before computing kt, one vmcnt(0)+barrier
// per K-tile via __syncthreads), XOR-swizzled row-major LDS so the staging
// reads are row-coalesced while ds_read_b128 frags stay bank-conflict-free.
// LDS[row][kg] = G[row][kg ^ (row&7)]  (16B-granule units, 8 granules/row).
template <typename TO>
__global__ __launch_bounds__(512, 2)
void gemm256(const ushortT* __restrict__ A, const ushortT* __restrict__ Bw,
             const float* __restrict__ bias, TO* __restrict__ out,
             int N, int K, int nbn) {
    __shared__ __align__(16) ushortT As[2][16384];   // [buf][256 rows][64 k] bf16
    __shared__ __align__(16) ushortT Bs[2][16384];
    const int t = threadIdx.x, lane = t & 63, wid = t >> 6;
    // XCD-chunked block swizzle (gridDim.x % 8 == 0 for both call sites)
    const int chunk = (int)gridDim.x >> 3;
    const int id2 = ((int)blockIdx.x & 7) * chunk + ((int)blockIdx.x >> 3);
    const int by = id2 / nbn, bx = id2 - by * nbn;
    const int m0 = by * 256, n0 = bx * 256;
    const int wm = wid >> 2, wn = wid & 3;

    // staging: call s covers rows s*64..s*64+63; thread t stages granule
    // (row = s*64 + (t>>3), kg = t&7); source chunk = kg ^ (row&7)
    const int srow = t >> 3;
    const int skg = (t & 7) ^ (srow & 7);
    const ushortT* gA[4];
    const ushortT* gB[4];
#pragma unroll
    for (int s = 0; s < 4; ++s) {
        gA[s] = A  + (size_t)(m0 + s * 64 + srow) * K + skg * 8;
        gB[s] = Bw + (size_t)(n0 + s * 64 + srow) * K + skg * 8;
    }
    const int ldsoff = wid * 512;   // ushorts within a 4096-ushort stage region

    f32x4 acc[8][4];
#pragma unroll
    for (int i = 0; i < 8; ++i)
#pragma unroll
        for (int j = 0; j < 4; ++j) acc[i][j] = fzero4();

    // frag-read addressing: row = base + {mt,nt}*16 + r15; (row&7) == (r15&7)
    const int r15 = lane & 15, kq16 = lane >> 4;
    const int rA = wm * 128 + r15;
    const int rB = wn * 64 + r15;
    const int sw0 = ((kq16) ^ (r15 & 7)) << 3;        // ks=0 chunk offset (ushorts)
    const int sw1 = ((4 + kq16) ^ (r15 & 7)) << 3;    // ks=1

    const int NT = K >> 6;
    int cur = 0;
    // prologue: stage kt=0 into buf0
#pragma unroll
    for (int s = 0; s < 4; ++s) {
        gl_lds16(gA[s], &As[0][s * 4096 + ldsoff]);
        gl_lds16(gB[s], &Bs[0][s * 4096 + ldsoff]);
    }
    __syncthreads();   // compiler drains vmcnt(0) before s_barrier

    for (int kt = 0; kt < NT; ++kt) {
        const ushortT* Ac = As[cur];
        const ushortT* Bc = Bs[cur];
        if (kt + 1 < NT) {
            const int nxt = cur ^ 1;
            const int ko = (kt + 1) * 64;
#pragma unroll
            for (int s = 0; s < 4; ++s) {
                gl_lds16(gA[s] + ko, &As[nxt][s * 4096 + ldsoff]);
                gl_lds16(gB[s] + ko, &Bs[nxt][s * 4096 + ldsoff]);
            }
        }
#pragma unroll
        for (int ks = 0; ks < 2; ++ks) {
            const int sw = ks ? sw1 : sw0;
            bf16x8 af[8], bfr[4];
#pragma unroll
            for (int mt = 0; mt < 8; ++mt)
                af[mt] = *(const bf16x8*)&Ac[(rA + mt * 16) * 64 + sw];
#pragma unroll
            for (int nt = 0; nt < 4; ++nt)
                bfr[nt] = *(const bf16x8*)&Bc[(rB + nt * 16) * 64 + sw];
#pragma unroll
            for (int mt = 0; mt < 8; ++mt)
#pragma unroll
                for (int nt = 0; nt < 4; ++nt)
                    acc[mt][nt] = MFMA16(af[mt], bfr[nt], acc[mt][nt]);
        }
        __syncthreads();   // drains vmcnt(0): kt+1 tile landed; lgkm drained
        cur ^= 1;
    }

    // epilogue: C/D layout col=lane&15, row=(lane>>4)*4+r
    const int cn = r15, rg = kq16 << 2;
#pragma unroll
    for (int mt = 0; mt < 8; ++mt) {
        int mrow = m0 + wm * 128 + mt * 16 + rg;
#pragma unroll
        for (int nt = 0; nt < 4; ++nt) {
            int ncol = n0 + wn * 64 + nt * 16 + cn;
            float bv = bias ? bias[ncol] : 0.f;
#pragma unroll
            for (int r = 0; r < 4; ++r) {
                float v = acc[mt][nt][r] + bv;
                if (sizeof(TO) == 2) ((ushortT*)out)[(size_t)(mrow + r) * N + ncol] = f2bf(v);
                else                 ((float*)out)[(size_t)(mrow + r) * N + ncol] = v;
            }
        }
    }
}

// ============ agent tokens: 8x8 mean pool of q (bf16 in, fp32 out), 8ch/thread ==========
__global__ void agent_pool(const ushortT* __restrict__ qkv, float* __restrict__ at) {
    int g = blockIdx.x * 256 + threadIdx.x;       // 16*49*64
    int c8 = (g & 63) << 3;
    int a = (g >> 6) % AG;
    int b = g / (AG * 64);
    int p1 = a / 7, p2 = a % 7;
    float s[8] = {};
    for (int yy = 0; yy < 8; ++yy)
#pragma unroll
        for (int xx = 0; xx < 8; ++xx) {
            int i = (p1 * 8 + yy) * 56 + (p2 * 8 + xx);
            const ushortT* p = &qkv[(size_t)(b * Nn + i) * 1536 + c8];
            ushort4 u0 = *(const ushort4*)p;
            ushort4 u1 = *(const ushort4*)(p + 4);
            s[0] += bf2f(u0.x); s[1] += bf2f(u0.y); s[2] += bf2f(u0.z); s[3] += bf2f(u0.w);
            s[4] += bf2f(u1.x); s[5] += bf2f(u1.y); s[6] += bf2f(u1.z); s[7] += bf2f(u1.w);
        }
    float* o = &at[((size_t)(b * AG + a) << 9) + c8];
#pragma unroll
    for (int j = 0; j < 8; ++j) o[j] = s[j] * (1.f / 64.f);
}

// ============ bilinear 7->56 biases ============
__device__ inline float bilin7(const float* __restrict__ p, int y, int x) {
    float fy = fminf(fmaxf(y * 0.125f - 0.4375f, 0.f), 6.f);
    float fx = fminf(fmaxf(x * 0.125f - 0.4375f, 0.f), 6.f);
    int y0 = (int)fy; float ty = fy - y0; int y1 = min(y0 + 1, 6);
    int x0 = (int)fx; float tx = fx - x0; int x1 = min(x0 + 1, 6);
    float v00 = p[y0 * 7 + x0], v01 = p[y0 * 7 + x1];
    float v10 = p[y1 * 7 + x0], v11 = p[y1 * 7 + x1];
    return (1.f - ty) * ((1.f - tx) * v00 + tx * v01) + ty * ((1.f - tx) * v10 + tx * v11);
}

__global__ void bias1_k(const float* __restrict__ an, const float* __restrict__ ahb,
                        const float* __restrict__ awb, float* __restrict__ out) {
    int g = blockIdx.x * 256 + threadIdx.x;       // [h][a][i]
    if (g >= HEADS * AG * Nn) return;
    int i = g % Nn; int a = (g / Nn) % AG; int h = g / (AG * Nn);
    int y = i / 56, x = i % 56;
    float v = bilin7(an + (h * AG + a) * 49, y, x);
    out[g] = v + ahb[(h * AG + a) * 56 + y] + awb[(h * AG + a) * 56 + x];
}

__global__ void bias2_k(const float* __restrict__ na, const float* __restrict__ hab,
                        const float* __restrict__ wab, float* __restrict__ out) {
    int g = blockIdx.x * 256 + threadIdx.x;       // [h][i][a]
    if (g >= HEADS * Nn * AG) return;
    int a = g % AG; int i = (g / AG) % Nn; int h = g / (AG * Nn);
    int y = i / 56, x = i % 56;
    float v = bilin7(na + (h * AG + a) * 49, y, x);
    out[g] = v + hab[(h * 56 + y) * AG + a] + wab[(h * 56 + x) * AG + a];
}

// ============ agent logits via MFMA: L[a][i] = (0.125*ah[a])·k[i] + b1 ============
__global__ __launch_bounds__(256)
void agent_logits_mfma(const ushortT* __restrict__ qkv, const float* __restrict__ at,
                       const float* __restrict__ b1, ushortT* __restrict__ L) {
    __shared__ __align__(16) ushortT ah_s[64 * 72];
    int t = threadIdx.x, lane = t & 63, wid = t >> 6;
    int bh = blockIdx.y, b = bh >> 3, h = bh & 7;
    for (int idx = t; idx < 512; idx += 256) {
        int a = idx >> 3, d8 = (idx & 7) << 3;
        bf16x8 tmp;
        if (a < AG) {
            const float* p = &at[((size_t)(b * AG + a) << 9) + (h << 6) + d8];
#pragma unroll
            for (int j = 0; j < 8; ++j) tmp[j] = (short)f2bf(p[j] * 0.125f);
        } else {
#pragma unroll
            for (int j = 0; j < 8; ++j) tmp[j] = 0;
        }
        *(bf16x8*)&ah_s[a * 72 + d8] = tmp;
    }
    __syncthreads();
    int r15 = lane & 15, kq = (lane >> 4) << 3;
    bf16x8 af[4][2];
#pragma unroll
    for (int mt = 0; mt < 4; ++mt)
#pragma unroll
        for (int ks = 0; ks < 2; ++ks)
            af[mt][ks] = *(const bf16x8*)&ah_s[(mt * 16 + r15) * 72 + ks * 32 + kq];
    int i0b = blockIdx.x * 448;
    int rbase = (lane >> 4) << 2;
    for (int tt = 0; tt < 7; ++tt) {
        int i0 = i0b + (wid * 7 + tt) * 16;
        const ushortT* kp = &qkv[(size_t)(b * Nn + i0 + r15) * 1536 + 512 + (h << 6) + kq];
        bf16x8 bk0 = *(const bf16x8*)kp;
        bf16x8 bk1 = *(const bf16x8*)(kp + 32);
        f32x4 acc[4];
#pragma unroll
        for (int mt = 0; mt < 4; ++mt) {
            acc[mt] = MFMA16(af[mt][0], bk0, fzero4());
            acc[mt] = MFMA16(af[mt][1], bk1, acc[mt]);
        }
        int ic = i0 + r15;
#pragma unroll
        for (int mt = 0; mt < 4; ++mt)
#pragma unroll
            for (int r = 0; r < 4; ++r) {
                int a = mt * 16 + rbase + r;
                if (a < AG) {
                    float v = acc[mt][r] + b1[(size_t)(h * AG + a) * Nn + ic];
                    L[(size_t)(bh * AG + a) * Nn + ic] = f2bf(v);
                }
            }
    }
}

// ============ softmax over bf16 rows of length Nn ============
__global__ __launch_bounds__(256)
void softmax_rows_bf(ushortT* __restrict__ L) {
    __shared__ float ex[Nn];
    __shared__ float red[256];
    ushortT* p = L + (size_t)blockIdx.x * Nn;
    int t = threadIdx.x;
    float m = -1e30f;
    for (int i = t; i < Nn; i += 256) { float v = bf2f(p[i]); ex[i] = v; m = fmaxf(m, v); }
    red[t] = m; __syncthreads();
    for (int s = 128; s; s >>= 1) { if (t < s) red[t] = fmaxf(red[t], red[t + s]); __syncthreads(); }
    m = red[0]; __syncthreads();
    float sum = 0.f;
    for (int i = t; i < Nn; i += 256) { float e = __expf(ex[i] - m); ex[i] = e; sum += e; }
    red[t] = sum; __syncthreads();
    for (int s = 128; s; s >>= 1) { if (t < s) red[t] += red[t + s]; __syncthreads(); }
    float inv = 1.f / red[0];
    for (int i = t; i < Nn; i += 256) p[i] = f2bf(ex[i] * inv);
}

__global__ void zerof(float* __restrict__ p, int nfl) {
    int g = blockIdx.x * 256 + threadIdx.x;
    if (g < nfl) p[g] = 0.f;
}

// ============ agent_v via MFMA: av[a][d] += P[a][i]·v[i][d] ============
__global__ __launch_bounds__(256)
void agent_v_mfma(const ushortT* __restrict__ qkv, const ushortT* __restrict__ L,
                  float* __restrict__ av) {
    __shared__ __align__(16) ushortT vt[4][64 * 72];   // per-wave vT[d][i]
    int t = threadIdx.x, lane = t & 63, wid = t >> 6;
    int bh = blockIdx.y, b = bh >> 3, h = bh & 7;
    int sub = blockIdx.x * 4 + wid;
    if (sub >= AG) return;                 // 49 chunks of 64 i
    int i0 = sub * 64;
    ushortT* vtw = vt[wid];
    {
        const ushortT* vp = &qkv[(size_t)(b * Nn + i0 + lane) * 1536 + 1024 + (h << 6)];
#pragma unroll
        for (int d8 = 0; d8 < 64; d8 += 8) {
            ushort4 u0 = *(const ushort4*)(vp + d8);
            ushort4 u1 = *(const ushort4*)(vp + d8 + 4);
            vtw[(d8 + 0) * 72 + lane] = u0.x; vtw[(d8 + 1) * 72 + lane] = u0.y;
            vtw[(d8 + 2) * 72 + lane] = u0.z; vtw[(d8 + 3) * 72 + lane] = u0.w;
            vtw[(d8 + 4) * 72 + lane] = u1.x; vtw[(d8 + 5) * 72 + lane] = u1.y;
            vtw[(d8 + 6) * 72 + lane] = u1.z; vtw[(d8 + 7) * 72 + lane] = u1.w;
        }
    }
    int r15 = lane & 15, kq = (lane >> 4) << 3;
    f32x4 acc[4][4];
#pragma unroll
    for (int i = 0; i < 4; ++i)
#pragma unroll
        for (int j = 0; j < 4; ++j) acc[i][j] = fzero4();
#pragma unroll
    for (int ks = 0; ks < 2; ++ks) {
        bf16x8 afr[4], bfr[4];
#pragma unroll
        for (int mt = 0; mt < 4; ++mt) {
            int a = min(mt * 16 + r15, AG - 1);
            afr[mt] = *(const bf16x8*)&L[(size_t)(bh * AG + a) * Nn + i0 + ks * 32 + kq];
        }
#pragma unroll
        for (int nt = 0; nt < 4; ++nt)
            bfr[nt] = *(const bf16x8*)&vtw[(nt * 16 + r15) * 72 + ks * 32 + kq];
#pragma unroll
        for (int mt = 0; mt < 4; ++mt)
#pragma unroll
            for (int nt = 0; nt < 4; ++nt)
                acc[mt][nt] = MFMA16(afr[mt], bfr[nt], acc[mt][nt]);
    }
    int rbase = (lane >> 4) << 2;
#pragma unroll
    for (int mt = 0; mt < 4; ++mt)
#pragma unroll
        for (int r = 0; r < 4; ++r) {
            int a = mt * 16 + rbase + r;
            if (a < AG) {
#pragma unroll
                for (int nt = 0; nt < 4; ++nt)
                    atomicAdd(&av[((size_t)(bh * AG + a) << 6) + nt * 16 + r15],
                              acc[mt][nt][r]);
            }
        }
}

// ============ fused q-attention via MFMA: QK^T -> reg softmax -> P·av ============
__global__ __launch_bounds__(256)
void q_attn_mfma(const ushortT* __restrict__ qkv, const float* __restrict__ at,
                 const float* __restrict__ av, const float* __restrict__ b2,
                 ushortT* __restrict__ attn) {
    __shared__ __align__(16) ushortT ah_s[64 * 72];
    __shared__ __align__(16) ushortT avT[64 * 72];
    __shared__ __align__(16) ushortT p_s[4][16 * 72];
    int t = threadIdx.x, lane = t & 63, wid = t >> 6;
    int bh = blockIdx.y, b = bh >> 3, h = bh & 7;
    for (int idx = t; idx < 512; idx += 256) {
        int a = idx >> 3, d8 = (idx & 7) << 3;
        bf16x8 tmp;
        if (a < AG) {
            const float* p = &at[((size_t)(b * AG + a) << 9) + (h << 6) + d8];
#pragma unroll
            for (int j = 0; j < 8; ++j) tmp[j] = (short)f2bf(p[j] * 0.125f);
        } else {
#pragma unroll
            for (int j = 0; j < 8; ++j) tmp[j] = 0;
        }
        *(bf16x8*)&ah_s[a * 72 + d8] = tmp;
    }
    for (int idx = t; idx < 4096; idx += 256) {     // avT[d][a] <- av[a][d]
        int a = idx >> 6, d = idx & 63;
        float v = (a < AG) ? av[((size_t)(bh * AG + a) << 6) + d] : 0.f;
        avT[d * 72 + a] = f2bf(v);
    }
    __syncthreads();
    int r15 = lane & 15, kq = (lane >> 4) << 3;
    bf16x8 bah[4][2], bav[4][2];
#pragma unroll
    for (int nt = 0; nt < 4; ++nt)
#pragma unroll
        for (int ks = 0; ks < 2; ++ks) {
            bah[nt][ks] = *(const bf16x8*)&ah_s[(nt * 16 + r15) * 72 + ks * 32 + kq];
            bav[nt][ks] = *(const bf16x8*)&avT[(nt * 16 + r15) * 72 + ks * 32 + kq];
        }
    ushortT* psw = p_s[wid];
    int i0b = blockIdx.x * 448;
    int rbase = (lane >> 4) << 2;
    for (int tt = 0; tt < 7; ++tt) {
        int i0 = i0b + (wid * 7 + tt) * 16;
        const ushortT* qp = &qkv[(size_t)(b * Nn + i0 + r15) * 1536 + (h << 6) + kq];
        bf16x8 aq0 = *(const bf16x8*)qp;
        bf16x8 aq1 = *(const bf16x8*)(qp + 32);
        f32x4 lg[4];
#pragma unroll
        for (int nt = 0; nt < 4; ++nt) {
            lg[nt] = MFMA16(aq0, bah[nt][0], fzero4());
            lg[nt] = MFMA16(aq1, bah[nt][1], lg[nt]);
        }
        float p4[4][4];   // [nt][r]
#pragma unroll
        for (int r = 0; r < 4; ++r) {
            int i = i0 + rbase + r;
            float vals[4]; float mx = -1e30f;
#pragma unroll
            for (int nt = 0; nt < 4; ++nt) {
                int a = nt * 16 + r15;
                float v = -1e30f;
                if (a < AG) v = lg[nt][r] + b2[(size_t)(h * Nn + i) * AG + a];
                vals[nt] = v;
                mx = fmaxf(mx, v);
            }
#pragma unroll
            for (int off = 8; off >= 1; off >>= 1) mx = fmaxf(mx, __shfl_xor(mx, off));
            float sm = 0.f;
#pragma unroll
            for (int nt = 0; nt < 4; ++nt) {
                float e = (vals[nt] > -1e29f) ? __expf(vals[nt] - mx) : 0.f;
                vals[nt] = e; sm += e;
            }
#pragma unroll
            for (int off = 8; off >= 1; off >>= 1) sm += __shfl_xor(sm, off);
            float inv = 1.f / sm;
#pragma unroll
            for (int nt = 0; nt < 4; ++nt) p4[nt][r] = vals[nt] * inv;
        }
#pragma unroll
        for (int nt = 0; nt < 4; ++nt)
#pragma unroll
            for (int r = 0; r < 4; ++r)
                psw[(rbase + r) * 72 + nt * 16 + r15] = f2bf(p4[nt][r]);
        bf16x8 ap0 = *(const bf16x8*)&psw[r15 * 72 + kq];
        bf16x8 ap1 = *(const bf16x8*)&psw[r15 * 72 + 32 + kq];
        f32x4 ov[4];
#pragma unroll
        for (int nt = 0; nt < 4; ++nt) {
            ov[nt] = MFMA16(ap0, bav[nt][0], fzero4());
            ov[nt] = MFMA16(ap1, bav[nt][1], ov[nt]);
        }
#pragma unroll
        for (int r = 0; r < 4; ++r) {
            int i = i0 + rbase + r;
            ushortT* op = &attn[(size_t)(b * Nn + i) * C_ + (h << 6)];
#pragma unroll
            for (int nt = 0; nt < 4; ++nt)
                op[nt * 16 + r15] = f2bf(ov[nt][r]);
        }
    }
}

// ============ depthwise 3x3 conv on v, added into attn; 8 channels/thread ============
__global__ void dwc_add_v(const ushortT* __restrict__ qkv, const float* __restrict__ wT,
                          const float* __restrict__ bb, ushortT* __restrict__ attn) {
    int g = blockIdx.x * 256 + threadIdx.x;   // B*Nn*64
    int c8 = (g & 63) << 3;
    int bi = g >> 6;
    int i = bi % Nn;
    int y = i / 56, x = i % 56;
    float acc[8];
    {
        float4 b0 = *(const float4*)&bb[c8];
        float4 b1 = *(const float4*)&bb[c8 + 4];
        acc[0] = b0.x; acc[1] = b0.y; acc[2] = b0.z; acc[3] = b0.w;
        acc[4] = b1.x; acc[5] = b1.y; acc[6] = b1.z; acc[7] = b1.w;
    }
#pragma unroll
    for (int dy = -1; dy <= 1; ++dy) {
        int yy = y + dy; if (yy < 0 || yy > 55) continue;
#pragma unroll
        for (int dx = -1; dx <= 1; ++dx) {
            int xx = x + dx; if (xx < 0 || xx > 55) continue;
            const ushortT* vp = &qkv[(size_t)(bi + dy * 56 + dx) * 1536 + 1024 + c8];
            ushort4 u0 = *(const ushort4*)vp;
            ushort4 u1 = *(const ushort4*)(vp + 4);
            const float* wp = &wT[((dy + 1) * 3 + dx + 1) * 512 + c8];
            float4 w0 = *(const float4*)wp;
            float4 w1 = *(const float4*)(wp + 4);
            acc[0] += bf2f(u0.x) * w0.x; acc[1] += bf2f(u0.y) * w0.y;
            acc[2] += bf2f(u0.z) * w0.z; acc[3] += bf2f(u0.w) * w0.w;
            acc[4] += bf2f(u1.x) * w1.x; acc[5] += bf2f(u1.y) * w1.y;
            acc[6] += bf2f(u1.z) * w1.z; acc[7] += bf2f(u1.w) * w1.w;
        }
    }
    ushortT* op = &attn[(size_t)bi * C_ + c8];
    ushort4 a0 = *(const ushort4*)op;
    ushort4 a1 = *(const ushort4*)(op + 4);
    ushort4 o0 = make_ushort4(f2bf(bf2f(a0.x) + acc[0]), f2bf(bf2f(a0.y) + acc[1]),
                              f2bf(bf2f(a0.z) + acc[2]), f2bf(bf2f(a0.w) + acc[3]));
    ushort4 o1 = make_ushort4(f2bf(bf2f(a1.x) + acc[4]), f2bf(bf2f(a1.y) + acc[5]),
                              f2bf(bf2f(a1.z) + acc[6]), f2bf(bf2f(a1.w) + acc[7]));
    *(ushort4*)op = o0; *(ushort4*)(op + 4) = o1;
}

extern "C" void kernel_launch(void* const* d_in, const int* in_sizes, int n_in,
                              void* d_out, int out_size, void* d_ws, size_t ws_size,
                              hipStream_t stream) {
    const float* x      = (const float*)d_in[0];
    const float* q_w    = (const float*)d_in[3];
    const float* kv_w   = (const float*)d_in[4];
    const float* proj_w = (const float*)d_in[5];
    const float* proj_b = (const float*)d_in[6];
    const float* dwc_w  = (const float*)d_in[7];
    const float* dwc_b  = (const float*)d_in[8];
    const float* an_b   = (const float*)d_in[9];
    const float* na_b   = (const float*)d_in[10];
    const float* ah_b   = (const float*)d_in[11];
    const float* aw_b   = (const float*)d_in[12];
    const float* ha_b   = (const float*)d_in[13];
    const float* wa_b   = (const float*)d_in[14];
    float* out = (float*)d_out;

    // ---- workspace (220,682,240 B ≈ 210.5 MiB); R region reused: xb -> L -> attn ----
    char* ws = (char*)d_ws;
    ushortT* R    = (ushortT*)(ws);                 // 51,380,224 B
    ushortT* qkv  = (ushortT*)(ws + 51380224);      // 154,140,672 B
    ushortT* Wqkv = (ushortT*)(ws + 205520896);     // 1,572,864 B
    ushortT* Wp   = (ushortT*)(ws + 207093760);     // 524,288 B
    float*   wT   = (float*)(ws + 207618048);       // 18,432 B
    float*   at   = (float*)(ws + 207636480);       // 1,605,632 B
    float*   b1   = (float*)(ws + 209242112);       // 4,917,248 B
    float*   b2   = (float*)(ws + 214159360);       // 4,917,248 B
    float*   av   = (float*)(ws + 219076608);       // 1,605,632 B
    ushortT* xb   = R;            // 50176x512 bf16 (dead after QKV GEMM)
    ushortT* L    = R;            // 6272x3136  bf16 (dead before attn written)
    ushortT* attn = R;            // 50176x512 bf16

    // 0) dtype conversions / repacks
    cvt_f2b4<<<25088, 256, 0, stream>>>(x, xb, 6422528);
    cvt_f2b4<<<256,   256, 0, stream>>>(q_w, Wqkv, 65536);
    cvt_f2b4<<<512,   256, 0, stream>>>(kv_w, Wqkv + 262144, 131072);
    cvt_f2b4<<<256,   256, 0, stream>>>(proj_w, Wp, 65536);
    repack_w<<<18,    256, 0, stream>>>(dwc_w, wT);
    // 1) fused QKV GEMM (bf16 MFMA, 256x256 2-phase)  M=50176 N=1536 K=512
    gemm256<ushortT><<<1176, 512, 0, stream>>>(xb, Wqkv, nullptr, qkv, 1536, 512, 6);
    // 2) agent tokens
    agent_pool<<<196, 256, 0, stream>>>(qkv, at);
    // 3) position biases
    bias1_k<<<4802, 256, 0, stream>>>(an_b, ah_b, aw_b, b1);
    bias2_k<<<4802, 256, 0, stream>>>(na_b, ha_b, wa_b, b2);
    // 4) agent attention
    agent_logits_mfma<<<dim3(7, 128), 256, 0, stream>>>(qkv, at, b1, L);
    softmax_rows_bf<<<6272, 256, 0, stream>>>(L);
    zerof<<<1568, 256, 0, stream>>>(av, B_ * HEADS * AG * HD);
    agent_v_mfma<<<dim3(13, 128), 256, 0, stream>>>(qkv, L, av);
    // 5) q attention (fused MFMA)
    q_attn_mfma<<<dim3(7, 128), 256, 0, stream>>>(qkv, at, av, b2, attn);
    // 6) depthwise conv add
    dwc_add_v<<<12544, 256, 0, stream>>>(qkv, wT, dwc_b, attn);
    // 7) output projection (bf16 MFMA, fp32 out + bias)  M=50176 N=512 K=512
    gemm256<float><<<392, 512, 0, stream>>>(attn, Wp, proj_b, out, 512, 512, 2);
}

// Round 2
// 621.701 us; speedup vs baseline: 1.1622x; 1.0217x over previous
//
#include <hip/hip_runtime.h>
#include <math.h>

#define B_ 16
#define C_ 512
#define Nn 3136
#define HEADS 8
#define HD 64
#define AG 49
#define Mrows (B_ * Nn)   // 50176

typedef unsigned short ushortT;
typedef __attribute__((ext_vector_type(8))) short bf16x8;
typedef __attribute__((ext_vector_type(4))) float f32x4;

#define MFMA16(a, b, c) __builtin_amdgcn_mfma_f32_16x16x32_bf16((a), (b), (c), 0, 0, 0)

__device__ inline float bf2f(ushortT u) { return __uint_as_float(((unsigned)u) << 16); }
__device__ inline ushortT f2bf(float f) {
    unsigned x = __float_as_uint(f);
    unsigned r = (x + 0x7fffu + ((x >> 16) & 1u)) >> 16;   // RNE
    return (ushortT)r;
}
__device__ inline f32x4 fzero4() { f32x4 z = {0.f, 0.f, 0.f, 0.f}; return z; }

// async global->LDS, 16B per lane; lds dest = wave-uniform base + lane*16
__device__ inline void gl_lds16(const ushortT* g, ushortT* l) {
    __builtin_amdgcn_global_load_lds(
        (const __attribute__((address_space(1))) void*)g,
        (__attribute__((address_space(3))) void*)l, 16, 0, 0);
}

#define VMCNT(n) asm volatile("s_waitcnt vmcnt(" #n ")" ::: "memory")
#define LGKM0_SB() { asm volatile("s_waitcnt lgkmcnt(0)" ::: "memory"); \
                     __builtin_amdgcn_sched_barrier(0); }
#define BAR() __builtin_amdgcn_s_barrier()

// ============ fp32 -> bf16 elementwise (x, weights) ============
__global__ void cvt_f2b4(const float* __restrict__ src, ushortT* __restrict__ dst, int n4) {
    int g = blockIdx.x * 256 + threadIdx.x;
    if (g >= n4) return;
    float4 v = *(const float4*)&src[(size_t)g * 4];
    ushort4 o = make_ushort4(f2bf(v.x), f2bf(v.y), f2bf(v.z), f2bf(v.w));
    *(ushort4*)&dst[(size_t)g * 4] = o;
}

// dwc_w [c][3][3] -> wT [tap][c] fp32
__global__ void repack_w(const float* __restrict__ w, float* __restrict__ wT) {
    int g = blockIdx.x * 256 + threadIdx.x;
    if (g >= 9 * 512) return;
    int c = g % 512, tap = g / 512;
    wT[g] = w[c * 9 + tap];
}

// one C-quadrant of the per-wave 128x64 tile: 4 m-frags x 2 n-frags x 2 k-slices
template <int MB, int NL>
__device__ __forceinline__ void quad(f32x4 (&acc)[8][4], const bf16x8 (&af)[4][2],
                                     const bf16x8 (&bf)[4][2]) {
#pragma unroll
    for (int m = 0; m < 4; ++m)
#pragma unroll
        for (int n = 0; n < 2; ++n) {
            acc[MB + m][NL + n] = MFMA16(af[m][0], bf[NL + n][0], acc[MB + m][NL + n]);
            acc[MB + m][NL + n] = MFMA16(af[m][1], bf[NL + n][1], acc[MB + m][NL + n]);
        }
}

// ============ MFMA GEMM: out[m,n] = sum_k A[m,k]*Bw[n,k] (+bias), K=512 fixed ======
// 256x256 tile, BK=64, 8 waves (2Mx4N), dbuf LDS (128 KiB), 8-phase schedule:
// per K-tile 4 phases = 4 C-quadrants x 16 MFMA; one half-tile staged per phase;
// counted s_waitcnt vmcnt(4) (never 0 in steady state); raw barriers; setprio.
// Half-tiles are row-INTERLEAVED so each half's first-read deadline staggers:
//   A_s0 = rows {0..63,128..191}, A_s1 = +64;  B_s0 = rows {q*64+0..31}, B_s1 = +32.
// Deadlines: p0 needs A_s0,B_s0; p1 needs B_s1; p2 needs A_s1; p3 none.
// Issue (tile t -> t+1): p0:A_s0  p1:B_s0  p2:B_s1  p3:A_s1.
// Waits: end-p0 vmcnt(4) [covers B_s1(t)], end-p1 vmcnt(4) [A_s1(t)],
//        end-p3 vmcnt(4) [A_s0,B_s0(t+1)]; last tile: vmcnt(2)/vmcnt(0).
// In-flight DMAs never target rows being read in the same phase (disjoint sets).
// LDS layout (both A,B): linear [256][64] with source-swizzled granules:
//   LDS[row][g] = G[row][g ^ (row&7)] (16B granules) -> conflict-free ds_read_b128.
template <typename TO>
__global__ __launch_bounds__(512, 2)
void gemm256(const ushortT* __restrict__ A, const ushortT* __restrict__ Bw,
             const float* __restrict__ bias, TO* __restrict__ out,
             int N, int nbn) {
    __shared__ __align__(16) ushortT As[2][16384];   // [buf][256 rows][64 k] bf16
    __shared__ __align__(16) ushortT Bs[2][16384];
    const int t = threadIdx.x, lane = t & 63, wid = t >> 6;
    // XCD-chunked block swizzle (gridDim.x % 8 == 0 for both call sites)
    const int chunk = (int)gridDim.x >> 3;
    const int id2 = ((int)blockIdx.x & 7) * chunk + ((int)blockIdx.x >> 3);
    const int by = id2 / nbn, bx = id2 - by * nbn;
    const int m0 = by * 256, n0 = bx * 256;
    const int wm = wid >> 2, wn = wid & 3;

    // ---- staging addressing: thread t stages granule (row_local = j*64 + t>>3,
    // kg = t&7); source granule = kg ^ (row&7); row&7 == (t>>3)&7 for all halves.
    const int rl0 = t >> 3;
    const int skg = (t & 7) ^ (rl0 & 7);
    const int ra0 = rl0 & 63;                                // A j=0 row (s0)
    const int ra1 = (rl0 & 63) + 128;                        // A j=1 row (s0)
    const int rb0 = (rl0 & 31) + ((rl0 >> 5) << 6);          // B j=0 row (s0)
    const int rb1 = rb0 + 128;                               // B j=1 row (s0)
    const ushortT* gA0 = A + (size_t)(m0 + ra0) * 512 + skg * 8;
    const ushortT* gA1 = A + (size_t)(m0 + ra1) * 512 + skg * 8;
    const ushortT* gB0 = Bw + (size_t)(n0 + rb0) * 512 + skg * 8;
    const ushortT* gB1 = Bw + (size_t)(n0 + rb1) * 512 + skg * 8;
    // LDS dest bases (wave-uniform), ushort units
    const int bA0 = wid * 512;
    const int bA1 = wid * 512 + 8192;
    const int gbu = ((wid * 8) & 31) + (((wid * 8) >> 5) << 6);
    const int bB0 = gbu * 64;
    const int bB1 = bB0 + 8192;

#define ISSA(bufi, ro, ko) { gl_lds16(gA0 + (ro) * 512 + (ko), &As[bufi][bA0 + (ro) * 64]); \
                             gl_lds16(gA1 + (ro) * 512 + (ko), &As[bufi][bA1 + (ro) * 64]); }
#define ISSB(bufi, ro, ko) { gl_lds16(gB0 + (ro) * 512 + (ko), &Bs[bufi][bB0 + (ro) * 64]); \
                             gl_lds16(gB1 + (ro) * 512 + (ko), &Bs[bufi][bB1 + (ro) * 64]); }

    f32x4 acc[8][4];
#pragma unroll
    for (int i = 0; i < 8; ++i)
#pragma unroll
        for (int j = 0; j < 4; ++j) acc[i][j] = fzero4();

    // frag-read addressing: row = base + frag*16 + r15; (row&7) == (r15&7)
    const int r15 = lane & 15, kq16 = lane >> 4;
    const int rA = wm * 128 + r15;
    const int rB = wn * 64 + r15;
    const int sw0 = ((kq16) ^ (r15 & 7)) << 3;
    const int sw1 = ((4 + kq16) ^ (r15 & 7)) << 3;

    // ---- prologue: stage tile 0 in retirement order As0, Bs0, Bs1, As1
    ISSA(0, 0, 0);
    ISSB(0, 0, 0);
    ISSB(0, 32, 0);
    ISSA(0, 64, 0);
    VMCNT(4);          // A_s0(0), B_s0(0) resident
    BAR();

    bf16x8 af[4][2], bf[4][2];
    for (int kt = 0; kt < 8; ++kt) {
        const ushortT* Ac = As[kt & 1];
        const ushortT* Bc = Bs[kt & 1];
        const int nb = (kt + 1) & 1;
        const int ko = (kt + 1) * 64;
        const bool pre = (kt < 7);
        // ---------------- p0: quad (mh0, nh0) ----------------
#pragma unroll
        for (int mt = 0; mt < 4; ++mt) {
            af[mt][0] = *(const bf16x8*)&Ac[(rA + mt * 16) * 64 + sw0];
            af[mt][1] = *(const bf16x8*)&Ac[(rA + mt * 16) * 64 + sw1];
        }
#pragma unroll
        for (int nt = 0; nt < 2; ++nt) {
            bf[nt][0] = *(const bf16x8*)&Bc[(rB + nt * 16) * 64 + sw0];
            bf[nt][1] = *(const bf16x8*)&Bc[(rB + nt * 16) * 64 + sw1];
        }
        if (pre) ISSA(nb, 0, ko);          // A_s0(t+1)
        BAR(); LGKM0_SB();
        __builtin_amdgcn_s_setprio(1);
        quad<0, 0>(acc, af, bf);
        __builtin_amdgcn_s_setprio(0);
        if (pre) { VMCNT(4); } else { VMCNT(2); }   // B_s1(t) resident
        BAR();
        // ---------------- p1: quad (mh0, nh1) ----------------
#pragma unroll
        for (int nt = 2; nt < 4; ++nt) {
            bf[nt][0] = *(const bf16x8*)&Bc[(rB + nt * 16) * 64 + sw0];
            bf[nt][1] = *(const bf16x8*)&Bc[(rB + nt * 16) * 64 + sw1];
        }
        if (pre) ISSB(nb, 0, ko);          // B_s0(t+1)
        BAR(); LGKM0_SB();
        __builtin_amdgcn_s_setprio(1);
        quad<0, 2>(acc, af, bf);
        __builtin_amdgcn_s_setprio(0);
        if (pre) { VMCNT(4); } else { VMCNT(0); }   // A_s1(t) resident
        BAR();
        // ---------------- p2: quad (mh1, nh0) ----------------
#pragma unroll
        for (int mt = 0; mt < 4; ++mt) {
            af[mt][0] = *(const bf16x8*)&Ac[(rA + 64 + mt * 16) * 64 + sw0];
            af[mt][1] = *(const bf16x8*)&Ac[(rA + 64 + mt * 16) * 64 + sw1];
        }
        if (pre) ISSB(nb, 32, ko);         // B_s1(t+1)
        BAR(); LGKM0_SB();
        __builtin_amdgcn_s_setprio(1);
        quad<4, 0>(acc, af, bf);
        __builtin_amdgcn_s_setprio(0);
        BAR();
        // ---------------- p3: quad (mh1, nh1) ----------------
        if (pre) ISSA(nb, 64, ko);         // A_s1(t+1)
        BAR(); LGKM0_SB();
        __builtin_amdgcn_s_setprio(1);
        quad<4, 2>(acc, af, bf);
        __builtin_amdgcn_s_setprio(0);
        if (pre) { VMCNT(4); }             // A_s0(t+1), B_s0(t+1) resident
        BAR();
    }
#undef ISSA
#undef ISSB

    // epilogue: C/D layout col=lane&15, row=(lane>>4)*4+r
    const int cn = r15, rg = kq16 << 2;
#pragma unroll
    for (int mt = 0; mt < 8; ++mt) {
        int mrow = m0 + wm * 128 + mt * 16 + rg;
#pragma unroll
        for (int nt = 0; nt < 4; ++nt) {
            int ncol = n0 + wn * 64 + nt * 16 + cn;
            float bv = bias ? bias[ncol] : 0.f;
#pragma unroll
            for (int r = 0; r < 4; ++r) {
                float v = acc[mt][nt][r] + bv;
                if (sizeof(TO) == 2) ((ushortT*)out)[(size_t)(mrow + r) * N + ncol] = f2bf(v);
                else                 ((float*)out)[(size_t)(mrow + r) * N + ncol] = v;
            }
        }
    }
}

// ============ agent tokens: 8x8 mean pool of q (bf16 in, fp32 out), 8ch/thread ==========
__global__ void agent_pool(const ushortT* __restrict__ qkv, float* __restrict__ at) {
    int g = blockIdx.x * 256 + threadIdx.x;       // 16*49*64
    int c8 = (g & 63) << 3;
    int a = (g >> 6) % AG;
    int b = g / (AG * 64);
    int p1 = a / 7, p2 = a % 7;
    float s[8] = {};
    for (int yy = 0; yy < 8; ++yy)
#pragma unroll
        for (int xx = 0; xx < 8; ++xx) {
            int i = (p1 * 8 + yy) * 56 + (p2 * 8 + xx);
            const ushortT* p = &qkv[(size_t)(b * Nn + i) * 1536 + c8];
            ushort4 u0 = *(const ushort4*)p;
            ushort4 u1 = *(const ushort4*)(p + 4);
            s[0] += bf2f(u0.x); s[1] += bf2f(u0.y); s[2] += bf2f(u0.z); s[3] += bf2f(u0.w);
            s[4] += bf2f(u1.x); s[5] += bf2f(u1.y); s[6] += bf2f(u1.z); s[7] += bf2f(u1.w);
        }
    float* o = &at[((size_t)(b * AG + a) << 9) + c8];
#pragma unroll
    for (int j = 0; j < 8; ++j) o[j] = s[j] * (1.f / 64.f);
}

// ============ bilinear 7->56 biases ============
__device__ inline float bilin7(const float* __restrict__ p, int y, int x) {
    float fy = fminf(fmaxf(y * 0.125f - 0.4375f, 0.f), 6.f);
    float fx = fminf(fmaxf(x * 0.125f - 0.4375f, 0.f), 6.f);
    int y0 = (int)fy; float ty = fy - y0; int y1 = min(y0 + 1, 6);
    int x0 = (int)fx; float tx = fx - x0; int x1 = min(x0 + 1, 6);
    float v00 = p[y0 * 7 + x0], v01 = p[y0 * 7 + x1];
    float v10 = p[y1 * 7 + x0], v11 = p[y1 * 7 + x1];
    return (1.f - ty) * ((1.f - tx) * v00 + tx * v01) + ty * ((1.f - tx) * v10 + tx * v11);
}

__global__ void bias1_k(const float* __restrict__ an, const float* __restrict__ ahb,
                        const float* __restrict__ awb, float* __restrict__ out) {
    int g = blockIdx.x * 256 + threadIdx.x;       // [h][a][i]
    if (g >= HEADS * AG * Nn) return;
    int i = g % Nn; int a = (g / Nn) % AG; int h = g / (AG * Nn);
    int y = i / 56, x = i % 56;
    float v = bilin7(an + (h * AG + a) * 49, y, x);
    out[g] = v + ahb[(h * AG + a) * 56 + y] + awb[(h * AG + a) * 56 + x];
}

__global__ void bias2_k(const float* __restrict__ na, const float* __restrict__ hab,
                        const float* __restrict__ wab, float* __restrict__ out) {
    int g = blockIdx.x * 256 + threadIdx.x;       // [h][i][a]
    if (g >= HEADS * Nn * AG) return;
    int a = g % AG; int i = (g / AG) % Nn; int h = g / (AG * Nn);
    int y = i / 56, x = i % 56;
    float v = bilin7(na + (h * AG + a) * 49, y, x);
    out[g] = v + hab[(h * 56 + y) * AG + a] + wab[(h * 56 + x) * AG + a];
}

// ============ agent logits via MFMA: L[a][i] = (0.125*ah[a])·k[i] + b1 ============
__global__ __launch_bounds__(256)
void agent_logits_mfma(const ushortT* __restrict__ qkv, const float* __restrict__ at,
                       const float* __restrict__ b1, ushortT* __restrict__ L) {
    __shared__ __align__(16) ushortT ah_s[64 * 72];
    int t = threadIdx.x, lane = t & 63, wid = t >> 6;
    int bh = blockIdx.y, b = bh >> 3, h = bh & 7;
    for (int idx = t; idx < 512; idx += 256) {
        int a = idx >> 3, d8 = (idx & 7) << 3;
        bf16x8 tmp;
        if (a < AG) {
            const float* p = &at[((size_t)(b * AG + a) << 9) + (h << 6) + d8];
#pragma unroll
            for (int j = 0; j < 8; ++j) tmp[j] = (short)f2bf(p[j] * 0.125f);
        } else {
#pragma unroll
            for (int j = 0; j < 8; ++j) tmp[j] = 0;
        }
        *(bf16x8*)&ah_s[a * 72 + d8] = tmp;
    }
    __syncthreads();
    int r15 = lane & 15, kq = (lane >> 4) << 3;
    bf16x8 af[4][2];
#pragma unroll
    for (int mt = 0; mt < 4; ++mt)
#pragma unroll
        for (int ks = 0; ks < 2; ++ks)
            af[mt][ks] = *(const bf16x8*)&ah_s[(mt * 16 + r15) * 72 + ks * 32 + kq];
    int i0b = blockIdx.x * 448;
    int rbase = (lane >> 4) << 2;
    for (int tt = 0; tt < 7; ++tt) {
        int i0 = i0b + (wid * 7 + tt) * 16;
        const ushortT* kp = &qkv[(size_t)(b * Nn + i0 + r15) * 1536 + 512 + (h << 6) + kq];
        bf16x8 bk0 = *(const bf16x8*)kp;
        bf16x8 bk1 = *(const bf16x8*)(kp + 32);
        f32x4 acc[4];
#pragma unroll
        for (int mt = 0; mt < 4; ++mt) {
            acc[mt] = MFMA16(af[mt][0], bk0, fzero4());
            acc[mt] = MFMA16(af[mt][1], bk1, acc[mt]);
        }
        int ic = i0 + r15;
#pragma unroll
        for (int mt = 0; mt < 4; ++mt)
#pragma unroll
            for (int r = 0; r < 4; ++r) {
                int a = mt * 16 + rbase + r;
                if (a < AG) {
                    float v = acc[mt][r] + b1[(size_t)(h * AG + a) * Nn + ic];
                    L[(size_t)(bh * AG + a) * Nn + ic] = f2bf(v);
                }
            }
    }
}

// ============ softmax over bf16 rows of length Nn ============
__global__ __launch_bounds__(256)
void softmax_rows_bf(ushortT* __restrict__ L) {
    __shared__ float ex[Nn];
    __shared__ float red[256];
    ushortT* p = L + (size_t)blockIdx.x * Nn;
    int t = threadIdx.x;
    float m = -1e30f;
    for (int i = t; i < Nn; i += 256) { float v = bf2f(p[i]); ex[i] = v; m = fmaxf(m, v); }
    red[t] = m; __syncthreads();
    for (int s = 128; s; s >>= 1) { if (t < s) red[t] = fmaxf(red[t], red[t + s]); __syncthreads(); }
    m = red[0]; __syncthreads();
    float sum = 0.f;
    for (int i = t; i < Nn; i += 256) { float e = __expf(ex[i] - m); ex[i] = e; sum += e; }
    red[t] = sum; __syncthreads();
    for (int s = 128; s; s >>= 1) { if (t < s) red[t] += red[t + s]; __syncthreads(); }
    float inv = 1.f / red[0];
    for (int i = t; i < Nn; i += 256) p[i] = f2bf(ex[i] * inv);
}

__global__ void zerof(float* __restrict__ p, int nfl) {
    int g = blockIdx.x * 256 + threadIdx.x;
    if (g < nfl) p[g] = 0.f;
}

// ============ agent_v via MFMA: av[a][d] += P[a][i]·v[i][d] ============
__global__ __launch_bounds__(256)
void agent_v_mfma(const ushortT* __restrict__ qkv, const ushortT* __restrict__ L,
                  float* __restrict__ av) {
    __shared__ __align__(16) ushortT vt[4][64 * 72];   // per-wave vT[d][i]
    int t = threadIdx.x, lane = t & 63, wid = t >> 6;
    int bh = blockIdx.y, b = bh >> 3, h = bh & 7;
    int sub = blockIdx.x * 4 + wid;
    if (sub >= AG) return;                 // 49 chunks of 64 i
    int i0 = sub * 64;
    ushortT* vtw = vt[wid];
    {
        const ushortT* vp = &qkv[(size_t)(b * Nn + i0 + lane) * 1536 + 1024 + (h << 6)];
#pragma unroll
        for (int d8 = 0; d8 < 64; d8 += 8) {
            ushort4 u0 = *(const ushort4*)(vp + d8);
            ushort4 u1 = *(const ushort4*)(vp + d8 + 4);
            vtw[(d8 + 0) * 72 + lane] = u0.x; vtw[(d8 + 1) * 72 + lane] = u0.y;
            vtw[(d8 + 2) * 72 + lane] = u0.z; vtw[(d8 + 3) * 72 + lane] = u0.w;
            vtw[(d8 + 4) * 72 + lane] = u1.x; vtw[(d8 + 5) * 72 + lane] = u1.y;
            vtw[(d8 + 6) * 72 + lane] = u1.z; vtw[(d8 + 7) * 72 + lane] = u1.w;
        }
    }
    int r15 = lane & 15, kq = (lane >> 4) << 3;
    f32x4 acc[4][4];
#pragma unroll
    for (int i = 0; i < 4; ++i)
#pragma unroll
        for (int j = 0; j < 4; ++j) acc[i][j] = fzero4();
#pragma unroll
    for (int ks = 0; ks < 2; ++ks) {
        bf16x8 afr[4], bfr[4];
#pragma unroll
        for (int mt = 0; mt < 4; ++mt) {
            int a = min(mt * 16 + r15, AG - 1);
            afr[mt] = *(const bf16x8*)&L[(size_t)(bh * AG + a) * Nn + i0 + ks * 32 + kq];
        }
#pragma unroll
        for (int nt = 0; nt < 4; ++nt)
            bfr[nt] = *(const bf16x8*)&vtw[(nt * 16 + r15) * 72 + ks * 32 + kq];
#pragma unroll
        for (int mt = 0; mt < 4; ++mt)
#pragma unroll
            for (int nt = 0; nt < 4; ++nt)
                acc[mt][nt] = MFMA16(afr[mt], bfr[nt], acc[mt][nt]);
    }
    int rbase = (lane >> 4) << 2;
#pragma unroll
    for (int mt = 0; mt < 4; ++mt)
#pragma unroll
        for (int r = 0; r < 4; ++r) {
            int a = mt * 16 + rbase + r;
            if (a < AG) {
#pragma unroll
                for (int nt = 0; nt < 4; ++nt)
                    atomicAdd(&av[((size_t)(bh * AG + a) << 6) + nt * 16 + r15],
                              acc[mt][nt][r]);
            }
        }
}

// ============ fused q-attention via MFMA: QK^T -> reg softmax -> P·av ============
__global__ __launch_bounds__(256)
void q_attn_mfma(const ushortT* __restrict__ qkv, const float* __restrict__ at,
                 const float* __restrict__ av, const float* __restrict__ b2,
                 ushortT* __restrict__ attn) {
    __shared__ __align__(16) ushortT ah_s[64 * 72];
    __shared__ __align__(16) ushortT avT[64 * 72];
    __shared__ __align__(16) ushortT p_s[4][16 * 72];
    int t = threadIdx.x, lane = t & 63, wid = t >> 6;
    int bh = blockIdx.y, b = bh >> 3, h = bh & 7;
    for (int idx = t; idx < 512; idx += 256) {
        int a = idx >> 3, d8 = (idx & 7) << 3;
        bf16x8 tmp;
        if (a < AG) {
            const float* p = &at[((size_t)(b * AG + a) << 9) + (h << 6) + d8];
#pragma unroll
            for (int j = 0; j < 8; ++j) tmp[j] = (short)f2bf(p[j] * 0.125f);
        } else {
#pragma unroll
            for (int j = 0; j < 8; ++j) tmp[j] = 0;
        }
        *(bf16x8*)&ah_s[a * 72 + d8] = tmp;
    }
    for (int idx = t; idx < 4096; idx += 256) {     // avT[d][a] <- av[a][d]
        int a = idx >> 6, d = idx & 63;
        float v = (a < AG) ? av[((size_t)(bh * AG + a) << 6) + d] : 0.f;
        avT[d * 72 + a] = f2bf(v);
    }
    __syncthreads();
    int r15 = lane & 15, kq = (lane >> 4) << 3;
    bf16x8 bah[4][2], bav[4][2];
#pragma unroll
    for (int nt = 0; nt < 4; ++nt)
#pragma unroll
        for (int ks = 0; ks < 2; ++ks) {
            bah[nt][ks] = *(const bf16x8*)&ah_s[(nt * 16 + r15) * 72 + ks * 32 + kq];
            bav[nt][ks] = *(const bf16x8*)&avT[(nt * 16 + r15) * 72 + ks * 32 + kq];
        }
    ushortT* psw = p_s[wid];
    int i0b = blockIdx.x * 448;
    int rbase = (lane >> 4) << 2;
    for (int tt = 0; tt < 7; ++tt) {
        int i0 = i0b + (wid * 7 + tt) * 16;
        const ushortT* qp = &qkv[(size_t)(b * Nn + i0 + r15) * 1536 + (h << 6) + kq];
        bf16x8 aq0 = *(const bf16x8*)qp;
        bf16x8 aq1 = *(const bf16x8*)(qp + 32);
        f32x4 lg[4];
#pragma unroll
        for (int nt = 0; nt < 4; ++nt) {
            lg[nt] = MFMA16(aq0, bah[nt][0], fzero4());
            lg[nt] = MFMA16(aq1, bah[nt][1], lg[nt]);
        }
        float p4[4][4];   // [nt][r]
#pragma unroll
        for (int r = 0; r < 4; ++r) {
            int i = i0 + rbase + r;
            float vals[4]; float mx = -1e30f;
#pragma unroll
            for (int nt = 0; nt < 4; ++nt) {
                int a = nt * 16 + r15;
                float v = -1e30f;
                if (a < AG) v = lg[nt][r] + b2[(size_t)(h * Nn + i) * AG + a];
                vals[nt] = v;
                mx = fmaxf(mx, v);
            }
#pragma unroll
            for (int off = 8; off >= 1; off >>= 1) mx = fmaxf(mx, __shfl_xor(mx, off));
            float sm = 0.f;
#pragma unroll
            for (int nt = 0; nt < 4; ++nt) {
                float e = (vals[nt] > -1e29f) ? __expf(vals[nt] - mx) : 0.f;
                vals[nt] = e; sm += e;
            }
#pragma unroll
            for (int off = 8; off >= 1; off >>= 1) sm += __shfl_xor(sm, off);
            float inv = 1.f / sm;
#pragma unroll
            for (int nt = 0; nt < 4; ++nt) p4[nt][r] = vals[nt] * inv;
        }
#pragma unroll
        for (int nt = 0; nt < 4; ++nt)
#pragma unroll
            for (int r = 0; r < 4; ++r)
                psw[(rbase + r) * 72 + nt * 16 + r15] = f2bf(p4[nt][r]);
        bf16x8 ap0 = *(const bf16x8*)&psw[r15 * 72 + kq];
        bf16x8 ap1 = *(const bf16x8*)&psw[r15 * 72 + 32 + kq];
        f32x4 ov[4];
#pragma unroll
        for (int nt = 0; nt < 4; ++nt) {
            ov[nt] = MFMA16(ap0, bav[nt][0], fzero4());
            ov[nt] = MFMA16(ap1, bav[nt][1], ov[nt]);
        }
#pragma unroll
        for (int r = 0; r < 4; ++r) {
            int i = i0 + rbase + r;
            ushortT* op = &attn[(size_t)(b * Nn + i) * C_ + (h << 6)];
#pragma unroll
            for (int nt = 0; nt < 4; ++nt)
                op[nt * 16 + r15] = f2bf(ov[nt][r]);
        }
    }
}

// ============ depthwise 3x3 conv on v, added into attn; 8 channels/thread ============
__global__ void dwc_add_v(const ushortT* __restrict__ qkv, const float* __restrict__ wT,
                          const float* __restrict__ bb, ushortT* __restrict__ attn) {
    int g = blockIdx.x * 256 + threadIdx.x;   // B*Nn*64
    int c8 = (g & 63) << 3;
    int bi = g >> 6;
    int i = bi % Nn;
    int y = i / 56, x = i % 56;
    float acc[8];
    {
        float4 b0 = *(const float4*)&bb[c8];
        float4 b1 = *(const float4*)&bb[c8 + 4];
        acc[0] = b0.x; acc[1] = b0.y; acc[2] = b0.z; acc[3] = b0.w;
        acc[4] = b1.x; acc[5] = b1.y; acc[6] = b1.z; acc[7] = b1.w;
    }
#pragma unroll
    for (int dy = -1; dy <= 1; ++dy) {
        int yy = y + dy; if (yy < 0 || yy > 55) continue;
#pragma unroll
        for (int dx = -1; dx <= 1; ++dx) {
            int xx = x + dx; if (xx < 0 || xx > 55) continue;
            const ushortT* vp = &qkv[(size_t)(bi + dy * 56 + dx) * 1536 + 1024 + c8];
            ushort4 u0 = *(const ushort4*)vp;
            ushort4 u1 = *(const ushort4*)(vp + 4);
            const float* wp = &wT[((dy + 1) * 3 + dx + 1) * 512 + c8];
            float4 w0 = *(const float4*)wp;
            float4 w1 = *(const float4*)(wp + 4);
            acc[0] += bf2f(u0.x) * w0.x; acc[1] += bf2f(u0.y) * w0.y;
            acc[2] += bf2f(u0.z) * w0.z; acc[3] += bf2f(u0.w) * w0.w;
            acc[4] += bf2f(u1.x) * w1.x; acc[5] += bf2f(u1.y) * w1.y;
            acc[6] += bf2f(u1.z) * w1.z; acc[7] += bf2f(u1.w) * w1.w;
        }
    }
    ushortT* op = &attn[(size_t)bi * C_ + c8];
    ushort4 a0 = *(const ushort4*)op;
    ushort4 a1 = *(const ushort4*)(op + 4);
    ushort4 o0 = make_ushort4(f2bf(bf2f(a0.x) + acc[0]), f2bf(bf2f(a0.y) + acc[1]),
                              f2bf(bf2f(a0.z) + acc[2]), f2bf(bf2f(a0.w) + acc[3]));
    ushort4 o1 = make_ushort4(f2bf(bf2f(a1.x) + acc[4]), f2bf(bf2f(a1.y) + acc[5]),
                              f2bf(bf2f(a1.z) + acc[6]), f2bf(bf2f(a1.w) + acc[7]));
    *(ushort4*)op = o0; *(ushort4*)(op + 4) = o1;
}

extern "C" void kernel_launch(void* const* d_in, const int* in_sizes, int n_in,
                              void* d_out, int out_size, void* d_ws, size_t ws_size,
                              hipStream_t stream) {
    const float* x      = (const float*)d_in[0];
    const float* q_w    = (const float*)d_in[3];
    const float* kv_w   = (const float*)d_in[4];
    const float* proj_w = (const float*)d_in[5];
    const float* proj_b = (const float*)d_in[6];
    const float* dwc_w  = (const float*)d_in[7];
    const float* dwc_b  = (const float*)d_in[8];
    const float* an_b   = (const float*)d_in[9];
    const float* na_b   = (const float*)d_in[10];
    const float* ah_b   = (const float*)d_in[11];
    const float* aw_b   = (const float*)d_in[12];
    const float* ha_b   = (const float*)d_in[13];
    const float* wa_b   = (const float*)d_in[14];
    float* out = (float*)d_out;

    // ---- workspace (220,682,240 B ≈ 210.5 MiB); R region reused: xb -> L -> attn ----
    char* ws = (char*)d_ws;
    ushortT* R    = (ushortT*)(ws);                 // 51,380,224 B
    ushortT* qkv  = (ushortT*)(ws + 51380224);      // 154,140,672 B
    ushortT* Wqkv = (ushortT*)(ws + 205520896);     // 1,572,864 B
    ushortT* Wp   = (ushortT*)(ws + 207093760);     // 524,288 B
    float*   wT   = (float*)(ws + 207618048);       // 18,432 B
    float*   at   = (float*)(ws + 207636480);       // 1,605,632 B
    float*   b1   = (float*)(ws + 209242112);       // 4,917,248 B
    float*   b2   = (float*)(ws + 214159360);       // 4,917,248 B
    float*   av   = (float*)(ws + 219076608);       // 1,605,632 B
    ushortT* xb   = R;            // 50176x512 bf16 (dead after QKV GEMM)
    ushortT* L    = R;            // 6272x3136  bf16 (dead before attn written)
    ushortT* attn = R;            // 50176x512 bf16

    // 0) dtype conversions / repacks
    cvt_f2b4<<<25088, 256, 0, stream>>>(x, xb, 6422528);
    cvt_f2b4<<<256,   256, 0, stream>>>(q_w, Wqkv, 65536);
    cvt_f2b4<<<512,   256, 0, stream>>>(kv_w, Wqkv + 262144, 131072);
    cvt_f2b4<<<256,   256, 0, stream>>>(proj_w, Wp, 65536);
    repack_w<<<18,    256, 0, stream>>>(dwc_w, wT);
    // 1) fused QKV GEMM (bf16 MFMA, 256x256 8-phase)  M=50176 N=1536 K=512
    gemm256<ushortT><<<1176, 512, 0, stream>>>(xb, Wqkv, nullptr, qkv, 1536, 6);
    // 2) agent tokens
    agent_pool<<<196, 256, 0, stream>>>(qkv, at);
    // 3) position biases
    bias1_k<<<4802, 256, 0, stream>>>(an_b, ah_b, aw_b, b1);
    bias2_k<<<4802, 256, 0, stream>>>(na_b, ha_b, wa_b, b2);
    // 4) agent attention
    agent_logits_mfma<<<dim3(7, 128), 256, 0, stream>>>(qkv, at, b1, L);
    softmax_rows_bf<<<6272, 256, 0, stream>>>(L);
    zerof<<<1568, 256, 0, stream>>>(av, B_ * HEADS * AG * HD);
    agent_v_mfma<<<dim3(13, 128), 256, 0, stream>>>(qkv, L, av);
    // 5) q attention (fused MFMA)
    q_attn_mfma<<<dim3(7, 128), 256, 0, stream>>>(qkv, at, av, b2, attn);
    // 6) depthwise conv add
    dwc_add_v<<<12544, 256, 0, stream>>>(qkv, wT, dwc_b, attn);
    // 7) output projection (bf16 MFMA, fp32 out + bias)  M=50176 N=512 K=512
    gemm256<float><<<392, 512, 0, stream>>>(attn, Wp, proj_b, out, 512, 2);
}

// Round 3
// 536.934 us; speedup vs baseline: 1.3457x; 1.1579x over previous
//
#include <hip/hip_runtime.h>
#include <math.h>

#define B_ 16
#define C_ 512
#define Nn 3136
#define HEADS 8
#define HD 64
#define AG 49
#define Mrows (B_ * Nn)   // 50176

typedef unsigned short ushortT;
typedef __attribute__((ext_vector_type(8))) short bf16x8;
typedef __attribute__((ext_vector_type(4))) float f32x4;

#define MFMA16(a, b, c) __builtin_amdgcn_mfma_f32_16x16x32_bf16((a), (b), (c), 0, 0, 0)

__device__ inline float bf2f(ushortT u) { return __uint_as_float(((unsigned)u) << 16); }
__device__ inline ushortT f2bf(float f) {
    unsigned x = __float_as_uint(f);
    unsigned r = (x + 0x7fffu + ((x >> 16) & 1u)) >> 16;   // RNE
    return (ushortT)r;
}
__device__ inline f32x4 fzero4() { f32x4 z = {0.f, 0.f, 0.f, 0.f}; return z; }

// async global->LDS, 16B per lane; lds dest = wave-uniform base + lane*16
__device__ inline void gl_lds16(const ushortT* g, ushortT* l) {
    __builtin_amdgcn_global_load_lds(
        (const __attribute__((address_space(1))) void*)g,
        (__attribute__((address_space(3))) void*)l, 16, 0, 0);
}

#define VMCNT(n) asm volatile("s_waitcnt vmcnt(" #n ")" ::: "memory")
#define LGKM0_SB() { asm volatile("s_waitcnt lgkmcnt(0)" ::: "memory"); \
                     __builtin_amdgcn_sched_barrier(0); }
#define BAR() __builtin_amdgcn_s_barrier()

// ============ fp32 -> bf16 elementwise (x, weights) ============
__global__ void cvt_f2b4(const float* __restrict__ src, ushortT* __restrict__ dst, int n4) {
    int g = blockIdx.x * 256 + threadIdx.x;
    if (g >= n4) return;
    float4 v = *(const float4*)&src[(size_t)g * 4];
    ushort4 o = make_ushort4(f2bf(v.x), f2bf(v.y), f2bf(v.z), f2bf(v.w));
    *(ushort4*)&dst[(size_t)g * 4] = o;
}

// dwc_w [c][3][3] -> wT [tap][c] fp32
__global__ void repack_w(const float* __restrict__ w, float* __restrict__ wT) {
    int g = blockIdx.x * 256 + threadIdx.x;
    if (g >= 9 * 512) return;
    int c = g % 512, tap = g / 512;
    wT[g] = w[c * 9 + tap];
}

// one C-quadrant of the per-wave 128x64 tile: 4 m-frags x 2 n-frags x 2 k-slices
template <int MB, int NL>
__device__ __forceinline__ void quad(f32x4 (&acc)[8][4], const bf16x8 (&af)[4][2],
                                     const bf16x8 (&bf)[4][2]) {
#pragma unroll
    for (int m = 0; m < 4; ++m)
#pragma unroll
        for (int n = 0; n < 2; ++n) {
            acc[MB + m][NL + n] = MFMA16(af[m][0], bf[NL + n][0], acc[MB + m][NL + n]);
            acc[MB + m][NL + n] = MFMA16(af[m][1], bf[NL + n][1], acc[MB + m][NL + n]);
        }
}

// ============ MFMA GEMM: out[m,n] = sum_k A[m,k]*Bw[n,k] (+bias), K=512 fixed ======
// 256x256 tile, BK=64, 8 waves (2Mx4N), dbuf LDS (128 KiB), 8-phase schedule.
// (See round-2 notes; at K=512 this is near the shallow-K structural ceiling.)
template <typename TO>
__global__ __launch_bounds__(512, 2)
void gemm256(const ushortT* __restrict__ A, const ushortT* __restrict__ Bw,
             const float* __restrict__ bias, TO* __restrict__ out,
             int N, int nbn) {
    __shared__ __align__(16) ushortT As[2][16384];   // [buf][256 rows][64 k] bf16
    __shared__ __align__(16) ushortT Bs[2][16384];
    const int t = threadIdx.x, lane = t & 63, wid = t >> 6;
    const int chunk = (int)gridDim.x >> 3;
    const int id2 = ((int)blockIdx.x & 7) * chunk + ((int)blockIdx.x >> 3);
    const int by = id2 / nbn, bx = id2 - by * nbn;
    const int m0 = by * 256, n0 = bx * 256;
    const int wm = wid >> 2, wn = wid & 3;

    const int rl0 = t >> 3;
    const int skg = (t & 7) ^ (rl0 & 7);
    const int ra0 = rl0 & 63;
    const int ra1 = (rl0 & 63) + 128;
    const int rb0 = (rl0 & 31) + ((rl0 >> 5) << 6);
    const int rb1 = rb0 + 128;
    const ushortT* gA0 = A + (size_t)(m0 + ra0) * 512 + skg * 8;
    const ushortT* gA1 = A + (size_t)(m0 + ra1) * 512 + skg * 8;
    const ushortT* gB0 = Bw + (size_t)(n0 + rb0) * 512 + skg * 8;
    const ushortT* gB1 = Bw + (size_t)(n0 + rb1) * 512 + skg * 8;
    const int bA0 = wid * 512;
    const int bA1 = wid * 512 + 8192;
    const int gbu = ((wid * 8) & 31) + (((wid * 8) >> 5) << 6);
    const int bB0 = gbu * 64;
    const int bB1 = bB0 + 8192;

#define ISSA(bufi, ro, ko) { gl_lds16(gA0 + (ro) * 512 + (ko), &As[bufi][bA0 + (ro) * 64]); \
                             gl_lds16(gA1 + (ro) * 512 + (ko), &As[bufi][bA1 + (ro) * 64]); }
#define ISSB(bufi, ro, ko) { gl_lds16(gB0 + (ro) * 512 + (ko), &Bs[bufi][bB0 + (ro) * 64]); \
                             gl_lds16(gB1 + (ro) * 512 + (ko), &Bs[bufi][bB1 + (ro) * 64]); }

    f32x4 acc[8][4];
#pragma unroll
    for (int i = 0; i < 8; ++i)
#pragma unroll
        for (int j = 0; j < 4; ++j) acc[i][j] = fzero4();

    const int r15 = lane & 15, kq16 = lane >> 4;
    const int rA = wm * 128 + r15;
    const int rB = wn * 64 + r15;
    const int sw0 = ((kq16) ^ (r15 & 7)) << 3;
    const int sw1 = ((4 + kq16) ^ (r15 & 7)) << 3;

    ISSA(0, 0, 0);
    ISSB(0, 0, 0);
    ISSB(0, 32, 0);
    ISSA(0, 64, 0);
    VMCNT(4);
    BAR();

    bf16x8 af[4][2], bf[4][2];
    for (int kt = 0; kt < 8; ++kt) {
        const ushortT* Ac = As[kt & 1];
        const ushortT* Bc = Bs[kt & 1];
        const int nb = (kt + 1) & 1;
        const int ko = (kt + 1) * 64;
        const bool pre = (kt < 7);
        // p0
#pragma unroll
        for (int mt = 0; mt < 4; ++mt) {
            af[mt][0] = *(const bf16x8*)&Ac[(rA + mt * 16) * 64 + sw0];
            af[mt][1] = *(const bf16x8*)&Ac[(rA + mt * 16) * 64 + sw1];
        }
#pragma unroll
        for (int nt = 0; nt < 2; ++nt) {
            bf[nt][0] = *(const bf16x8*)&Bc[(rB + nt * 16) * 64 + sw0];
            bf[nt][1] = *(const bf16x8*)&Bc[(rB + nt * 16) * 64 + sw1];
        }
        if (pre) ISSA(nb, 0, ko);
        BAR(); LGKM0_SB();
        __builtin_amdgcn_s_setprio(1);
        quad<0, 0>(acc, af, bf);
        __builtin_amdgcn_s_setprio(0);
        if (pre) { VMCNT(4); } else { VMCNT(2); }
        BAR();
        // p1
#pragma unroll
        for (int nt = 2; nt < 4; ++nt) {
            bf[nt][0] = *(const bf16x8*)&Bc[(rB + nt * 16) * 64 + sw0];
            bf[nt][1] = *(const bf16x8*)&Bc[(rB + nt * 16) * 64 + sw1];
        }
        if (pre) ISSB(nb, 0, ko);
        BAR(); LGKM0_SB();
        __builtin_amdgcn_s_setprio(1);
        quad<0, 2>(acc, af, bf);
        __builtin_amdgcn_s_setprio(0);
        if (pre) { VMCNT(4); } else { VMCNT(0); }
        BAR();
        // p2
#pragma unroll
        for (int mt = 0; mt < 4; ++mt) {
            af[mt][0] = *(const bf16x8*)&Ac[(rA + 64 + mt * 16) * 64 + sw0];
            af[mt][1] = *(const bf16x8*)&Ac[(rA + 64 + mt * 16) * 64 + sw1];
        }
        if (pre) ISSB(nb, 32, ko);
        BAR(); LGKM0_SB();
        __builtin_amdgcn_s_setprio(1);
        quad<4, 0>(acc, af, bf);
        __builtin_amdgcn_s_setprio(0);
        BAR();
        // p3
        if (pre) ISSA(nb, 64, ko);
        BAR(); LGKM0_SB();
        __builtin_amdgcn_s_setprio(1);
        quad<4, 2>(acc, af, bf);
        __builtin_amdgcn_s_setprio(0);
        if (pre) { VMCNT(4); }
        BAR();
    }
#undef ISSA
#undef ISSB

    const int cn = r15, rg = kq16 << 2;
#pragma unroll
    for (int mt = 0; mt < 8; ++mt) {
        int mrow = m0 + wm * 128 + mt * 16 + rg;
#pragma unroll
        for (int nt = 0; nt < 4; ++nt) {
            int ncol = n0 + wn * 64 + nt * 16 + cn;
            float bv = bias ? bias[ncol] : 0.f;
#pragma unroll
            for (int r = 0; r < 4; ++r) {
                float v = acc[mt][nt][r] + bv;
                if (sizeof(TO) == 2) ((ushortT*)out)[(size_t)(mrow + r) * N + ncol] = f2bf(v);
                else                 ((float*)out)[(size_t)(mrow + r) * N + ncol] = v;
            }
        }
    }
}

// ============ agent tokens: 8x8 mean pool of q (bf16 in, fp32 out), 8ch/thread ==========
__global__ void agent_pool(const ushortT* __restrict__ qkv, float* __restrict__ at) {
    int g = blockIdx.x * 256 + threadIdx.x;       // 16*49*64
    int c8 = (g & 63) << 3;
    int a = (g >> 6) % AG;
    int b = g / (AG * 64);
    int p1 = a / 7, p2 = a % 7;
    float s[8] = {};
    for (int yy = 0; yy < 8; ++yy)
#pragma unroll
        for (int xx = 0; xx < 8; ++xx) {
            int i = (p1 * 8 + yy) * 56 + (p2 * 8 + xx);
            const ushortT* p = &qkv[(size_t)(b * Nn + i) * 1536 + c8];
            ushort4 u0 = *(const ushort4*)p;
            ushort4 u1 = *(const ushort4*)(p + 4);
            s[0] += bf2f(u0.x); s[1] += bf2f(u0.y); s[2] += bf2f(u0.z); s[3] += bf2f(u0.w);
            s[4] += bf2f(u1.x); s[5] += bf2f(u1.y); s[6] += bf2f(u1.z); s[7] += bf2f(u1.w);
        }
    float* o = &at[((size_t)(b * AG + a) << 9) + c8];
#pragma unroll
    for (int j = 0; j < 8; ++j) o[j] = s[j] * (1.f / 64.f);
}

// ============ bilinear 7->56 biases ============
__device__ inline float bilin7(const float* __restrict__ p, int y, int x) {
    float fy = fminf(fmaxf(y * 0.125f - 0.4375f, 0.f), 6.f);
    float fx = fminf(fmaxf(x * 0.125f - 0.4375f, 0.f), 6.f);
    int y0 = (int)fy; float ty = fy - y0; int y1 = min(y0 + 1, 6);
    int x0 = (int)fx; float tx = fx - x0; int x1 = min(x0 + 1, 6);
    float v00 = p[y0 * 7 + x0], v01 = p[y0 * 7 + x1];
    float v10 = p[y1 * 7 + x0], v11 = p[y1 * 7 + x1];
    return (1.f - ty) * ((1.f - tx) * v00 + tx * v01) + ty * ((1.f - tx) * v10 + tx * v11);
}

__global__ void bias1_k(const float* __restrict__ an, const float* __restrict__ ahb,
                        const float* __restrict__ awb, float* __restrict__ out) {
    int g = blockIdx.x * 256 + threadIdx.x;       // [h][a][i]
    if (g >= HEADS * AG * Nn) return;
    int i = g % Nn; int a = (g / Nn) % AG; int h = g / (AG * Nn);
    int y = i / 56, x = i % 56;
    float v = bilin7(an + (h * AG + a) * 49, y, x);
    out[g] = v + ahb[(h * AG + a) * 56 + y] + awb[(h * AG + a) * 56 + x];
}

__global__ void bias2_k(const float* __restrict__ na, const float* __restrict__ hab,
                        const float* __restrict__ wab, float* __restrict__ out) {
    int g = blockIdx.x * 256 + threadIdx.x;       // [h][i][a]
    if (g >= HEADS * Nn * AG) return;
    int a = g % AG; int i = (g / AG) % Nn; int h = g / (AG * Nn);
    int y = i / 56, x = i % 56;
    float v = bilin7(na + (h * AG + a) * 49, y, x);
    out[g] = v + hab[(h * 56 + y) * AG + a] + wab[(h * 56 + x) * AG + a];
}

__global__ void zerof(float* __restrict__ p, int nfl) {
    int g = blockIdx.x * 256 + threadIdx.x;
    if (g < nfl) p[g] = 0.f;
}

// ============ FUSED agent attention: num[a][d] += sum_i exp(l[a,i]) v[i,d],
//              den[a] += sum_i exp(l[a,i]);  l = (0.125 ah[a])·k[i] + b1.
// No-max softmax is safe: |l| <~ 1 (ah std 1/8, scale 1/8, 64-dim dot, bias <=0.05).
// grid (7, 128): blockIdx.x = i-split (448 i each), blockIdx.y = bh. 4 waves.
// Per 64-i chunk: wave w computes S for i-slice [i0+16w, +16) x all 64 a (8 MFMA),
// exp -> p_s[a][i] (bf16); cooperative vT staging; barrier; PV: wave w owns a-rows
// [16w,+16): num-acc += P·v (8 MFMA). End: atomicAdd num/den (associative, no max).
__global__ __launch_bounds__(256)
void agent_av_fused(const ushortT* __restrict__ qkv, const float* __restrict__ at,
                    const float* __restrict__ b1, float* __restrict__ num,
                    float* __restrict__ den) {
    __shared__ __align__(16) ushortT ah_s[64 * 72];
    __shared__ __align__(16) ushortT vt[64 * 72];    // vT[d][i] for current chunk
    __shared__ __align__(16) ushortT p_s[64 * 72];   // P[a][i] bf16 for current chunk
    const int t = threadIdx.x, lane = t & 63, wid = t >> 6;
    const int bh = blockIdx.y, b = bh >> 3, h = bh & 7;
    // stage agent tokens (scaled) as MFMA A-operand rows
    for (int idx = t; idx < 512; idx += 256) {
        int a = idx >> 3, d8 = (idx & 7) << 3;
        bf16x8 tmp;
        if (a < AG) {
            const float* p = &at[((size_t)(b * AG + a) << 9) + (h << 6) + d8];
#pragma unroll
            for (int j = 0; j < 8; ++j) tmp[j] = (short)f2bf(p[j] * 0.125f);
        } else {
#pragma unroll
            for (int j = 0; j < 8; ++j) tmp[j] = 0;
        }
        *(bf16x8*)&ah_s[a * 72 + d8] = tmp;
    }
    __syncthreads();
    const int r15 = lane & 15, kq = (lane >> 4) << 3;
    const int rbase = (lane >> 4) << 2;
    bf16x8 af[4][2];
#pragma unroll
    for (int mt = 0; mt < 4; ++mt)
#pragma unroll
        for (int ks = 0; ks < 2; ++ks)
            af[mt][ks] = *(const bf16x8*)&ah_s[(mt * 16 + r15) * 72 + ks * 32 + kq];

    f32x4 accn[4];                          // PV acc: a-rows [16*wid,+16) x 64 d
#pragma unroll
    for (int nt = 0; nt < 4; ++nt) accn[nt] = fzero4();
    float denl[4][4];                       // den partials: a = mt*16+rbase+r
#pragma unroll
    for (int mt = 0; mt < 4; ++mt)
#pragma unroll
        for (int r = 0; r < 4; ++r) denl[mt][r] = 0.f;

    const int i0b = blockIdx.x * 448;
    const int svi = t >> 2, svd = (t & 3) << 4;   // vT staging: thread -> (i-col, 16 d)
    for (int cc = 0; cc < 7; ++cc) {
        const int i0 = i0b + cc * 64;
        // ---- cooperative vT staging: vt[d][i] <- v[i0+i][d]
        {
            const ushortT* vp = &qkv[(size_t)(b * Nn + i0 + svi) * 1536 + 1024 + (h << 6) + svd];
            bf16x8 u0 = *(const bf16x8*)vp;
            bf16x8 u1 = *(const bf16x8*)(vp + 8);
#pragma unroll
            for (int j = 0; j < 8; ++j) {
                vt[(svd + j) * 72 + svi]     = (ushortT)u0[j];
                vt[(svd + 8 + j) * 72 + svi] = (ushortT)u1[j];
            }
        }
        // ---- S for this wave's 16-i slice (all 64 a), exp, den partial, P write
        {
            const int iw = i0 + wid * 16;
            const ushortT* kp = &qkv[(size_t)(b * Nn + iw + r15) * 1536 + 512 + (h << 6) + kq];
            bf16x8 bk0 = *(const bf16x8*)kp;
            bf16x8 bk1 = *(const bf16x8*)(kp + 32);
            f32x4 sacc[4];
#pragma unroll
            for (int mt = 0; mt < 4; ++mt) {
                sacc[mt] = MFMA16(af[mt][0], bk0, fzero4());
                sacc[mt] = MFMA16(af[mt][1], bk1, sacc[mt]);
            }
            const int ic = iw + r15;        // this lane's i (C-layout col)
#pragma unroll
            for (int mt = 0; mt < 4; ++mt)
#pragma unroll
                for (int r = 0; r < 4; ++r) {
                    int a = mt * 16 + rbase + r;
                    float e = 0.f;
                    if (a < AG)
                        e = __expf(sacc[mt][r] + b1[(size_t)(h * AG + a) * Nn + ic]);
                    denl[mt][r] += e;
                    p_s[a * 72 + wid * 16 + r15] = f2bf(e);
                }
        }
        __syncthreads();   // vt + p_s complete
        // ---- PV: wave owns a-rows [16*wid, +16); A = p_s rows, B = vt rows (d)
        {
            bf16x8 ap0 = *(const bf16x8*)&p_s[(wid * 16 + r15) * 72 + kq];
            bf16x8 ap1 = *(const bf16x8*)&p_s[(wid * 16 + r15) * 72 + 32 + kq];
#pragma unroll
            for (int nt = 0; nt < 4; ++nt) {
                bf16x8 bv0 = *(const bf16x8*)&vt[(nt * 16 + r15) * 72 + kq];
                bf16x8 bv1 = *(const bf16x8*)&vt[(nt * 16 + r15) * 72 + 32 + kq];
                accn[nt] = MFMA16(ap0, bv0, accn[nt]);
                accn[nt] = MFMA16(ap1, bv1, accn[nt]);
            }
        }
        __syncthreads();   // protect vt/p_s before next chunk's overwrite
    }
    // ---- write num: a = 16*wid + rbase + r, d = nt*16 + r15
#pragma unroll
    for (int r = 0; r < 4; ++r) {
        int a = wid * 16 + rbase + r;
        if (a < AG) {
#pragma unroll
            for (int nt = 0; nt < 4; ++nt)
                atomicAdd(&num[((size_t)(bh * AG + a) << 6) + nt * 16 + r15],
                          accn[nt][r]);
        }
    }
    // ---- reduce den over the 16-lane i-groups, then atomic
#pragma unroll
    for (int mt = 0; mt < 4; ++mt)
#pragma unroll
        for (int r = 0; r < 4; ++r) {
            float s = denl[mt][r];
#pragma unroll
            for (int off = 8; off >= 1; off >>= 1) s += __shfl_xor(s, off);
            if (r15 == 0) {
                int a = mt * 16 + rbase + r;
                if (a < AG) atomicAdd(&den[bh * AG + a], s);
            }
        }
}

// ============ fused q-attention via MFMA: QK^T -> reg softmax (no max) -> P·av ======
// av = num/den folded into the avT staging. Logits bounded (|l| <~ 1.2) => exp safe.
__global__ __launch_bounds__(256)
void q_attn_mfma(const ushortT* __restrict__ qkv, const float* __restrict__ at,
                 const float* __restrict__ num, const float* __restrict__ den,
                 const float* __restrict__ b2, ushortT* __restrict__ attn) {
    __shared__ __align__(16) ushortT ah_s[64 * 72];
    __shared__ __align__(16) ushortT avT[64 * 72];
    __shared__ __align__(16) ushortT p_s[4][16 * 72];
    int t = threadIdx.x, lane = t & 63, wid = t >> 6;
    int bh = blockIdx.y, b = bh >> 3, h = bh & 7;
    for (int idx = t; idx < 512; idx += 256) {
        int a = idx >> 3, d8 = (idx & 7) << 3;
        bf16x8 tmp;
        if (a < AG) {
            const float* p = &at[((size_t)(b * AG + a) << 9) + (h << 6) + d8];
#pragma unroll
            for (int j = 0; j < 8; ++j) tmp[j] = (short)f2bf(p[j] * 0.125f);
        } else {
#pragma unroll
            for (int j = 0; j < 8; ++j) tmp[j] = 0;
        }
        *(bf16x8*)&ah_s[a * 72 + d8] = tmp;
    }
    for (int idx = t; idx < 4096; idx += 256) {     // avT[d][a] <- num[a][d]/den[a]
        int a = idx >> 6, d = idx & 63;
        float v = 0.f;
        if (a < AG)
            v = num[((size_t)(bh * AG + a) << 6) + d] / den[bh * AG + a];
        avT[d * 72 + a] = f2bf(v);
    }
    __syncthreads();
    int r15 = lane & 15, kq = (lane >> 4) << 3;
    bf16x8 bah[4][2], bav[4][2];
#pragma unroll
    for (int nt = 0; nt < 4; ++nt)
#pragma unroll
        for (int ks = 0; ks < 2; ++ks) {
            bah[nt][ks] = *(const bf16x8*)&ah_s[(nt * 16 + r15) * 72 + ks * 32 + kq];
            bav[nt][ks] = *(const bf16x8*)&avT[(nt * 16 + r15) * 72 + ks * 32 + kq];
        }
    ushortT* psw = p_s[wid];
    int i0b = blockIdx.x * 448;
    int rbase = (lane >> 4) << 2;
    for (int tt = 0; tt < 7; ++tt) {
        int i0 = i0b + (wid * 7 + tt) * 16;
        const ushortT* qp = &qkv[(size_t)(b * Nn + i0 + r15) * 1536 + (h << 6) + kq];
        bf16x8 aq0 = *(const bf16x8*)qp;
        bf16x8 aq1 = *(const bf16x8*)(qp + 32);
        f32x4 lg[4];
#pragma unroll
        for (int nt = 0; nt < 4; ++nt) {
            lg[nt] = MFMA16(aq0, bah[nt][0], fzero4());
            lg[nt] = MFMA16(aq1, bah[nt][1], lg[nt]);
        }
        float p4[4][4];   // [nt][r]
#pragma unroll
        for (int r = 0; r < 4; ++r) {
            int i = i0 + rbase + r;
            float vals[4]; float sm = 0.f;
#pragma unroll
            for (int nt = 0; nt < 4; ++nt) {
                int a = nt * 16 + r15;
                float e = 0.f;
                if (a < AG) e = __expf(lg[nt][r] + b2[(size_t)(h * Nn + i) * AG + a]);
                vals[nt] = e; sm += e;
            }
#pragma unroll
            for (int off = 8; off >= 1; off >>= 1) sm += __shfl_xor(sm, off);
            float inv = 1.f / sm;
#pragma unroll
            for (int nt = 0; nt < 4; ++nt) p4[nt][r] = vals[nt] * inv;
        }
#pragma unroll
        for (int nt = 0; nt < 4; ++nt)
#pragma unroll
            for (int r = 0; r < 4; ++r)
                psw[(rbase + r) * 72 + nt * 16 + r15] = f2bf(p4[nt][r]);
        bf16x8 ap0 = *(const bf16x8*)&psw[r15 * 72 + kq];
        bf16x8 ap1 = *(const bf16x8*)&psw[r15 * 72 + 32 + kq];
        f32x4 ov[4];
#pragma unroll
        for (int nt = 0; nt < 4; ++nt) {
            ov[nt] = MFMA16(ap0, bav[nt][0], fzero4());
            ov[nt] = MFMA16(ap1, bav[nt][1], ov[nt]);
        }
#pragma unroll
        for (int r = 0; r < 4; ++r) {
            int i = i0 + rbase + r;
            ushortT* op = &attn[(size_t)(b * Nn + i) * C_ + (h << 6)];
#pragma unroll
            for (int nt = 0; nt < 4; ++nt)
                op[nt * 16 + r15] = f2bf(ov[nt][r]);
        }
    }
}

// ============ depthwise 3x3 conv on v, added into attn; 8 channels/thread ============
__global__ void dwc_add_v(const ushortT* __restrict__ qkv, const float* __restrict__ wT,
                          const float* __restrict__ bb, ushortT* __restrict__ attn) {
    int g = blockIdx.x * 256 + threadIdx.x;   // B*Nn*64
    int c8 = (g & 63) << 3;
    int bi = g >> 6;
    int i = bi % Nn;
    int y = i / 56, x = i % 56;
    float acc[8];
    {
        float4 b0 = *(const float4*)&bb[c8];
        float4 b1 = *(const float4*)&bb[c8 + 4];
        acc[0] = b0.x; acc[1] = b0.y; acc[2] = b0.z; acc[3] = b0.w;
        acc[4] = b1.x; acc[5] = b1.y; acc[6] = b1.z; acc[7] = b1.w;
    }
#pragma unroll
    for (int dy = -1; dy <= 1; ++dy) {
        int yy = y + dy; if (yy < 0 || yy > 55) continue;
#pragma unroll
        for (int dx = -1; dx <= 1; ++dx) {
            int xx = x + dx; if (xx < 0 || xx > 55) continue;
            const ushortT* vp = &qkv[(size_t)(bi + dy * 56 + dx) * 1536 + 1024 + c8];
            ushort4 u0 = *(const ushort4*)vp;
            ushort4 u1 = *(const ushort4*)(vp + 4);
            const float* wp = &wT[((dy + 1) * 3 + dx + 1) * 512 + c8];
            float4 w0 = *(const float4*)wp;
            float4 w1 = *(const float4*)(wp + 4);
            acc[0] += bf2f(u0.x) * w0.x; acc[1] += bf2f(u0.y) * w0.y;
            acc[2] += bf2f(u0.z) * w0.z; acc[3] += bf2f(u0.w) * w0.w;
            acc[4] += bf2f(u1.x) * w1.x; acc[5] += bf2f(u1.y) * w1.y;
            acc[6] += bf2f(u1.z) * w1.z; acc[7] += bf2f(u1.w) * w1.w;
        }
    }
    ushortT* op = &attn[(size_t)bi * C_ + c8];
    ushort4 a0 = *(const ushort4*)op;
    ushort4 a1 = *(const ushort4*)(op + 4);
    ushort4 o0 = make_ushort4(f2bf(bf2f(a0.x) + acc[0]), f2bf(bf2f(a0.y) + acc[1]),
                              f2bf(bf2f(a0.z) + acc[2]), f2bf(bf2f(a0.w) + acc[3]));
    ushort4 o1 = make_ushort4(f2bf(bf2f(a1.x) + acc[4]), f2bf(bf2f(a1.y) + acc[5]),
                              f2bf(bf2f(a1.z) + acc[6]), f2bf(bf2f(a1.w) + acc[7]));
    *(ushort4*)op = o0; *(ushort4*)(op + 4) = o1;
}

extern "C" void kernel_launch(void* const* d_in, const int* in_sizes, int n_in,
                              void* d_out, int out_size, void* d_ws, size_t ws_size,
                              hipStream_t stream) {
    const float* x      = (const float*)d_in[0];
    const float* q_w    = (const float*)d_in[3];
    const float* kv_w   = (const float*)d_in[4];
    const float* proj_w = (const float*)d_in[5];
    const float* proj_b = (const float*)d_in[6];
    const float* dwc_w  = (const float*)d_in[7];
    const float* dwc_b  = (const float*)d_in[8];
    const float* an_b   = (const float*)d_in[9];
    const float* na_b   = (const float*)d_in[10];
    const float* ah_b   = (const float*)d_in[11];
    const float* aw_b   = (const float*)d_in[12];
    const float* ha_b   = (const float*)d_in[13];
    const float* wa_b   = (const float*)d_in[14];
    float* out = (float*)d_out;

    // ---- workspace (220,682,240 B); R region reused: xb -> attn; L eliminated ----
    char* ws = (char*)d_ws;
    ushortT* R    = (ushortT*)(ws);                 // 51,380,224 B
    ushortT* qkv  = (ushortT*)(ws + 51380224);      // 154,140,672 B
    ushortT* Wqkv = (ushortT*)(ws + 205520896);     // 1,572,864 B (dead after QKV gemm)
    ushortT* Wp   = (ushortT*)(ws + 207093760);     // 524,288 B
    float*   wT   = (float*)(ws + 207618048);       // 18,432 B
    float*   at   = (float*)(ws + 207636480);       // 1,605,632 B
    float*   b1   = (float*)(ws + 209242112);       // 4,917,248 B
    float*   b2   = (float*)(ws + 214159360);       // 4,917,248 B
    float*   num  = (float*)(ws + 219076608);       // 1,605,632 B  [bh][49][64]
    float*   den  = (float*)Wqkv;                   // 25,088 B (reuses dead Wqkv)
    ushortT* xb   = R;            // 50176x512 bf16 (dead after QKV GEMM)
    ushortT* attn = R;            // 50176x512 bf16

    // 0) dtype conversions / repacks
    cvt_f2b4<<<25088, 256, 0, stream>>>(x, xb, 6422528);
    cvt_f2b4<<<256,   256, 0, stream>>>(q_w, Wqkv, 65536);
    cvt_f2b4<<<512,   256, 0, stream>>>(kv_w, Wqkv + 262144, 131072);
    cvt_f2b4<<<256,   256, 0, stream>>>(proj_w, Wp, 65536);
    repack_w<<<18,    256, 0, stream>>>(dwc_w, wT);
    // 1) fused QKV GEMM (bf16 MFMA, 256x256 8-phase)  M=50176 N=1536 K=512
    gemm256<ushortT><<<1176, 512, 0, stream>>>(xb, Wqkv, nullptr, qkv, 1536, 6);
    // 2) agent tokens
    agent_pool<<<196, 256, 0, stream>>>(qkv, at);
    // 3) position biases
    bias1_k<<<4802, 256, 0, stream>>>(an_b, ah_b, aw_b, b1);
    bias2_k<<<4802, 256, 0, stream>>>(na_b, ha_b, wa_b, b2);
    // 4) fused agent attention (no-max softmax, associative accumulation)
    zerof<<<1568, 256, 0, stream>>>(num, B_ * HEADS * AG * HD);
    zerof<<<25,   256, 0, stream>>>(den, B_ * HEADS * AG);
    agent_av_fused<<<dim3(7, 128), 256, 0, stream>>>(qkv, at, b1, num, den);
    // 5) q attention (fused MFMA, no-max softmax, av=num/den)
    q_attn_mfma<<<dim3(7, 128), 256, 0, stream>>>(qkv, at, num, den, b2, attn);
    // 6) depthwise conv add
    dwc_add_v<<<12544, 256, 0, stream>>>(qkv, wT, dwc_b, attn);
    // 7) output projection (bf16 MFMA, fp32 out + bias)  M=50176 N=512 K=512
    gemm256<float><<<392, 512, 0, stream>>>(attn, Wp, proj_b, out, 512, 2);
}

// Round 4
// 527.507 us; speedup vs baseline: 1.3698x; 1.0179x over previous
//
#include <hip/hip_runtime.h>
#include <math.h>

#define B_ 16
#define C_ 512
#define Nn 3136
#define HEADS 8
#define HD 64
#define AG 49
#define Mrows (B_ * Nn)   // 50176

typedef unsigned short ushortT;
typedef __attribute__((ext_vector_type(8))) short bf16x8;
typedef __attribute__((ext_vector_type(4))) float f32x4;

#define MFMA16(a, b, c) __builtin_amdgcn_mfma_f32_16x16x32_bf16((a), (b), (c), 0, 0, 0)

__device__ inline float bf2f(ushortT u) { return __uint_as_float(((unsigned)u) << 16); }
__device__ inline ushortT f2bf(float f) {
    unsigned x = __float_as_uint(f);
    unsigned r = (x + 0x7fffu + ((x >> 16) & 1u)) >> 16;   // RNE
    return (ushortT)r;
}
__device__ inline f32x4 fzero4() { f32x4 z = {0.f, 0.f, 0.f, 0.f}; return z; }

// async global->LDS, 16B per lane; lds dest = wave-uniform base + lane*16
__device__ inline void gl_lds16(const ushortT* g, ushortT* l) {
    __builtin_amdgcn_global_load_lds(
        (const __attribute__((address_space(1))) void*)g,
        (__attribute__((address_space(3))) void*)l, 16, 0, 0);
}

#define VMCNT(n) asm volatile("s_waitcnt vmcnt(" #n ")" ::: "memory")
#define LGKM0_SB() { asm volatile("s_waitcnt lgkmcnt(0)" ::: "memory"); \
                     __builtin_amdgcn_sched_barrier(0); }
#define BAR() __builtin_amdgcn_s_barrier()

// ============ fp32 -> bf16 elementwise (x) ============
__global__ void cvt_f2b4(const float* __restrict__ src, ushortT* __restrict__ dst, int n4) {
    int g = blockIdx.x * 256 + threadIdx.x;
    if (g >= n4) return;
    float4 v = *(const float4*)&src[(size_t)g * 4];
    ushort4 o = make_ushort4(f2bf(v.x), f2bf(v.y), f2bf(v.z), f2bf(v.w));
    *(ushort4*)&dst[(size_t)g * 4] = o;
}

// ============ all weight converts + dwc repack in ONE launch ============
// g<65536: q_w quads -> Wqkv[0..]; g<196608: kv_w quads -> Wqkv[262144..];
// g<262144: proj_w quads -> Wp; else: dwc_w [c][3][3] -> wT[tap][c] (4608 taps)
__global__ void cvt_weights(const float* __restrict__ qw, const float* __restrict__ kvw,
                            const float* __restrict__ pw, const float* __restrict__ dwcw,
                            ushortT* __restrict__ Wqkv, ushortT* __restrict__ Wp,
                            float* __restrict__ wT) {
    int g = blockIdx.x * 256 + threadIdx.x;
    if (g < 196608) {
        const float* src = (g < 65536) ? &qw[(size_t)g * 4] : &kvw[(size_t)(g - 65536) * 4];
        float4 v = *(const float4*)src;
        *(ushort4*)&Wqkv[(size_t)g * 4] =
            make_ushort4(f2bf(v.x), f2bf(v.y), f2bf(v.z), f2bf(v.w));
    } else if (g < 262144) {
        float4 v = *(const float4*)&pw[(size_t)(g - 196608) * 4];
        *(ushort4*)&Wp[(size_t)(g - 196608) * 4] =
            make_ushort4(f2bf(v.x), f2bf(v.y), f2bf(v.z), f2bf(v.w));
    } else {
        int gg = g - 262144;
        if (gg < 4608) { int c = gg & 511, tap = gg >> 9; wT[gg] = dwcw[c * 9 + tap]; }
    }
}

// one C-quadrant of the per-wave 128x64 tile: 4 m-frags x 2 n-frags x 2 k-slices
template <int MB, int NL>
__device__ __forceinline__ void quad(f32x4 (&acc)[8][4], const bf16x8 (&af)[4][2],
                                     const bf16x8 (&bf)[4][2]) {
#pragma unroll
    for (int m = 0; m < 4; ++m)
#pragma unroll
        for (int n = 0; n < 2; ++n) {
            acc[MB + m][NL + n] = MFMA16(af[m][0], bf[NL + n][0], acc[MB + m][NL + n]);
            acc[MB + m][NL + n] = MFMA16(af[m][1], bf[NL + n][1], acc[MB + m][NL + n]);
        }
}

// ============ MFMA GEMM: out[m,n] = sum_k A[m,k]*Bw[n,k] (+bias), K=512 fixed ======
// 256x256 tile, BK=64, 8 waves (2Mx4N), dbuf LDS (128 KiB), 4 phases/K-tile.
// ROUND-4 wait discipline: issue ALL 8 next-tile loads early (4 at p0, 4 at p1),
// single vmcnt(0) at end-p3 with ~3 phases of compute slack (>> HBM/L3 latency).
// Hazards: next-tile DMA writes target buf^1 (read side is buf); buf^1's prior
// reads are lgkm-drained inside each phase of tile t-1 before its end barrier.
template <typename TO>
__global__ __launch_bounds__(512, 2)
void gemm256(const ushortT* __restrict__ A, const ushortT* __restrict__ Bw,
             const float* __restrict__ bias, TO* __restrict__ out,
             int N, int nbn) {
    __shared__ __align__(16) ushortT As[2][16384];   // [buf][256 rows][64 k] bf16
    __shared__ __align__(16) ushortT Bs[2][16384];
    const int t = threadIdx.x, lane = t & 63, wid = t >> 6;
    const int chunk = (int)gridDim.x >> 3;
    const int id2 = ((int)blockIdx.x & 7) * chunk + ((int)blockIdx.x >> 3);
    const int by = id2 / nbn, bx = id2 - by * nbn;
    const int m0 = by * 256, n0 = bx * 256;
    const int wm = wid >> 2, wn = wid & 3;

    const int rl0 = t >> 3;
    const int skg = (t & 7) ^ (rl0 & 7);
    const int ra0 = rl0 & 63;
    const int ra1 = (rl0 & 63) + 128;
    const int rb0 = (rl0 & 31) + ((rl0 >> 5) << 6);
    const int rb1 = rb0 + 128;
    const ushortT* gA0 = A + (size_t)(m0 + ra0) * 512 + skg * 8;
    const ushortT* gA1 = A + (size_t)(m0 + ra1) * 512 + skg * 8;
    const ushortT* gB0 = Bw + (size_t)(n0 + rb0) * 512 + skg * 8;
    const ushortT* gB1 = Bw + (size_t)(n0 + rb1) * 512 + skg * 8;
    const int bA0 = wid * 512;
    const int bA1 = wid * 512 + 8192;
    const int gbu = ((wid * 8) & 31) + (((wid * 8) >> 5) << 6);
    const int bB0 = gbu * 64;
    const int bB1 = bB0 + 8192;

#define ISSA(bufi, ro, ko) { gl_lds16(gA0 + (ro) * 512 + (ko), &As[bufi][bA0 + (ro) * 64]); \
                             gl_lds16(gA1 + (ro) * 512 + (ko), &As[bufi][bA1 + (ro) * 64]); }
#define ISSB(bufi, ro, ko) { gl_lds16(gB0 + (ro) * 512 + (ko), &Bs[bufi][bB0 + (ro) * 64]); \
                             gl_lds16(gB1 + (ro) * 512 + (ko), &Bs[bufi][bB1 + (ro) * 64]); }

    f32x4 acc[8][4];
#pragma unroll
    for (int i = 0; i < 8; ++i)
#pragma unroll
        for (int j = 0; j < 4; ++j) acc[i][j] = fzero4();

    const int r15 = lane & 15, kq16 = lane >> 4;
    const int rA = wm * 128 + r15;
    const int rB = wn * 64 + r15;
    const int sw0 = ((kq16) ^ (r15 & 7)) << 3;
    const int sw1 = ((4 + kq16) ^ (r15 & 7)) << 3;

    // prologue: stage tile 0 fully, drain, go
    ISSA(0, 0, 0); ISSA(0, 64, 0);
    ISSB(0, 0, 0); ISSB(0, 32, 0);
    VMCNT(0);
    BAR();

    bf16x8 af[4][2], bf[4][2];
    for (int kt = 0; kt < 8; ++kt) {
        const ushortT* Ac = As[kt & 1];
        const ushortT* Bc = Bs[kt & 1];
        const int nb = (kt + 1) & 1;
        const int ko = (kt + 1) * 64;
        const bool pre = (kt < 7);
        // ---------------- p0: quad (mh0, nh0); issue next-tile A (all) ----------------
#pragma unroll
        for (int mt = 0; mt < 4; ++mt) {
            af[mt][0] = *(const bf16x8*)&Ac[(rA + mt * 16) * 64 + sw0];
            af[mt][1] = *(const bf16x8*)&Ac[(rA + mt * 16) * 64 + sw1];
        }
#pragma unroll
        for (int nt = 0; nt < 2; ++nt) {
            bf[nt][0] = *(const bf16x8*)&Bc[(rB + nt * 16) * 64 + sw0];
            bf[nt][1] = *(const bf16x8*)&Bc[(rB + nt * 16) * 64 + sw1];
        }
        if (pre) { ISSA(nb, 0, ko); ISSA(nb, 64, ko); }
        BAR(); LGKM0_SB();
        __builtin_amdgcn_s_setprio(1);
        quad<0, 0>(acc, af, bf);
        __builtin_amdgcn_s_setprio(0);
        BAR();
        // ---------------- p1: quad (mh0, nh1); issue next-tile B (all) ----------------
#pragma unroll
        for (int nt = 2; nt < 4; ++nt) {
            bf[nt][0] = *(const bf16x8*)&Bc[(rB + nt * 16) * 64 + sw0];
            bf[nt][1] = *(const bf16x8*)&Bc[(rB + nt * 16) * 64 + sw1];
        }
        if (pre) { ISSB(nb, 0, ko); ISSB(nb, 32, ko); }
        BAR(); LGKM0_SB();
        __builtin_amdgcn_s_setprio(1);
        quad<0, 2>(acc, af, bf);
        __builtin_amdgcn_s_setprio(0);
        BAR();
        // ---------------- p2: quad (mh1, nh0) ----------------
#pragma unroll
        for (int mt = 0; mt < 4; ++mt) {
            af[mt][0] = *(const bf16x8*)&Ac[(rA + 64 + mt * 16) * 64 + sw0];
            af[mt][1] = *(const bf16x8*)&Ac[(rA + 64 + mt * 16) * 64 + sw1];
        }
        BAR(); LGKM0_SB();
        __builtin_amdgcn_s_setprio(1);
        quad<4, 0>(acc, af, bf);
        __builtin_amdgcn_s_setprio(0);
        BAR();
        // ---------------- p3: quad (mh1, nh1); single drain of next tile --------------
        __builtin_amdgcn_s_setprio(1);
        quad<4, 2>(acc, af, bf);
        __builtin_amdgcn_s_setprio(0);
        if (pre) { VMCNT(0); }
        BAR();
    }
#undef ISSA
#undef ISSB

    const int cn = r15, rg = kq16 << 2;
#pragma unroll
    for (int mt = 0; mt < 8; ++mt) {
        int mrow = m0 + wm * 128 + mt * 16 + rg;
#pragma unroll
        for (int nt = 0; nt < 4; ++nt) {
            int ncol = n0 + wn * 64 + nt * 16 + cn;
            float bv = bias ? bias[ncol] : 0.f;
#pragma unroll
            for (int r = 0; r < 4; ++r) {
                float v = acc[mt][nt][r] + bv;
                if (sizeof(TO) == 2) ((ushortT*)out)[(size_t)(mrow + r) * N + ncol] = f2bf(v);
                else                 ((float*)out)[(size_t)(mrow + r) * N + ncol] = v;
            }
        }
    }
}

// ============ agent tokens: 8x8 mean pool of q; 784 blocks, LDS reduce ============
__global__ __launch_bounds__(256)
void agent_pool(const ushortT* __restrict__ qkv, float* __restrict__ at) {
    __shared__ float red[256][9];
    int t = threadIdx.x;
    int ba = blockIdx.x;                 // 784 = 16*49
    int b = ba / AG, a = ba % AG;
    int c8 = (t & 63) << 3, qr = t >> 6;
    int p1 = a / 7, p2 = a % 7;
    float s[8] = {};
#pragma unroll
    for (int pp = 0; pp < 16; ++pp) {
        int pos = (qr << 4) + pp;
        int i = (p1 * 8 + (pos >> 3)) * 56 + p2 * 8 + (pos & 7);
        bf16x8 u = *(const bf16x8*)&qkv[(size_t)(b * Nn + i) * 1536 + c8];
#pragma unroll
        for (int j = 0; j < 8; ++j) s[j] += bf2f((ushortT)u[j]);
    }
#pragma unroll
    for (int j = 0; j < 8; ++j) red[t][j] = s[j];
    __syncthreads();
    if (t < 64) {
        float* o = &at[((size_t)(b * AG + a) << 9) + (t << 3)];
#pragma unroll
        for (int j = 0; j < 8; ++j)
            o[j] = (red[t][j] + red[t + 64][j] + red[t + 128][j] + red[t + 192][j])
                   * (1.f / 64.f);
    }
}

// ============ bilinear 7->56 biases (b1 + b2 merged into one launch) ============
__device__ inline float bilin7(const float* __restrict__ p, int y, int x) {
    float fy = fminf(fmaxf(y * 0.125f - 0.4375f, 0.f), 6.f);
    float fx = fminf(fmaxf(x * 0.125f - 0.4375f, 0.f), 6.f);
    int y0 = (int)fy; float ty = fy - y0; int y1 = min(y0 + 1, 6);
    int x0 = (int)fx; float tx = fx - x0; int x1 = min(x0 + 1, 6);
    float v00 = p[y0 * 7 + x0], v01 = p[y0 * 7 + x1];
    float v10 = p[y1 * 7 + x0], v11 = p[y1 * 7 + x1];
    return (1.f - ty) * ((1.f - tx) * v00 + tx * v01) + ty * ((1.f - tx) * v10 + tx * v11);
}

__global__ void bias_k(const float* __restrict__ an, const float* __restrict__ ahb,
                       const float* __restrict__ awb, const float* __restrict__ na,
                       const float* __restrict__ hab, const float* __restrict__ wab,
                       float* __restrict__ b1, float* __restrict__ b2) {
    int g = blockIdx.x * 256 + threadIdx.x;
    const int NT = HEADS * AG * Nn;
    if (g < NT) {                         // b1 [h][a][i]
        int i = g % Nn; int a = (g / Nn) % AG; int h = g / (AG * Nn);
        int y = i / 56, x = i % 56;
        b1[g] = bilin7(an + (h * AG + a) * 49, y, x)
              + ahb[(h * AG + a) * 56 + y] + awb[(h * AG + a) * 56 + x];
    } else {
        g -= NT; if (g >= NT) return;     // b2 [h][i][a]
        int a = g % AG; int i = (g / AG) % Nn; int h = g / (AG * Nn);
        int y = i / 56, x = i % 56;
        b2[g] = bilin7(na + (h * AG + a) * 49, y, x)
              + hab[(h * 56 + y) * AG + a] + wab[(h * 56 + x) * AG + a];
    }
}

__global__ void zero2(float* __restrict__ num, int n1, float* __restrict__ den, int n2) {
    int g = blockIdx.x * 256 + threadIdx.x;
    if (g < n1) num[g] = 0.f;
    else if (g - n1 < n2) den[g - n1] = 0.f;
}

// ============ FUSED agent attention (see round-3 notes): num/den accumulation ======
__global__ __launch_bounds__(256)
void agent_av_fused(const ushortT* __restrict__ qkv, const float* __restrict__ at,
                    const float* __restrict__ b1, float* __restrict__ num,
                    float* __restrict__ den) {
    __shared__ __align__(16) ushortT ah_s[64 * 72];
    __shared__ __align__(16) ushortT vt[64 * 72];    // vT[d][i] for current chunk
    __shared__ __align__(16) ushortT p_s[64 * 72];   // P[a][i] bf16 for current chunk
    const int t = threadIdx.x, lane = t & 63, wid = t >> 6;
    const int bh = blockIdx.y, b = bh >> 3, h = bh & 7;
    for (int idx = t; idx < 512; idx += 256) {
        int a = idx >> 3, d8 = (idx & 7) << 3;
        bf16x8 tmp;
        if (a < AG) {
            const float* p = &at[((size_t)(b * AG + a) << 9) + (h << 6) + d8];
#pragma unroll
            for (int j = 0; j < 8; ++j) tmp[j] = (short)f2bf(p[j] * 0.125f);
        } else {
#pragma unroll
            for (int j = 0; j < 8; ++j) tmp[j] = 0;
        }
        *(bf16x8*)&ah_s[a * 72 + d8] = tmp;
    }
    __syncthreads();
    const int r15 = lane & 15, kq = (lane >> 4) << 3;
    const int rbase = (lane >> 4) << 2;
    bf16x8 af[4][2];
#pragma unroll
    for (int mt = 0; mt < 4; ++mt)
#pragma unroll
        for (int ks = 0; ks < 2; ++ks)
            af[mt][ks] = *(const bf16x8*)&ah_s[(mt * 16 + r15) * 72 + ks * 32 + kq];

    f32x4 accn[4];
#pragma unroll
    for (int nt = 0; nt < 4; ++nt) accn[nt] = fzero4();
    float denl[4][4];
#pragma unroll
    for (int mt = 0; mt < 4; ++mt)
#pragma unroll
        for (int r = 0; r < 4; ++r) denl[mt][r] = 0.f;

    const int i0b = blockIdx.x * 448;
    const int svi = t >> 2, svd = (t & 3) << 4;
    for (int cc = 0; cc < 7; ++cc) {
        const int i0 = i0b + cc * 64;
        {
            const ushortT* vp = &qkv[(size_t)(b * Nn + i0 + svi) * 1536 + 1024 + (h << 6) + svd];
            bf16x8 u0 = *(const bf16x8*)vp;
            bf16x8 u1 = *(const bf16x8*)(vp + 8);
#pragma unroll
            for (int j = 0; j < 8; ++j) {
                vt[(svd + j) * 72 + svi]     = (ushortT)u0[j];
                vt[(svd + 8 + j) * 72 + svi] = (ushortT)u1[j];
            }
        }
        {
            const int iw = i0 + wid * 16;
            const ushortT* kp = &qkv[(size_t)(b * Nn + iw + r15) * 1536 + 512 + (h << 6) + kq];
            bf16x8 bk0 = *(const bf16x8*)kp;
            bf16x8 bk1 = *(const bf16x8*)(kp + 32);
            f32x4 sacc[4];
#pragma unroll
            for (int mt = 0; mt < 4; ++mt) {
                sacc[mt] = MFMA16(af[mt][0], bk0, fzero4());
                sacc[mt] = MFMA16(af[mt][1], bk1, sacc[mt]);
            }
            const int ic = iw + r15;
#pragma unroll
            for (int mt = 0; mt < 4; ++mt)
#pragma unroll
                for (int r = 0; r < 4; ++r) {
                    int a = mt * 16 + rbase + r;
                    float e = 0.f;
                    if (a < AG)
                        e = __expf(sacc[mt][r] + b1[(size_t)(h * AG + a) * Nn + ic]);
                    denl[mt][r] += e;
                    p_s[a * 72 + wid * 16 + r15] = f2bf(e);
                }
        }
        __syncthreads();
        {
            bf16x8 ap0 = *(const bf16x8*)&p_s[(wid * 16 + r15) * 72 + kq];
            bf16x8 ap1 = *(const bf16x8*)&p_s[(wid * 16 + r15) * 72 + 32 + kq];
#pragma unroll
            for (int nt = 0; nt < 4; ++nt) {
                bf16x8 bv0 = *(const bf16x8*)&vt[(nt * 16 + r15) * 72 + kq];
                bf16x8 bv1 = *(const bf16x8*)&vt[(nt * 16 + r15) * 72 + 32 + kq];
                accn[nt] = MFMA16(ap0, bv0, accn[nt]);
                accn[nt] = MFMA16(ap1, bv1, accn[nt]);
            }
        }
        __syncthreads();
    }
#pragma unroll
    for (int r = 0; r < 4; ++r) {
        int a = wid * 16 + rbase + r;
        if (a < AG) {
#pragma unroll
            for (int nt = 0; nt < 4; ++nt)
                atomicAdd(&num[((size_t)(bh * AG + a) << 6) + nt * 16 + r15],
                          accn[nt][r]);
        }
    }
#pragma unroll
    for (int mt = 0; mt < 4; ++mt)
#pragma unroll
        for (int r = 0; r < 4; ++r) {
            float s = denl[mt][r];
#pragma unroll
            for (int off = 8; off >= 1; off >>= 1) s += __shfl_xor(s, off);
            if (r15 == 0) {
                int a = mt * 16 + rbase + r;
                if (a < AG) atomicAdd(&den[bh * AG + a], s);
            }
        }
}

// ============ fused q-attention via MFMA: QK^T -> reg softmax (no max) -> P·av ======
__global__ __launch_bounds__(256)
void q_attn_mfma(const ushortT* __restrict__ qkv, const float* __restrict__ at,
                 const float* __restrict__ num, const float* __restrict__ den,
                 const float* __restrict__ b2, ushortT* __restrict__ attn) {
    __shared__ __align__(16) ushortT ah_s[64 * 72];
    __shared__ __align__(16) ushortT avT[64 * 72];
    __shared__ __align__(16) ushortT p_s[4][16 * 72];
    int t = threadIdx.x, lane = t & 63, wid = t >> 6;
    int bh = blockIdx.y, b = bh >> 3, h = bh & 7;
    for (int idx = t; idx < 512; idx += 256) {
        int a = idx >> 3, d8 = (idx & 7) << 3;
        bf16x8 tmp;
        if (a < AG) {
            const float* p = &at[((size_t)(b * AG + a) << 9) + (h << 6) + d8];
#pragma unroll
            for (int j = 0; j < 8; ++j) tmp[j] = (short)f2bf(p[j] * 0.125f);
        } else {
#pragma unroll
            for (int j = 0; j < 8; ++j) tmp[j] = 0;
        }
        *(bf16x8*)&ah_s[a * 72 + d8] = tmp;
    }
    for (int idx = t; idx < 4096; idx += 256) {     // avT[d][a] <- num[a][d]/den[a]
        int a = idx >> 6, d = idx & 63;
        float v = 0.f;
        if (a < AG)
            v = num[((size_t)(bh * AG + a) << 6) + d] / den[bh * AG + a];
        avT[d * 72 + a] = f2bf(v);
    }
    __syncthreads();
    int r15 = lane & 15, kq = (lane >> 4) << 3;
    bf16x8 bah[4][2], bav[4][2];
#pragma unroll
    for (int nt = 0; nt < 4; ++nt)
#pragma unroll
        for (int ks = 0; ks < 2; ++ks) {
            bah[nt][ks] = *(const bf16x8*)&ah_s[(nt * 16 + r15) * 72 + ks * 32 + kq];
            bav[nt][ks] = *(const bf16x8*)&avT[(nt * 16 + r15) * 72 + ks * 32 + kq];
        }
    ushortT* psw = p_s[wid];
    int i0b = blockIdx.x * 448;
    int rbase = (lane >> 4) << 2;
    for (int tt = 0; tt < 7; ++tt) {
        int i0 = i0b + (wid * 7 + tt) * 16;
        const ushortT* qp = &qkv[(size_t)(b * Nn + i0 + r15) * 1536 + (h << 6) + kq];
        bf16x8 aq0 = *(const bf16x8*)qp;
        bf16x8 aq1 = *(const bf16x8*)(qp + 32);
        f32x4 lg[4];
#pragma unroll
        for (int nt = 0; nt < 4; ++nt) {
            lg[nt] = MFMA16(aq0, bah[nt][0], fzero4());
            lg[nt] = MFMA16(aq1, bah[nt][1], lg[nt]);
        }
        float p4[4][4];   // [nt][r]
#pragma unroll
        for (int r = 0; r < 4; ++r) {
            int i = i0 + rbase + r;
            float vals[4]; float sm = 0.f;
#pragma unroll
            for (int nt = 0; nt < 4; ++nt) {
                int a = nt * 16 + r15;
                float e = 0.f;
                if (a < AG) e = __expf(lg[nt][r] + b2[(size_t)(h * Nn + i) * AG + a]);
                vals[nt] = e; sm += e;
            }
#pragma unroll
            for (int off = 8; off >= 1; off >>= 1) sm += __shfl_xor(sm, off);
            float inv = 1.f / sm;
#pragma unroll
            for (int nt = 0; nt < 4; ++nt) p4[nt][r] = vals[nt] * inv;
        }
#pragma unroll
        for (int nt = 0; nt < 4; ++nt)
#pragma unroll
            for (int r = 0; r < 4; ++r)
                psw[(rbase + r) * 72 + nt * 16 + r15] = f2bf(p4[nt][r]);
        bf16x8 ap0 = *(const bf16x8*)&psw[r15 * 72 + kq];
        bf16x8 ap1 = *(const bf16x8*)&psw[r15 * 72 + 32 + kq];
        f32x4 ov[4];
#pragma unroll
        for (int nt = 0; nt < 4; ++nt) {
            ov[nt] = MFMA16(ap0, bav[nt][0], fzero4());
            ov[nt] = MFMA16(ap1, bav[nt][1], ov[nt]);
        }
#pragma unroll
        for (int r = 0; r < 4; ++r) {
            int i = i0 + rbase + r;
            ushortT* op = &attn[(size_t)(b * Nn + i) * C_ + (h << 6)];
#pragma unroll
            for (int nt = 0; nt < 4; ++nt)
                op[nt * 16 + r15] = f2bf(ov[nt][r]);
        }
    }
}

// ============ depthwise 3x3 conv on v, added into attn; 8 channels/thread ============
__global__ void dwc_add_v(const ushortT* __restrict__ qkv, const float* __restrict__ wT,
                          const float* __restrict__ bb, ushortT* __restrict__ attn) {
    int g = blockIdx.x * 256 + threadIdx.x;   // B*Nn*64
    int c8 = (g & 63) << 3;
    int bi = g >> 6;
    int i = bi % Nn;
    int y = i / 56, x = i % 56;
    float acc[8];
    {
        float4 b0 = *(const float4*)&bb[c8];
        float4 b1 = *(const float4*)&bb[c8 + 4];
        acc[0] = b0.x; acc[1] = b0.y; acc[2] = b0.z; acc[3] = b0.w;
        acc[4] = b1.x; acc[5] = b1.y; acc[6] = b1.z; acc[7] = b1.w;
    }
#pragma unroll
    for (int dy = -1; dy <= 1; ++dy) {
        int yy = y + dy; if (yy < 0 || yy > 55) continue;
#pragma unroll
        for (int dx = -1; dx <= 1; ++dx) {
            int xx = x + dx; if (xx < 0 || xx > 55) continue;
            const ushortT* vp = &qkv[(size_t)(bi + dy * 56 + dx) * 1536 + 1024 + c8];
            ushort4 u0 = *(const ushort4*)vp;
            ushort4 u1 = *(const ushort4*)(vp + 4);
            const float* wp = &wT[((dy + 1) * 3 + dx + 1) * 512 + c8];
            float4 w0 = *(const float4*)wp;
            float4 w1 = *(const float4*)(wp + 4);
            acc[0] += bf2f(u0.x) * w0.x; acc[1] += bf2f(u0.y) * w0.y;
            acc[2] += bf2f(u0.z) * w0.z; acc[3] += bf2f(u0.w) * w0.w;
            acc[4] += bf2f(u1.x) * w1.x; acc[5] += bf2f(u1.y) * w1.y;
            acc[6] += bf2f(u1.z) * w1.z; acc[7] += bf2f(u1.w) * w1.w;
        }
    }
    ushortT* op = &attn[(size_t)bi * C_ + c8];
    ushort4 a0 = *(const ushort4*)op;
    ushort4 a1 = *(const ushort4*)(op + 4);
    ushort4 o0 = make_ushort4(f2bf(bf2f(a0.x) + acc[0]), f2bf(bf2f(a0.y) + acc[1]),
                              f2bf(bf2f(a0.z) + acc[2]), f2bf(bf2f(a0.w) + acc[3]));
    ushort4 o1 = make_ushort4(f2bf(bf2f(a1.x) + acc[4]), f2bf(bf2f(a1.y) + acc[5]),
                              f2bf(bf2f(a1.z) + acc[6]), f2bf(bf2f(a1.w) + acc[7]));
    *(ushort4*)op = o0; *(ushort4*)(op + 4) = o1;
}

extern "C" void kernel_launch(void* const* d_in, const int* in_sizes, int n_in,
                              void* d_out, int out_size, void* d_ws, size_t ws_size,
                              hipStream_t stream) {
    const float* x      = (const float*)d_in[0];
    const float* q_w    = (const float*)d_in[3];
    const float* kv_w   = (const float*)d_in[4];
    const float* proj_w = (const float*)d_in[5];
    const float* proj_b = (const float*)d_in[6];
    const float* dwc_w  = (const float*)d_in[7];
    const float* dwc_b  = (const float*)d_in[8];
    const float* an_b   = (const float*)d_in[9];
    const float* na_b   = (const float*)d_in[10];
    const float* ah_b   = (const float*)d_in[11];
    const float* aw_b   = (const float*)d_in[12];
    const float* ha_b   = (const float*)d_in[13];
    const float* wa_b   = (const float*)d_in[14];
    float* out = (float*)d_out;

    // ---- workspace (220,682,240 B); R region reused: xb -> attn ----
    char* ws = (char*)d_ws;
    ushortT* R    = (ushortT*)(ws);                 // 51,380,224 B
    ushortT* qkv  = (ushortT*)(ws + 51380224);      // 154,140,672 B
    ushortT* Wqkv = (ushortT*)(ws + 205520896);     // 1,572,864 B (dead after QKV gemm)
    ushortT* Wp   = (ushortT*)(ws + 207093760);     // 524,288 B
    float*   wT   = (float*)(ws + 207618048);       // 18,432 B
    float*   at   = (float*)(ws + 207636480);       // 1,605,632 B
    float*   b1   = (float*)(ws + 209242112);       // 4,917,248 B
    float*   b2   = (float*)(ws + 214159360);       // 4,917,248 B
    float*   num  = (float*)(ws + 219076608);       // 1,605,632 B  [bh][49][64]
    float*   den  = (float*)Wqkv;                   // 25,088 B (reuses dead Wqkv)
    ushortT* xb   = R;            // 50176x512 bf16 (dead after QKV GEMM)
    ushortT* attn = R;            // 50176x512 bf16

    // 0) dtype conversions / repacks (2 launches)
    cvt_f2b4<<<25088, 256, 0, stream>>>(x, xb, 6422528);
    cvt_weights<<<1042, 256, 0, stream>>>(q_w, kv_w, proj_w, dwc_w, Wqkv, Wp, wT);
    // 1) fused QKV GEMM (bf16 MFMA, 256x256, deep-slack pipeline)  M=50176 N=1536 K=512
    gemm256<ushortT><<<1176, 512, 0, stream>>>(xb, Wqkv, nullptr, qkv, 1536, 6);
    // 2) agent tokens
    agent_pool<<<784, 256, 0, stream>>>(qkv, at);
    // 3) position biases (one launch)
    bias_k<<<9604, 256, 0, stream>>>(an_b, ah_b, aw_b, na_b, ha_b, wa_b, b1, b2);
    // 4) fused agent attention (no-max softmax, associative accumulation)
    zero2<<<1593, 256, 0, stream>>>(num, B_ * HEADS * AG * HD, den, B_ * HEADS * AG);
    agent_av_fused<<<dim3(7, 128), 256, 0, stream>>>(qkv, at, b1, num, den);
    // 5) q attention (fused MFMA, no-max softmax, av=num/den)
    q_attn_mfma<<<dim3(7, 128), 256, 0, stream>>>(qkv, at, num, den, b2, attn);
    // 6) depthwise conv add
    dwc_add_v<<<12544, 256, 0, stream>>>(qkv, wT, dwc_b, attn);
    // 7) output projection (bf16 MFMA, fp32 out + bias)  M=50176 N=512 K=512
    gemm256<float><<<392, 512, 0, stream>>>(attn, Wp, proj_b, out, 512, 2);
}

// Round 5
// 522.259 us; speedup vs baseline: 1.3835x; 1.0100x over previous
//
#include <hip/hip_runtime.h>
#include <math.h>

#define B_ 16
#define C_ 512
#define Nn 3136
#define HEADS 8
#define HD 64
#define AG 49
#define Mrows (B_ * Nn)   // 50176

typedef unsigned short ushortT;
typedef __attribute__((ext_vector_type(8))) short bf16x8;
typedef __attribute__((ext_vector_type(4))) float f32x4;

#define MFMA16(a, b, c) __builtin_amdgcn_mfma_f32_16x16x32_bf16((a), (b), (c), 0, 0, 0)

__device__ inline float bf2f(ushortT u) { return __uint_as_float(((unsigned)u) << 16); }
__device__ inline ushortT f2bf(float f) {
    unsigned x = __float_as_uint(f);
    unsigned r = (x + 0x7fffu + ((x >> 16) & 1u)) >> 16;   // RNE
    return (ushortT)r;
}
__device__ inline f32x4 fzero4() { f32x4 z = {0.f, 0.f, 0.f, 0.f}; return z; }

// async global->LDS, 16B per lane; lds dest = wave-uniform base + lane*16
__device__ inline void gl_lds16(const ushortT* g, ushortT* l) {
    __builtin_amdgcn_global_load_lds(
        (const __attribute__((address_space(1))) void*)g,
        (__attribute__((address_space(3))) void*)l, 16, 0, 0);
}

#define VMCNT(n) asm volatile("s_waitcnt vmcnt(" #n ")" ::: "memory")
#define LGKM0_SB() { asm volatile("s_waitcnt lgkmcnt(0)" ::: "memory"); \
                     __builtin_amdgcn_sched_barrier(0); }
#define BAR() __builtin_amdgcn_s_barrier()

// ============ all weight converts + dwc repack in ONE launch ============
__global__ void cvt_weights(const float* __restrict__ qw, const float* __restrict__ kvw,
                            const float* __restrict__ pw, const float* __restrict__ dwcw,
                            ushortT* __restrict__ Wqkv, ushortT* __restrict__ Wp,
                            float* __restrict__ wT) {
    int g = blockIdx.x * 256 + threadIdx.x;
    if (g < 196608) {
        const float* src = (g < 65536) ? &qw[(size_t)g * 4] : &kvw[(size_t)(g - 65536) * 4];
        float4 v = *(const float4*)src;
        *(ushort4*)&Wqkv[(size_t)g * 4] =
            make_ushort4(f2bf(v.x), f2bf(v.y), f2bf(v.z), f2bf(v.w));
    } else if (g < 262144) {
        float4 v = *(const float4*)&pw[(size_t)(g - 196608) * 4];
        *(ushort4*)&Wp[(size_t)(g - 196608) * 4] =
            make_ushort4(f2bf(v.x), f2bf(v.y), f2bf(v.z), f2bf(v.w));
    } else {
        int gg = g - 262144;
        if (gg < 4608) { int c = gg & 511, tap = gg >> 9; wT[gg] = dwcw[c * 9 + tap]; }
    }
}

// one C-quadrant of the per-wave 128x64 tile: 4 m-frags x 2 n-frags x 2 k-slices
template <int MB, int NL>
__device__ __forceinline__ void quad(f32x4 (&acc)[8][4], const bf16x8 (&af)[4][2],
                                     const bf16x8 (&bf)[4][2]) {
#pragma unroll
    for (int m = 0; m < 4; ++m)
#pragma unroll
        for (int n = 0; n < 2; ++n) {
            acc[MB + m][NL + n] = MFMA16(af[m][0], bf[NL + n][0], acc[MB + m][NL + n]);
            acc[MB + m][NL + n] = MFMA16(af[m][1], bf[NL + n][1], acc[MB + m][NL + n]);
        }
}

// ============ QKV GEMM with fused fp32->bf16 A-conversion, K=512 ============
// out[m,n] = sum_k x[m,k]*Bw[n,k];  x fp32 (reg-staged + cvt + swizzled ds_write),
// Bw bf16 (DMA, source-swizzled). 256x256 tile, BK=64, 8 waves, dbuf LDS.
// Barrier-FREE inside the tile (reads hit buf, writes hit buf^1 -> no hazard);
// one __syncthreads per K-tile (its implicit vmcnt/lgkm drain covers the DMA
// landing + ds_write visibility). Waves drift -> ds_read/MFMA pipes overlap.
// LDS invariant (both A,B): LDS[row][g] = G[row][g ^ (row&7)] (16B granules);
// A achieves it on the WRITE side (per-lane addr), B on the DMA SOURCE side.
__global__ __launch_bounds__(512, 2)
void gemm_f32a(const float* __restrict__ A32, const ushortT* __restrict__ Bw,
               ushortT* __restrict__ out, int N, int nbn) {
    __shared__ __align__(16) ushortT As[2][16384];   // [buf][256 rows][64 k] bf16
    __shared__ __align__(16) ushortT Bs[2][16384];
    const int t = threadIdx.x, lane = t & 63, wid = t >> 6;
    const int chunk = (int)gridDim.x >> 3;
    const int id2 = ((int)blockIdx.x & 7) * chunk + ((int)blockIdx.x >> 3);
    const int by = id2 / nbn, bx = id2 - by * nbn;
    const int m0 = by * 256, n0 = bx * 256;
    const int wm = wid >> 2, wn = wid & 3;

    // ---- A reg-staging: thread t -> rows rl0+{0,64,128,192}, source granule t&7
    const int rl0 = t >> 3;
    const int kg = t & 7;
    const int wkg = kg ^ (rl0 & 7);                  // write-side swizzled granule
    const float* gAr = A32 + (size_t)(m0 + rl0) * 512 + kg * 8;
    const int dA0 = rl0 * 64 + wkg * 8;              // LDS ushort offsets, row rl0+64j
    // ---- B DMA staging (source-swizzled), identical to proven gemm256 path
    const int rb0 = (rl0 & 31) + ((rl0 >> 5) << 6);
    const int rb1 = rb0 + 128;
    const ushortT* gB0 = Bw + (size_t)(n0 + rb0) * 512 + wkg * 8;
    const ushortT* gB1 = Bw + (size_t)(n0 + rb1) * 512 + wkg * 8;
    const int gbu = ((wid * 8) & 31) + (((wid * 8) >> 5) << 6);
    const int bB0 = gbu * 64;
    const int bB1 = bB0 + 8192;

#define ISSB(bufi, ro, ko) { gl_lds16(gB0 + (ro) * 512 + (ko), &Bs[bufi][bB0 + (ro) * 64]); \
                             gl_lds16(gB1 + (ro) * 512 + (ko), &Bs[bufi][bB1 + (ro) * 64]); }
#define CVTW(bufi) { \
    _Pragma("unroll") \
    for (int j = 0; j < 4; ++j) { \
        bf16x8 w; \
        w[0]=(short)f2bf(pa[j][0].x); w[1]=(short)f2bf(pa[j][0].y); \
        w[2]=(short)f2bf(pa[j][0].z); w[3]=(short)f2bf(pa[j][0].w); \
        w[4]=(short)f2bf(pa[j][1].x); w[5]=(short)f2bf(pa[j][1].y); \
        w[6]=(short)f2bf(pa[j][1].z); w[7]=(short)f2bf(pa[j][1].w); \
        *(bf16x8*)&As[bufi][dA0 + j * 4096] = w; \
    } }

    f32x4 acc[8][4];
#pragma unroll
    for (int i = 0; i < 8; ++i)
#pragma unroll
        for (int j = 0; j < 4; ++j) acc[i][j] = fzero4();

    // frag-read addressing (unchanged): row&7 == r15&7
    const int r15 = lane & 15, kq16 = lane >> 4;
    const int rA = wm * 128 + r15;
    const int rB = wn * 64 + r15;
    const int sw0 = ((kq16) ^ (r15 & 7)) << 3;
    const int sw1 = ((4 + kq16) ^ (r15 & 7)) << 3;

    float4 pa[4][2];
    // prologue: tile 0 -> regs/DMA, cvt+write, fence
#pragma unroll
    for (int j = 0; j < 4; ++j) {
        const float* s = gAr + (size_t)j * 64 * 512;
        pa[j][0] = *(const float4*)s; pa[j][1] = *(const float4*)(s + 4);
    }
    ISSB(0, 0, 0); ISSB(0, 32, 0);
    CVTW(0);
    __syncthreads();

    bf16x8 af[4][2], bf[4][2];
    int cur = 0;
    for (int kt = 0; kt < 8; ++kt) {
        const ushortT* Ac = As[cur];
        const ushortT* Bc = Bs[cur];
        const int nb = cur ^ 1;
        const int ko = (kt + 1) * 64;
        const bool pre = (kt < 7);
        if (pre) {
#pragma unroll
            for (int j = 0; j < 4; ++j) {
                const float* s = gAr + (size_t)j * 64 * 512 + ko;
                pa[j][0] = *(const float4*)s; pa[j][1] = *(const float4*)(s + 4);
            }
            ISSB(nb, 0, ko); ISSB(nb, 32, ko);
        }
        // ---- compute (no intra-tile barriers; compiler manages lgkm waits) ----
#pragma unroll
        for (int mt = 0; mt < 4; ++mt) {
            af[mt][0] = *(const bf16x8*)&Ac[(rA + mt * 16) * 64 + sw0];
            af[mt][1] = *(const bf16x8*)&Ac[(rA + mt * 16) * 64 + sw1];
        }
#pragma unroll
        for (int nt = 0; nt < 2; ++nt) {
            bf[nt][0] = *(const bf16x8*)&Bc[(rB + nt * 16) * 64 + sw0];
            bf[nt][1] = *(const bf16x8*)&Bc[(rB + nt * 16) * 64 + sw1];
        }
        __builtin_amdgcn_s_setprio(1);
        quad<0, 0>(acc, af, bf);
        __builtin_amdgcn_s_setprio(0);
#pragma unroll
        for (int nt = 2; nt < 4; ++nt) {
            bf[nt][0] = *(const bf16x8*)&Bc[(rB + nt * 16) * 64 + sw0];
            bf[nt][1] = *(const bf16x8*)&Bc[(rB + nt * 16) * 64 + sw1];
        }
        __builtin_amdgcn_s_setprio(1);
        quad<0, 2>(acc, af, bf);
        __builtin_amdgcn_s_setprio(0);
#pragma unroll
        for (int mt = 0; mt < 4; ++mt) {
            af[mt][0] = *(const bf16x8*)&Ac[(rA + 64 + mt * 16) * 64 + sw0];
            af[mt][1] = *(const bf16x8*)&Ac[(rA + 64 + mt * 16) * 64 + sw1];
        }
        __builtin_amdgcn_s_setprio(1);
        quad<4, 0>(acc, af, bf);
        quad<4, 2>(acc, af, bf);
        __builtin_amdgcn_s_setprio(0);
        // ---- stage next A into buf^1 (compiler waits pa loads via vmcnt) ----
        if (pre) { CVTW(nb); }
        __syncthreads();   // drains vmcnt (B DMA landed) + lgkm (A writes visible)
        cur ^= 1;
    }
#undef ISSB
#undef CVTW

    const int cn = r15, rg = kq16 << 2;
#pragma unroll
    for (int mt = 0; mt < 8; ++mt) {
        int mrow = m0 + wm * 128 + mt * 16 + rg;
#pragma unroll
        for (int nt = 0; nt < 4; ++nt) {
            int ncol = n0 + wn * 64 + nt * 16 + cn;
#pragma unroll
            for (int r = 0; r < 4; ++r)
                out[(size_t)(mrow + r) * N + ncol] = f2bf(acc[mt][nt][r]);
        }
    }
}

// ============ proj GEMM (bf16 A via DMA) — unchanged control ============
template <typename TO>
__global__ __launch_bounds__(512, 2)
void gemm256(const ushortT* __restrict__ A, const ushortT* __restrict__ Bw,
             const float* __restrict__ bias, TO* __restrict__ out,
             int N, int nbn) {
    __shared__ __align__(16) ushortT As[2][16384];
    __shared__ __align__(16) ushortT Bs[2][16384];
    const int t = threadIdx.x, lane = t & 63, wid = t >> 6;
    const int chunk = (int)gridDim.x >> 3;
    const int id2 = ((int)blockIdx.x & 7) * chunk + ((int)blockIdx.x >> 3);
    const int by = id2 / nbn, bx = id2 - by * nbn;
    const int m0 = by * 256, n0 = bx * 256;
    const int wm = wid >> 2, wn = wid & 3;

    const int rl0 = t >> 3;
    const int skg = (t & 7) ^ (rl0 & 7);
    const int ra0 = rl0 & 63;
    const int ra1 = (rl0 & 63) + 128;
    const int rb0 = (rl0 & 31) + ((rl0 >> 5) << 6);
    const int rb1 = rb0 + 128;
    const ushortT* gA0 = A + (size_t)(m0 + ra0) * 512 + skg * 8;
    const ushortT* gA1 = A + (size_t)(m0 + ra1) * 512 + skg * 8;
    const ushortT* gB0 = Bw + (size_t)(n0 + rb0) * 512 + skg * 8;
    const ushortT* gB1 = Bw + (size_t)(n0 + rb1) * 512 + skg * 8;
    const int bA0 = wid * 512;
    const int bA1 = wid * 512 + 8192;
    const int gbu = ((wid * 8) & 31) + (((wid * 8) >> 5) << 6);
    const int bB0 = gbu * 64;
    const int bB1 = bB0 + 8192;

#define ISSA(bufi, ro, ko) { gl_lds16(gA0 + (ro) * 512 + (ko), &As[bufi][bA0 + (ro) * 64]); \
                             gl_lds16(gA1 + (ro) * 512 + (ko), &As[bufi][bA1 + (ro) * 64]); }
#define ISSB(bufi, ro, ko) { gl_lds16(gB0 + (ro) * 512 + (ko), &Bs[bufi][bB0 + (ro) * 64]); \
                             gl_lds16(gB1 + (ro) * 512 + (ko), &Bs[bufi][bB1 + (ro) * 64]); }

    f32x4 acc[8][4];
#pragma unroll
    for (int i = 0; i < 8; ++i)
#pragma unroll
        for (int j = 0; j < 4; ++j) acc[i][j] = fzero4();

    const int r15 = lane & 15, kq16 = lane >> 4;
    const int rA = wm * 128 + r15;
    const int rB = wn * 64 + r15;
    const int sw0 = ((kq16) ^ (r15 & 7)) << 3;
    const int sw1 = ((4 + kq16) ^ (r15 & 7)) << 3;

    ISSA(0, 0, 0); ISSA(0, 64, 0);
    ISSB(0, 0, 0); ISSB(0, 32, 0);
    VMCNT(0);
    BAR();

    bf16x8 af[4][2], bf[4][2];
    for (int kt = 0; kt < 8; ++kt) {
        const ushortT* Ac = As[kt & 1];
        const ushortT* Bc = Bs[kt & 1];
        const int nb = (kt + 1) & 1;
        const int ko = (kt + 1) * 64;
        const bool pre = (kt < 7);
#pragma unroll
        for (int mt = 0; mt < 4; ++mt) {
            af[mt][0] = *(const bf16x8*)&Ac[(rA + mt * 16) * 64 + sw0];
            af[mt][1] = *(const bf16x8*)&Ac[(rA + mt * 16) * 64 + sw1];
        }
#pragma unroll
        for (int nt = 0; nt < 2; ++nt) {
            bf[nt][0] = *(const bf16x8*)&Bc[(rB + nt * 16) * 64 + sw0];
            bf[nt][1] = *(const bf16x8*)&Bc[(rB + nt * 16) * 64 + sw1];
        }
        if (pre) { ISSA(nb, 0, ko); ISSA(nb, 64, ko); }
        BAR(); LGKM0_SB();
        __builtin_amdgcn_s_setprio(1);
        quad<0, 0>(acc, af, bf);
        __builtin_amdgcn_s_setprio(0);
        BAR();
#pragma unroll
        for (int nt = 2; nt < 4; ++nt) {
            bf[nt][0] = *(const bf16x8*)&Bc[(rB + nt * 16) * 64 + sw0];
            bf[nt][1] = *(const bf16x8*)&Bc[(rB + nt * 16) * 64 + sw1];
        }
        if (pre) { ISSB(nb, 0, ko); ISSB(nb, 32, ko); }
        BAR(); LGKM0_SB();
        __builtin_amdgcn_s_setprio(1);
        quad<0, 2>(acc, af, bf);
        __builtin_amdgcn_s_setprio(0);
        BAR();
#pragma unroll
        for (int mt = 0; mt < 4; ++mt) {
            af[mt][0] = *(const bf16x8*)&Ac[(rA + 64 + mt * 16) * 64 + sw0];
            af[mt][1] = *(const bf16x8*)&Ac[(rA + 64 + mt * 16) * 64 + sw1];
        }
        BAR(); LGKM0_SB();
        __builtin_amdgcn_s_setprio(1);
        quad<4, 0>(acc, af, bf);
        __builtin_amdgcn_s_setprio(0);
        BAR();
        __builtin_amdgcn_s_setprio(1);
        quad<4, 2>(acc, af, bf);
        __builtin_amdgcn_s_setprio(0);
        if (pre) { VMCNT(0); }
        BAR();
    }
#undef ISSA
#undef ISSB

    const int cn = r15, rg = kq16 << 2;
#pragma unroll
    for (int mt = 0; mt < 8; ++mt) {
        int mrow = m0 + wm * 128 + mt * 16 + rg;
#pragma unroll
        for (int nt = 0; nt < 4; ++nt) {
            int ncol = n0 + wn * 64 + nt * 16 + cn;
            float bv = bias ? bias[ncol] : 0.f;
#pragma unroll
            for (int r = 0; r < 4; ++r) {
                float v = acc[mt][nt][r] + bv;
                if (sizeof(TO) == 2) ((ushortT*)out)[(size_t)(mrow + r) * N + ncol] = f2bf(v);
                else                 ((float*)out)[(size_t)(mrow + r) * N + ncol] = v;
            }
        }
    }
}

// ============ agent tokens: 8x8 mean pool of q; 784 blocks, LDS reduce ============
__global__ __launch_bounds__(256)
void agent_pool(const ushortT* __restrict__ qkv, float* __restrict__ at) {
    __shared__ float red[256][9];
    int t = threadIdx.x;
    int ba = blockIdx.x;                 // 784 = 16*49
    int b = ba / AG, a = ba % AG;
    int c8 = (t & 63) << 3, qr = t >> 6;
    int p1 = a / 7, p2 = a % 7;
    float s[8] = {};
#pragma unroll
    for (int pp = 0; pp < 16; ++pp) {
        int pos = (qr << 4) + pp;
        int i = (p1 * 8 + (pos >> 3)) * 56 + p2 * 8 + (pos & 7);
        bf16x8 u = *(const bf16x8*)&qkv[(size_t)(b * Nn + i) * 1536 + c8];
#pragma unroll
        for (int j = 0; j < 8; ++j) s[j] += bf2f((ushortT)u[j]);
    }
#pragma unroll
    for (int j = 0; j < 8; ++j) red[t][j] = s[j];
    __syncthreads();
    if (t < 64) {
        float* o = &at[((size_t)(b * AG + a) << 9) + (t << 3)];
#pragma unroll
        for (int j = 0; j < 8; ++j)
            o[j] = (red[t][j] + red[t + 64][j] + red[t + 128][j] + red[t + 192][j])
                   * (1.f / 64.f);
    }
}

// ============ bilinear 7->56 biases, bf16 out (b1 + b2 in one launch) ============
__device__ inline float bilin7(const float* __restrict__ p, int y, int x) {
    float fy = fminf(fmaxf(y * 0.125f - 0.4375f, 0.f), 6.f);
    float fx = fminf(fmaxf(x * 0.125f - 0.4375f, 0.f), 6.f);
    int y0 = (int)fy; float ty = fy - y0; int y1 = min(y0 + 1, 6);
    int x0 = (int)fx; float tx = fx - x0; int x1 = min(x0 + 1, 6);
    float v00 = p[y0 * 7 + x0], v01 = p[y0 * 7 + x1];
    float v10 = p[y1 * 7 + x0], v11 = p[y1 * 7 + x1];
    return (1.f - ty) * ((1.f - tx) * v00 + tx * v01) + ty * ((1.f - tx) * v10 + tx * v11);
}

__global__ void bias_k(const float* __restrict__ an, const float* __restrict__ ahb,
                       const float* __restrict__ awb, const float* __restrict__ na,
                       const float* __restrict__ hab, const float* __restrict__ wab,
                       ushortT* __restrict__ b1, ushortT* __restrict__ b2) {
    int g = blockIdx.x * 256 + threadIdx.x;
    const int NT = HEADS * AG * Nn;
    if (g < NT) {                         // b1 [h][a][i]
        int i = g % Nn; int a = (g / Nn) % AG; int h = g / (AG * Nn);
        int y = i / 56, x = i % 56;
        b1[g] = f2bf(bilin7(an + (h * AG + a) * 49, y, x)
                     + ahb[(h * AG + a) * 56 + y] + awb[(h * AG + a) * 56 + x]);
    } else {
        g -= NT; if (g >= NT) return;     // b2 [h][i][a]
        int a = g % AG; int i = (g / AG) % Nn; int h = g / (AG * Nn);
        int y = i / 56, x = i % 56;
        b2[g] = f2bf(bilin7(na + (h * AG + a) * 49, y, x)
                     + hab[(h * 56 + y) * AG + a] + wab[(h * 56 + x) * AG + a]);
    }
}

__global__ void zero2(float* __restrict__ num, int n1, float* __restrict__ den, int n2) {
    int g = blockIdx.x * 256 + threadIdx.x;
    if (g < n1) num[g] = 0.f;
    else if (g - n1 < n2) den[g - n1] = 0.f;
}

// ============ FUSED agent attention: num/den accumulation (no-max softmax) ======
__global__ __launch_bounds__(256)
void agent_av_fused(const ushortT* __restrict__ qkv, const float* __restrict__ at,
                    const ushortT* __restrict__ b1, float* __restrict__ num,
                    float* __restrict__ den) {
    __shared__ __align__(16) ushortT ah_s[64 * 72];
    __shared__ __align__(16) ushortT vt[64 * 72];    // vT[d][i] for current chunk
    __shared__ __align__(16) ushortT p_s[64 * 72];   // P[a][i] bf16 for current chunk
    const int t = threadIdx.x, lane = t & 63, wid = t >> 6;
    const int bh = blockIdx.y, b = bh >> 3, h = bh & 7;
    for (int idx = t; idx < 512; idx += 256) {
        int a = idx >> 3, d8 = (idx & 7) << 3;
        bf16x8 tmp;
        if (a < AG) {
            const float* p = &at[((size_t)(b * AG + a) << 9) + (h << 6) + d8];
#pragma unroll
            for (int j = 0; j < 8; ++j) tmp[j] = (short)f2bf(p[j] * 0.125f);
        } else {
#pragma unroll
            for (int j = 0; j < 8; ++j) tmp[j] = 0;
        }
        *(bf16x8*)&ah_s[a * 72 + d8] = tmp;
    }
    __syncthreads();
    const int r15 = lane & 15, kq = (lane >> 4) << 3;
    const int rbase = (lane >> 4) << 2;
    bf16x8 af[4][2];
#pragma unroll
    for (int mt = 0; mt < 4; ++mt)
#pragma unroll
        for (int ks = 0; ks < 2; ++ks)
            af[mt][ks] = *(const bf16x8*)&ah_s[(mt * 16 + r15) * 72 + ks * 32 + kq];

    f32x4 accn[4];
#pragma unroll
    for (int nt = 0; nt < 4; ++nt) accn[nt] = fzero4();
    float denl[4][4];
#pragma unroll
    for (int mt = 0; mt < 4; ++mt)
#pragma unroll
        for (int r = 0; r < 4; ++r) denl[mt][r] = 0.f;

    const int i0b = blockIdx.x * 448;
    const int svi = t >> 2, svd = (t & 3) << 4;
    for (int cc = 0; cc < 7; ++cc) {
        const int i0 = i0b + cc * 64;
        {
            const ushortT* vp = &qkv[(size_t)(b * Nn + i0 + svi) * 1536 + 1024 + (h << 6) + svd];
            bf16x8 u0 = *(const bf16x8*)vp;
            bf16x8 u1 = *(const bf16x8*)(vp + 8);
#pragma unroll
            for (int j = 0; j < 8; ++j) {
                vt[(svd + j) * 72 + svi]     = (ushortT)u0[j];
                vt[(svd + 8 + j) * 72 + svi] = (ushortT)u1[j];
            }
        }
        {
            const int iw = i0 + wid * 16;
            const ushortT* kp = &qkv[(size_t)(b * Nn + iw + r15) * 1536 + 512 + (h << 6) + kq];
            bf16x8 bk0 = *(const bf16x8*)kp;
            bf16x8 bk1 = *(const bf16x8*)(kp + 32);
            f32x4 sacc[4];
#pragma unroll
            for (int mt = 0; mt < 4; ++mt) {
                sacc[mt] = MFMA16(af[mt][0], bk0, fzero4());
                sacc[mt] = MFMA16(af[mt][1], bk1, sacc[mt]);
            }
            const int ic = iw + r15;
#pragma unroll
            for (int mt = 0; mt < 4; ++mt)
#pragma unroll
                for (int r = 0; r < 4; ++r) {
                    int a = mt * 16 + rbase + r;
                    float e = 0.f;
                    if (a < AG)
                        e = __expf(sacc[mt][r] + bf2f(b1[(size_t)(h * AG + a) * Nn + ic]));
                    denl[mt][r] += e;
                    p_s[a * 72 + wid * 16 + r15] = f2bf(e);
                }
        }
        __syncthreads();
        {
            bf16x8 ap0 = *(const bf16x8*)&p_s[(wid * 16 + r15) * 72 + kq];
            bf16x8 ap1 = *(const bf16x8*)&p_s[(wid * 16 + r15) * 72 + 32 + kq];
#pragma unroll
            for (int nt = 0; nt < 4; ++nt) {
                bf16x8 bv0 = *(const bf16x8*)&vt[(nt * 16 + r15) * 72 + kq];
                bf16x8 bv1 = *(const bf16x8*)&vt[(nt * 16 + r15) * 72 + 32 + kq];
                accn[nt] = MFMA16(ap0, bv0, accn[nt]);
                accn[nt] = MFMA16(ap1, bv1, accn[nt]);
            }
        }
        __syncthreads();
    }
#pragma unroll
    for (int r = 0; r < 4; ++r) {
        int a = wid * 16 + rbase + r;
        if (a < AG) {
#pragma unroll
            for (int nt = 0; nt < 4; ++nt)
                atomicAdd(&num[((size_t)(bh * AG + a) << 6) + nt * 16 + r15],
                          accn[nt][r]);
        }
    }
#pragma unroll
    for (int mt = 0; mt < 4; ++mt)
#pragma unroll
        for (int r = 0; r < 4; ++r) {
            float s = denl[mt][r];
#pragma unroll
            for (int off = 8; off >= 1; off >>= 1) s += __shfl_xor(s, off);
            if (r15 == 0) {
                int a = mt * 16 + rbase + r;
                if (a < AG) atomicAdd(&den[bh * AG + a], s);
            }
        }
}

// ============ fused q-attention via MFMA: QK^T -> reg softmax (no max) -> P·av ======
__global__ __launch_bounds__(256)
void q_attn_mfma(const ushortT* __restrict__ qkv, const float* __restrict__ at,
                 const float* __restrict__ num, const float* __restrict__ den,
                 const ushortT* __restrict__ b2, ushortT* __restrict__ attn) {
    __shared__ __align__(16) ushortT ah_s[64 * 72];
    __shared__ __align__(16) ushortT avT[64 * 72];
    __shared__ __align__(16) ushortT p_s[4][16 * 72];
    int t = threadIdx.x, lane = t & 63, wid = t >> 6;
    int bh = blockIdx.y, b = bh >> 3, h = bh & 7;
    for (int idx = t; idx < 512; idx += 256) {
        int a = idx >> 3, d8 = (idx & 7) << 3;
        bf16x8 tmp;
        if (a < AG) {
            const float* p = &at[((size_t)(b * AG + a) << 9) + (h << 6) + d8];
#pragma unroll
            for (int j = 0; j < 8; ++j) tmp[j] = (short)f2bf(p[j] * 0.125f);
        } else {
#pragma unroll
            for (int j = 0; j < 8; ++j) tmp[j] = 0;
        }
        *(bf16x8*)&ah_s[a * 72 + d8] = tmp;
    }
    for (int idx = t; idx < 4096; idx += 256) {     // avT[d][a] <- num[a][d]/den[a]
        int a = idx >> 6, d = idx & 63;
        float v = 0.f;
        if (a < AG)
            v = num[((size_t)(bh * AG + a) << 6) + d] / den[bh * AG + a];
        avT[d * 72 + a] = f2bf(v);
    }
    __syncthreads();
    int r15 = lane & 15, kq = (lane >> 4) << 3;
    bf16x8 bah[4][2], bav[4][2];
#pragma unroll
    for (int nt = 0; nt < 4; ++nt)
#pragma unroll
        for (int ks = 0; ks < 2; ++ks) {
            bah[nt][ks] = *(const bf16x8*)&ah_s[(nt * 16 + r15) * 72 + ks * 32 + kq];
            bav[nt][ks] = *(const bf16x8*)&avT[(nt * 16 + r15) * 72 + ks * 32 + kq];
        }
    ushortT* psw = p_s[wid];
    int i0b = blockIdx.x * 448;
    int rbase = (lane >> 4) << 2;
    for (int tt = 0; tt < 7; ++tt) {
        int i0 = i0b + (wid * 7 + tt) * 16;
        const ushortT* qp = &qkv[(size_t)(b * Nn + i0 + r15) * 1536 + (h << 6) + kq];
        bf16x8 aq0 = *(const bf16x8*)qp;
        bf16x8 aq1 = *(const bf16x8*)(qp + 32);
        f32x4 lg[4];
#pragma unroll
        for (int nt = 0; nt < 4; ++nt) {
            lg[nt] = MFMA16(aq0, bah[nt][0], fzero4());
            lg[nt] = MFMA16(aq1, bah[nt][1], lg[nt]);
        }
        float p4[4][4];   // [nt][r]
#pragma unroll
        for (int r = 0; r < 4; ++r) {
            int i = i0 + rbase + r;
            float vals[4]; float sm = 0.f;
#pragma unroll
            for (int nt = 0; nt < 4; ++nt) {
                int a = nt * 16 + r15;
                float e = 0.f;
                if (a < AG)
                    e = __expf(lg[nt][r] + bf2f(b2[(size_t)(h * Nn + i) * AG + a]));
                vals[nt] = e; sm += e;
            }
#pragma unroll
            for (int off = 8; off >= 1; off >>= 1) sm += __shfl_xor(sm, off);
            float inv = 1.f / sm;
#pragma unroll
            for (int nt = 0; nt < 4; ++nt) p4[nt][r] = vals[nt] * inv;
        }
#pragma unroll
        for (int nt = 0; nt < 4; ++nt)
#pragma unroll
            for (int r = 0; r < 4; ++r)
                psw[(rbase + r) * 72 + nt * 16 + r15] = f2bf(p4[nt][r]);
        bf16x8 ap0 = *(const bf16x8*)&psw[r15 * 72 + kq];
        bf16x8 ap1 = *(const bf16x8*)&psw[r15 * 72 + 32 + kq];
        f32x4 ov[4];
#pragma unroll
        for (int nt = 0; nt < 4; ++nt) {
            ov[nt] = MFMA16(ap0, bav[nt][0], fzero4());
            ov[nt] = MFMA16(ap1, bav[nt][1], ov[nt]);
        }
#pragma unroll
        for (int r = 0; r < 4; ++r) {
            int i = i0 + rbase + r;
            ushortT* op = &attn[(size_t)(b * Nn + i) * C_ + (h << 6)];
#pragma unroll
            for (int nt = 0; nt < 4; ++nt)
                op[nt * 16 + r15] = f2bf(ov[nt][r]);
        }
    }
}

// ============ depthwise 3x3 conv on v, added into attn; 8 channels/thread ============
__global__ void dwc_add_v(const ushortT* __restrict__ qkv, const float* __restrict__ wT,
                          const float* __restrict__ bb, ushortT* __restrict__ attn) {
    int g = blockIdx.x * 256 + threadIdx.x;   // B*Nn*64
    int c8 = (g & 63) << 3;
    int bi = g >> 6;
    int i = bi % Nn;
    int y = i / 56, x = i % 56;
    float acc[8];
    {
        float4 b0 = *(const float4*)&bb[c8];
        float4 b1 = *(const float4*)&bb[c8 + 4];
        acc[0] = b0.x; acc[1] = b0.y; acc[2] = b0.z; acc[3] = b0.w;
        acc[4] = b1.x; acc[5] = b1.y; acc[6] = b1.z; acc[7] = b1.w;
    }
#pragma unroll
    for (int dy = -1; dy <= 1; ++dy) {
        int yy = y + dy; if (yy < 0 || yy > 55) continue;
#pragma unroll
        for (int dx = -1; dx <= 1; ++dx) {
            int xx = x + dx; if (xx < 0 || xx > 55) continue;
            const ushortT* vp = &qkv[(size_t)(bi + dy * 56 + dx) * 1536 + 1024 + c8];
            ushort4 u0 = *(const ushort4*)vp;
            ushort4 u1 = *(const ushort4*)(vp + 4);
            const float* wp = &wT[((dy + 1) * 3 + dx + 1) * 512 + c8];
            float4 w0 = *(const float4*)wp;
            float4 w1 = *(const float4*)(wp + 4);
            acc[0] += bf2f(u0.x) * w0.x; acc[1] += bf2f(u0.y) * w0.y;
            acc[2] += bf2f(u0.z) * w0.z; acc[3] += bf2f(u0.w) * w0.w;
            acc[4] += bf2f(u1.x) * w1.x; acc[5] += bf2f(u1.y) * w1.y;
            acc[6] += bf2f(u1.z) * w1.z; acc[7] += bf2f(u1.w) * w1.w;
        }
    }
    ushortT* op = &attn[(size_t)bi * C_ + c8];
    ushort4 a0 = *(const ushort4*)op;
    ushort4 a1 = *(const ushort4*)(op + 4);
    ushort4 o0 = make_ushort4(f2bf(bf2f(a0.x) + acc[0]), f2bf(bf2f(a0.y) + acc[1]),
                              f2bf(bf2f(a0.z) + acc[2]), f2bf(bf2f(a0.w) + acc[3]));
    ushort4 o1 = make_ushort4(f2bf(bf2f(a1.x) + acc[4]), f2bf(bf2f(a1.y) + acc[5]),
                              f2bf(bf2f(a1.z) + acc[6]), f2bf(bf2f(a1.w) + acc[7]));
    *(ushort4*)op = o0; *(ushort4*)(op + 4) = o1;
}

extern "C" void kernel_launch(void* const* d_in, const int* in_sizes, int n_in,
                              void* d_out, int out_size, void* d_ws, size_t ws_size,
                              hipStream_t stream) {
    const float* x      = (const float*)d_in[0];
    const float* q_w    = (const float*)d_in[3];
    const float* kv_w   = (const float*)d_in[4];
    const float* proj_w = (const float*)d_in[5];
    const float* proj_b = (const float*)d_in[6];
    const float* dwc_w  = (const float*)d_in[7];
    const float* dwc_b  = (const float*)d_in[8];
    const float* an_b   = (const float*)d_in[9];
    const float* na_b   = (const float*)d_in[10];
    const float* ah_b   = (const float*)d_in[11];
    const float* aw_b   = (const float*)d_in[12];
    const float* ha_b   = (const float*)d_in[13];
    const float* wa_b   = (const float*)d_in[14];
    float* out = (float*)d_out;

    // ---- workspace layout (within 220,682,240 B); R region: attn only now ----
    char* ws = (char*)d_ws;
    ushortT* R    = (ushortT*)(ws);                 // 51,380,224 B
    ushortT* qkv  = (ushortT*)(ws + 51380224);      // 154,140,672 B
    ushortT* Wqkv = (ushortT*)(ws + 205520896);     // 1,572,864 B
    ushortT* Wp   = (ushortT*)(ws + 207093760);     // 524,288 B
    float*   wT   = (float*)(ws + 207618048);       // 18,432 B
    float*   at   = (float*)(ws + 207636480);       // 1,605,632 B
    ushortT* b1   = (ushortT*)(ws + 209242112);     // 2,458,624 B (bf16)
    ushortT* b2   = (ushortT*)(ws + 211700736);     // 2,458,624 B (bf16)
    float*   num  = (float*)(ws + 214159360);       // 1,605,632 B  [bh][49][64]
    float*   den  = (float*)(ws + 215764992);       // 25,088 B
    ushortT* attn = R;

    // 0) weight converts / repack (x conversion now fused into QKV GEMM)
    cvt_weights<<<1042, 256, 0, stream>>>(q_w, kv_w, proj_w, dwc_w, Wqkv, Wp, wT);
    // 1) QKV GEMM with fused fp32->bf16 A staging  M=50176 N=1536 K=512
    gemm_f32a<<<1176, 512, 0, stream>>>(x, Wqkv, qkv, 1536, 6);
    // 2) agent tokens
    agent_pool<<<784, 256, 0, stream>>>(qkv, at);
    // 3) position biases (bf16, one launch)
    bias_k<<<9604, 256, 0, stream>>>(an_b, ah_b, aw_b, na_b, ha_b, wa_b, b1, b2);
    // 4) fused agent attention (no-max softmax, associative accumulation)
    zero2<<<1593, 256, 0, stream>>>(num, B_ * HEADS * AG * HD, den, B_ * HEADS * AG);
    agent_av_fused<<<dim3(7, 128), 256, 0, stream>>>(qkv, at, b1, num, den);
    // 5) q attention (fused MFMA, no-max softmax, av=num/den)
    q_attn_mfma<<<dim3(7, 128), 256, 0, stream>>>(qkv, at, num, den, b2, attn);
    // 6) depthwise conv add
    dwc_add_v<<<12544, 256, 0, stream>>>(qkv, wT, dwc_b, attn);
    // 7) output projection (bf16 MFMA, fp32 out + bias)  M=50176 N=512 K=512
    gemm256<float><<<392, 512, 0, stream>>>(attn, Wp, proj_b, out, 512, 2);
}

// Round 6
// 518.751 us; speedup vs baseline: 1.3929x; 1.0068x over previous
//
#include <hip/hip_runtime.h>
#include <math.h>

#define B_ 16
#define C_ 512
#define Nn 3136
#define HEADS 8
#define HD 64
#define AG 49
#define Mrows (B_ * Nn)   // 50176

typedef unsigned short ushortT;
typedef __attribute__((ext_vector_type(8))) short bf16x8;
typedef __attribute__((ext_vector_type(4))) float f32x4;

#define MFMA16(a, b, c) __builtin_amdgcn_mfma_f32_16x16x32_bf16((a), (b), (c), 0, 0, 0)

__device__ inline float bf2f(ushortT u) { return __uint_as_float(((unsigned)u) << 16); }
__device__ inline ushortT f2bf(float f) {
    unsigned x = __float_as_uint(f);
    unsigned r = (x + 0x7fffu + ((x >> 16) & 1u)) >> 16;   // RNE
    return (ushortT)r;
}
__device__ inline f32x4 fzero4() { f32x4 z = {0.f, 0.f, 0.f, 0.f}; return z; }

// async global->LDS, 16B per lane; lds dest = wave-uniform base + lane*16
__device__ inline void gl_lds16(const ushortT* g, ushortT* l) {
    __builtin_amdgcn_global_load_lds(
        (const __attribute__((address_space(1))) void*)g,
        (__attribute__((address_space(3))) void*)l, 16, 0, 0);
}

#define VMCNT(n) asm volatile("s_waitcnt vmcnt(" #n ")" ::: "memory")
#define LGKM0_SB() { asm volatile("s_waitcnt lgkmcnt(0)" ::: "memory"); \
                     __builtin_amdgcn_sched_barrier(0); }
#define BAR() __builtin_amdgcn_s_barrier()

// ============ all weight converts + dwc repack in ONE launch ============
__global__ void cvt_weights(const float* __restrict__ qw, const float* __restrict__ kvw,
                            const float* __restrict__ pw, const float* __restrict__ dwcw,
                            ushortT* __restrict__ Wqkv, ushortT* __restrict__ Wp,
                            float* __restrict__ wT) {
    int g = blockIdx.x * 256 + threadIdx.x;
    if (g < 196608) {
        const float* src = (g < 65536) ? &qw[(size_t)g * 4] : &kvw[(size_t)(g - 65536) * 4];
        float4 v = *(const float4*)src;
        *(ushort4*)&Wqkv[(size_t)g * 4] =
            make_ushort4(f2bf(v.x), f2bf(v.y), f2bf(v.z), f2bf(v.w));
    } else if (g < 262144) {
        float4 v = *(const float4*)&pw[(size_t)(g - 196608) * 4];
        *(ushort4*)&Wp[(size_t)(g - 196608) * 4] =
            make_ushort4(f2bf(v.x), f2bf(v.y), f2bf(v.z), f2bf(v.w));
    } else {
        int gg = g - 262144;
        if (gg < 4608) { int c = gg & 511, tap = gg >> 9; wT[gg] = dwcw[c * 9 + tap]; }
    }
}

// one C-quadrant of the per-wave 128x64 tile: 4 m-frags x 2 n-frags x 2 k-slices
template <int MB, int NL>
__device__ __forceinline__ void quad(f32x4 (&acc)[8][4], const bf16x8 (&af)[4][2],
                                     const bf16x8 (&bf)[4][2]) {
#pragma unroll
    for (int m = 0; m < 4; ++m)
#pragma unroll
        for (int n = 0; n < 2; ++n) {
            acc[MB + m][NL + n] = MFMA16(af[m][0], bf[NL + n][0], acc[MB + m][NL + n]);
            acc[MB + m][NL + n] = MFMA16(af[m][1], bf[NL + n][1], acc[MB + m][NL + n]);
        }
}

// ============ QKV GEMM with fused fp32->bf16 A-conversion, K=512 (unchanged) ======
__global__ __launch_bounds__(512, 2)
void gemm_f32a(const float* __restrict__ A32, const ushortT* __restrict__ Bw,
               ushortT* __restrict__ out, int N, int nbn) {
    __shared__ __align__(16) ushortT As[2][16384];   // [buf][256 rows][64 k] bf16
    __shared__ __align__(16) ushortT Bs[2][16384];
    const int t = threadIdx.x, lane = t & 63, wid = t >> 6;
    const int chunk = (int)gridDim.x >> 3;
    const int id2 = ((int)blockIdx.x & 7) * chunk + ((int)blockIdx.x >> 3);
    const int by = id2 / nbn, bx = id2 - by * nbn;
    const int m0 = by * 256, n0 = bx * 256;
    const int wm = wid >> 2, wn = wid & 3;

    const int rl0 = t >> 3;
    const int kg = t & 7;
    const int wkg = kg ^ (rl0 & 7);
    const float* gAr = A32 + (size_t)(m0 + rl0) * 512 + kg * 8;
    const int dA0 = rl0 * 64 + wkg * 8;
    const int rb0 = (rl0 & 31) + ((rl0 >> 5) << 6);
    const int rb1 = rb0 + 128;
    const ushortT* gB0 = Bw + (size_t)(n0 + rb0) * 512 + wkg * 8;
    const ushortT* gB1 = Bw + (size_t)(n0 + rb1) * 512 + wkg * 8;
    const int gbu = ((wid * 8) & 31) + (((wid * 8) >> 5) << 6);
    const int bB0 = gbu * 64;
    const int bB1 = bB0 + 8192;

#define ISSB(bufi, ro, ko) { gl_lds16(gB0 + (ro) * 512 + (ko), &Bs[bufi][bB0 + (ro) * 64]); \
                             gl_lds16(gB1 + (ro) * 512 + (ko), &Bs[bufi][bB1 + (ro) * 64]); }
#define CVTW(bufi) { \
    _Pragma("unroll") \
    for (int j = 0; j < 4; ++j) { \
        bf16x8 w; \
        w[0]=(short)f2bf(pa[j][0].x); w[1]=(short)f2bf(pa[j][0].y); \
        w[2]=(short)f2bf(pa[j][0].z); w[3]=(short)f2bf(pa[j][0].w); \
        w[4]=(short)f2bf(pa[j][1].x); w[5]=(short)f2bf(pa[j][1].y); \
        w[6]=(short)f2bf(pa[j][1].z); w[7]=(short)f2bf(pa[j][1].w); \
        *(bf16x8*)&As[bufi][dA0 + j * 4096] = w; \
    } }

    f32x4 acc[8][4];
#pragma unroll
    for (int i = 0; i < 8; ++i)
#pragma unroll
        for (int j = 0; j < 4; ++j) acc[i][j] = fzero4();

    const int r15 = lane & 15, kq16 = lane >> 4;
    const int rA = wm * 128 + r15;
    const int rB = wn * 64 + r15;
    const int sw0 = ((kq16) ^ (r15 & 7)) << 3;
    const int sw1 = ((4 + kq16) ^ (r15 & 7)) << 3;

    float4 pa[4][2];
#pragma unroll
    for (int j = 0; j < 4; ++j) {
        const float* s = gAr + (size_t)j * 64 * 512;
        pa[j][0] = *(const float4*)s; pa[j][1] = *(const float4*)(s + 4);
    }
    ISSB(0, 0, 0); ISSB(0, 32, 0);
    CVTW(0);
    __syncthreads();

    bf16x8 af[4][2], bf[4][2];
    int cur = 0;
    for (int kt = 0; kt < 8; ++kt) {
        const ushortT* Ac = As[cur];
        const ushortT* Bc = Bs[cur];
        const int nb = cur ^ 1;
        const int ko = (kt + 1) * 64;
        const bool pre = (kt < 7);
        if (pre) {
#pragma unroll
            for (int j = 0; j < 4; ++j) {
                const float* s = gAr + (size_t)j * 64 * 512 + ko;
                pa[j][0] = *(const float4*)s; pa[j][1] = *(const float4*)(s + 4);
            }
            ISSB(nb, 0, ko); ISSB(nb, 32, ko);
        }
#pragma unroll
        for (int mt = 0; mt < 4; ++mt) {
            af[mt][0] = *(const bf16x8*)&Ac[(rA + mt * 16) * 64 + sw0];
            af[mt][1] = *(const bf16x8*)&Ac[(rA + mt * 16) * 64 + sw1];
        }
#pragma unroll
        for (int nt = 0; nt < 2; ++nt) {
            bf[nt][0] = *(const bf16x8*)&Bc[(rB + nt * 16) * 64 + sw0];
            bf[nt][1] = *(const bf16x8*)&Bc[(rB + nt * 16) * 64 + sw1];
        }
        __builtin_amdgcn_s_setprio(1);
        quad<0, 0>(acc, af, bf);
        __builtin_amdgcn_s_setprio(0);
#pragma unroll
        for (int nt = 2; nt < 4; ++nt) {
            bf[nt][0] = *(const bf16x8*)&Bc[(rB + nt * 16) * 64 + sw0];
            bf[nt][1] = *(const bf16x8*)&Bc[(rB + nt * 16) * 64 + sw1];
        }
        __builtin_amdgcn_s_setprio(1);
        quad<0, 2>(acc, af, bf);
        __builtin_amdgcn_s_setprio(0);
#pragma unroll
        for (int mt = 0; mt < 4; ++mt) {
            af[mt][0] = *(const bf16x8*)&Ac[(rA + 64 + mt * 16) * 64 + sw0];
            af[mt][1] = *(const bf16x8*)&Ac[(rA + 64 + mt * 16) * 64 + sw1];
        }
        __builtin_amdgcn_s_setprio(1);
        quad<4, 0>(acc, af, bf);
        quad<4, 2>(acc, af, bf);
        __builtin_amdgcn_s_setprio(0);
        if (pre) { CVTW(nb); }
        __syncthreads();
        cur ^= 1;
    }
#undef ISSB
#undef CVTW

    const int cn = r15, rg = kq16 << 2;
#pragma unroll
    for (int mt = 0; mt < 8; ++mt) {
        int mrow = m0 + wm * 128 + mt * 16 + rg;
#pragma unroll
        for (int nt = 0; nt < 4; ++nt) {
            int ncol = n0 + wn * 64 + nt * 16 + cn;
#pragma unroll
            for (int r = 0; r < 4; ++r)
                out[(size_t)(mrow + r) * N + ncol] = f2bf(acc[mt][nt][r]);
        }
    }
}

// ============ proj GEMM (bf16 A via DMA) — unchanged control ============
template <typename TO>
__global__ __launch_bounds__(512, 2)
void gemm256(const ushortT* __restrict__ A, const ushortT* __restrict__ Bw,
             const float* __restrict__ bias, TO* __restrict__ out,
             int N, int nbn) {
    __shared__ __align__(16) ushortT As[2][16384];
    __shared__ __align__(16) ushortT Bs[2][16384];
    const int t = threadIdx.x, lane = t & 63, wid = t >> 6;
    const int chunk = (int)gridDim.x >> 3;
    const int id2 = ((int)blockIdx.x & 7) * chunk + ((int)blockIdx.x >> 3);
    const int by = id2 / nbn, bx = id2 - by * nbn;
    const int m0 = by * 256, n0 = bx * 256;
    const int wm = wid >> 2, wn = wid & 3;

    const int rl0 = t >> 3;
    const int skg = (t & 7) ^ (rl0 & 7);
    const int ra0 = rl0 & 63;
    const int ra1 = (rl0 & 63) + 128;
    const int rb0 = (rl0 & 31) + ((rl0 >> 5) << 6);
    const int rb1 = rb0 + 128;
    const ushortT* gA0 = A + (size_t)(m0 + ra0) * 512 + skg * 8;
    const ushortT* gA1 = A + (size_t)(m0 + ra1) * 512 + skg * 8;
    const ushortT* gB0 = Bw + (size_t)(n0 + rb0) * 512 + skg * 8;
    const ushortT* gB1 = Bw + (size_t)(n0 + rb1) * 512 + skg * 8;
    const int bA0 = wid * 512;
    const int bA1 = wid * 512 + 8192;
    const int gbu = ((wid * 8) & 31) + (((wid * 8) >> 5) << 6);
    const int bB0 = gbu * 64;
    const int bB1 = bB0 + 8192;

#define ISSA(bufi, ro, ko) { gl_lds16(gA0 + (ro) * 512 + (ko), &As[bufi][bA0 + (ro) * 64]); \
                             gl_lds16(gA1 + (ro) * 512 + (ko), &As[bufi][bA1 + (ro) * 64]); }
#define ISSB(bufi, ro, ko) { gl_lds16(gB0 + (ro) * 512 + (ko), &Bs[bufi][bB0 + (ro) * 64]); \
                             gl_lds16(gB1 + (ro) * 512 + (ko), &Bs[bufi][bB1 + (ro) * 64]); }

    f32x4 acc[8][4];
#pragma unroll
    for (int i = 0; i < 8; ++i)
#pragma unroll
        for (int j = 0; j < 4; ++j) acc[i][j] = fzero4();

    const int r15 = lane & 15, kq16 = lane >> 4;
    const int rA = wm * 128 + r15;
    const int rB = wn * 64 + r15;
    const int sw0 = ((kq16) ^ (r15 & 7)) << 3;
    const int sw1 = ((4 + kq16) ^ (r15 & 7)) << 3;

    ISSA(0, 0, 0); ISSA(0, 64, 0);
    ISSB(0, 0, 0); ISSB(0, 32, 0);
    VMCNT(0);
    BAR();

    bf16x8 af[4][2], bf[4][2];
    for (int kt = 0; kt < 8; ++kt) {
        const ushortT* Ac = As[kt & 1];
        const ushortT* Bc = Bs[kt & 1];
        const int nb = (kt + 1) & 1;
        const int ko = (kt + 1) * 64;
        const bool pre = (kt < 7);
#pragma unroll
        for (int mt = 0; mt < 4; ++mt) {
            af[mt][0] = *(const bf16x8*)&Ac[(rA + mt * 16) * 64 + sw0];
            af[mt][1] = *(const bf16x8*)&Ac[(rA + mt * 16) * 64 + sw1];
        }
#pragma unroll
        for (int nt = 0; nt < 2; ++nt) {
            bf[nt][0] = *(const bf16x8*)&Bc[(rB + nt * 16) * 64 + sw0];
            bf[nt][1] = *(const bf16x8*)&Bc[(rB + nt * 16) * 64 + sw1];
        }
        if (pre) { ISSA(nb, 0, ko); ISSA(nb, 64, ko); }
        BAR(); LGKM0_SB();
        __builtin_amdgcn_s_setprio(1);
        quad<0, 0>(acc, af, bf);
        __builtin_amdgcn_s_setprio(0);
        BAR();
#pragma unroll
        for (int nt = 2; nt < 4; ++nt) {
            bf[nt][0] = *(const bf16x8*)&Bc[(rB + nt * 16) * 64 + sw0];
            bf[nt][1] = *(const bf16x8*)&Bc[(rB + nt * 16) * 64 + sw1];
        }
        if (pre) { ISSB(nb, 0, ko); ISSB(nb, 32, ko); }
        BAR(); LGKM0_SB();
        __builtin_amdgcn_s_setprio(1);
        quad<0, 2>(acc, af, bf);
        __builtin_amdgcn_s_setprio(0);
        BAR();
#pragma unroll
        for (int mt = 0; mt < 4; ++mt) {
            af[mt][0] = *(const bf16x8*)&Ac[(rA + 64 + mt * 16) * 64 + sw0];
            af[mt][1] = *(const bf16x8*)&Ac[(rA + 64 + mt * 16) * 64 + sw1];
        }
        BAR(); LGKM0_SB();
        __builtin_amdgcn_s_setprio(1);
        quad<4, 0>(acc, af, bf);
        __builtin_amdgcn_s_setprio(0);
        BAR();
        __builtin_amdgcn_s_setprio(1);
        quad<4, 2>(acc, af, bf);
        __builtin_amdgcn_s_setprio(0);
        if (pre) { VMCNT(0); }
        BAR();
    }
#undef ISSA
#undef ISSB

    const int cn = r15, rg = kq16 << 2;
#pragma unroll
    for (int mt = 0; mt < 8; ++mt) {
        int mrow = m0 + wm * 128 + mt * 16 + rg;
#pragma unroll
        for (int nt = 0; nt < 4; ++nt) {
            int ncol = n0 + wn * 64 + nt * 16 + cn;
            float bv = bias ? bias[ncol] : 0.f;
#pragma unroll
            for (int r = 0; r < 4; ++r) {
                float v = acc[mt][nt][r] + bv;
                if (sizeof(TO) == 2) ((ushortT*)out)[(size_t)(mrow + r) * N + ncol] = f2bf(v);
                else                 ((float*)out)[(size_t)(mrow + r) * N + ncol] = v;
            }
        }
    }
}

// ============ agent tokens: 8x8 mean pool of q -> PRE-SCALED bf16 (x0.125) ======
// at_bf[(b*AG+a)*512 + c] = f2bf(mean * 0.125); x(1/512) is exact pow2 scaling,
// single RNE round -> bit-identical to the old fp32-mean-then-scale path.
__global__ __launch_bounds__(256)
void agent_pool(const ushortT* __restrict__ qkv, ushortT* __restrict__ at) {
    __shared__ float red[256][9];
    int t = threadIdx.x;
    int ba = blockIdx.x;                 // 784 = 16*49
    int b = ba / AG, a = ba % AG;
    int c8 = (t & 63) << 3, qr = t >> 6;
    int p1 = a / 7, p2 = a % 7;
    float s[8] = {};
#pragma unroll
    for (int pp = 0; pp < 16; ++pp) {
        int pos = (qr << 4) + pp;
        int i = (p1 * 8 + (pos >> 3)) * 56 + p2 * 8 + (pos & 7);
        bf16x8 u = *(const bf16x8*)&qkv[(size_t)(b * Nn + i) * 1536 + c8];
#pragma unroll
        for (int j = 0; j < 8; ++j) s[j] += bf2f((ushortT)u[j]);
    }
#pragma unroll
    for (int j = 0; j < 8; ++j) red[t][j] = s[j];
    __syncthreads();
    if (t < 64) {
        ushortT* o = &at[((size_t)(b * AG + a) << 9) + (t << 3)];
#pragma unroll
        for (int j = 0; j < 8; ++j)
            o[j] = f2bf((red[t][j] + red[t + 64][j] + red[t + 128][j] + red[t + 192][j])
                        * (1.f / 512.f));
    }
}

// ============ bilinear 7->56 biases, bf16 out (b1 + b2 in one launch) ============
__device__ inline float bilin7(const float* __restrict__ p, int y, int x) {
    float fy = fminf(fmaxf(y * 0.125f - 0.4375f, 0.f), 6.f);
    float fx = fminf(fmaxf(x * 0.125f - 0.4375f, 0.f), 6.f);
    int y0 = (int)fy; float ty = fy - y0; int y1 = min(y0 + 1, 6);
    int x0 = (int)fx; float tx = fx - x0; int x1 = min(x0 + 1, 6);
    float v00 = p[y0 * 7 + x0], v01 = p[y0 * 7 + x1];
    float v10 = p[y1 * 7 + x0], v11 = p[y1 * 7 + x1];
    return (1.f - ty) * ((1.f - tx) * v00 + tx * v01) + ty * ((1.f - tx) * v10 + tx * v11);
}

__global__ void bias_k(const float* __restrict__ an, const float* __restrict__ ahb,
                       const float* __restrict__ awb, const float* __restrict__ na,
                       const float* __restrict__ hab, const float* __restrict__ wab,
                       ushortT* __restrict__ b1, ushortT* __restrict__ b2) {
    int g = blockIdx.x * 256 + threadIdx.x;
    const int NT = HEADS * AG * Nn;
    if (g < NT) {                         // b1 [h][a][i]
        int i = g % Nn; int a = (g / Nn) % AG; int h = g / (AG * Nn);
        int y = i / 56, x = i % 56;
        b1[g] = f2bf(bilin7(an + (h * AG + a) * 49, y, x)
                     + ahb[(h * AG + a) * 56 + y] + awb[(h * AG + a) * 56 + x]);
    } else {
        g -= NT; if (g >= NT) return;     // b2 [h][i][a]
        int a = g % AG; int i = (g / AG) % Nn; int h = g / (AG * Nn);
        int y = i / 56, x = i % 56;
        b2[g] = f2bf(bilin7(na + (h * AG + a) * 49, y, x)
                     + hab[(h * 56 + y) * AG + a] + wab[(h * 56 + x) * AG + a]);
    }
}

// ============ FUSED agent attention, ATOMIC-FREE partials ============
// grid (4,128): block (bx,bh) owns chunk range {0:[0,13) 1:[13,25) 2:[25,37) 3:[37,49)}
// (512 blocks = exactly 2 resident/CU, no tail). Plain stores:
//   num_p[((bx*128+bh)*AG+a)*64+d]  (each element written once)
//   den_p[(bx*128+bh)*64+a]         (LDS-reduced across the 4 waves)
// q_attn sums the 4 partials. No-max softmax as before (|logit| <~ 1.2).
__global__ __launch_bounds__(256)
void agent_av_fused(const ushortT* __restrict__ qkv, const ushortT* __restrict__ at,
                    const ushortT* __restrict__ b1, float* __restrict__ num_p,
                    float* __restrict__ den_p) {
    __shared__ __align__(16) ushortT ah_s[64 * 72];
    __shared__ __align__(16) ushortT vt[64 * 72];    // vT[d][i] for current chunk
    __shared__ __align__(16) ushortT p_s[64 * 72];   // P[a][i] bf16 for current chunk
    const int t = threadIdx.x, lane = t & 63, wid = t >> 6;
    const int bx = blockIdx.x, bh = blockIdx.y, b = bh >> 3, h = bh & 7;
    const int cs = bx ? (13 + 12 * (bx - 1)) : 0;
    const int ce = cs + (bx ? 12 : 13);
    for (int idx = t; idx < 512; idx += 256) {
        int a = idx >> 3, d8 = (idx & 7) << 3;
        bf16x8 tmp;
        if (a < AG) {
            tmp = *(const bf16x8*)&at[((size_t)(b * AG + a) << 9) + (h << 6) + d8];
        } else {
#pragma unroll
            for (int j = 0; j < 8; ++j) tmp[j] = 0;
        }
        *(bf16x8*)&ah_s[a * 72 + d8] = tmp;
    }
    __syncthreads();
    const int r15 = lane & 15, kq = (lane >> 4) << 3;
    const int rbase = (lane >> 4) << 2;
    bf16x8 af[4][2];
#pragma unroll
    for (int mt = 0; mt < 4; ++mt)
#pragma unroll
        for (int ks = 0; ks < 2; ++ks)
            af[mt][ks] = *(const bf16x8*)&ah_s[(mt * 16 + r15) * 72 + ks * 32 + kq];

    f32x4 accn[4];
#pragma unroll
    for (int nt = 0; nt < 4; ++nt) accn[nt] = fzero4();
    float denl[4][4];
#pragma unroll
    for (int mt = 0; mt < 4; ++mt)
#pragma unroll
        for (int r = 0; r < 4; ++r) denl[mt][r] = 0.f;

    const int svi = t >> 2, svd = (t & 3) << 4;
    for (int cc = cs; cc < ce; ++cc) {
        const int i0 = cc * 64;
        {
            const ushortT* vp = &qkv[(size_t)(b * Nn + i0 + svi) * 1536 + 1024 + (h << 6) + svd];
            bf16x8 u0 = *(const bf16x8*)vp;
            bf16x8 u1 = *(const bf16x8*)(vp + 8);
#pragma unroll
            for (int j = 0; j < 8; ++j) {
                vt[(svd + j) * 72 + svi]     = (ushortT)u0[j];
                vt[(svd + 8 + j) * 72 + svi] = (ushortT)u1[j];
            }
        }
        {
            const int iw = i0 + wid * 16;
            const ushortT* kp = &qkv[(size_t)(b * Nn + iw + r15) * 1536 + 512 + (h << 6) + kq];
            bf16x8 bk0 = *(const bf16x8*)kp;
            bf16x8 bk1 = *(const bf16x8*)(kp + 32);
            f32x4 sacc[4];
#pragma unroll
            for (int mt = 0; mt < 4; ++mt) {
                sacc[mt] = MFMA16(af[mt][0], bk0, fzero4());
                sacc[mt] = MFMA16(af[mt][1], bk1, sacc[mt]);
            }
            const int ic = iw + r15;
#pragma unroll
            for (int mt = 0; mt < 4; ++mt)
#pragma unroll
                for (int r = 0; r < 4; ++r) {
                    int a = mt * 16 + rbase + r;
                    float e = 0.f;
                    if (a < AG)
                        e = __expf(sacc[mt][r] + bf2f(b1[(size_t)(h * AG + a) * Nn + ic]));
                    denl[mt][r] += e;
                    p_s[a * 72 + wid * 16 + r15] = f2bf(e);
                }
        }
        __syncthreads();
        {
            bf16x8 ap0 = *(const bf16x8*)&p_s[(wid * 16 + r15) * 72 + kq];
            bf16x8 ap1 = *(const bf16x8*)&p_s[(wid * 16 + r15) * 72 + 32 + kq];
#pragma unroll
            for (int nt = 0; nt < 4; ++nt) {
                bf16x8 bv0 = *(const bf16x8*)&vt[(nt * 16 + r15) * 72 + kq];
                bf16x8 bv1 = *(const bf16x8*)&vt[(nt * 16 + r15) * 72 + 32 + kq];
                accn[nt] = MFMA16(ap0, bv0, accn[nt]);
                accn[nt] = MFMA16(ap1, bv1, accn[nt]);
            }
        }
        __syncthreads();
    }
    // ---- num partial: plain stores (a = 16*wid + rbase + r, d = nt*16 + r15)
#pragma unroll
    for (int r = 0; r < 4; ++r) {
        int a = wid * 16 + rbase + r;
        if (a < AG) {
#pragma unroll
            for (int nt = 0; nt < 4; ++nt)
                num_p[(((size_t)bx * 128 + bh) * AG + a) * 64 + nt * 16 + r15] =
                    accn[nt][r];
        }
    }
    // ---- den partial: shfl-reduce over i, LDS-reduce over waves, one store
    float* dsc = (float*)vt;   // safe: all vt reads drained by the loop's last barrier
#pragma unroll
    for (int mt = 0; mt < 4; ++mt)
#pragma unroll
        for (int r = 0; r < 4; ++r) {
            float s = denl[mt][r];
#pragma unroll
            for (int off = 8; off >= 1; off >>= 1) s += __shfl_xor(s, off);
            if (r15 == 0) dsc[wid * 64 + mt * 16 + rbase + r] = s;
        }
    __syncthreads();
    if (t < 64)
        den_p[((size_t)bx * 128 + bh) * 64 + t] =
            dsc[t] + dsc[64 + t] + dsc[128 + t] + dsc[192 + t];
}

// ============ fused q-attention: QK^T -> reg softmax (no max) -> P·av ============
// av = (sum of 4 num partials) / (sum of 4 den partials), folded into avT staging.
__global__ __launch_bounds__(256)
void q_attn_mfma(const ushortT* __restrict__ qkv, const ushortT* __restrict__ at,
                 const float* __restrict__ num_p, const float* __restrict__ den_p,
                 const ushortT* __restrict__ b2, ushortT* __restrict__ attn) {
    __shared__ __align__(16) ushortT ah_s[64 * 72];
    __shared__ __align__(16) ushortT avT[64 * 72];
    __shared__ __align__(16) ushortT p_s[4][16 * 72];
    __shared__ float den_s[64];
    int t = threadIdx.x, lane = t & 63, wid = t >> 6;
    int bh = blockIdx.y, b = bh >> 3, h = bh & 7;
    for (int idx = t; idx < 512; idx += 256) {
        int a = idx >> 3, d8 = (idx & 7) << 3;
        bf16x8 tmp;
        if (a < AG) {
            tmp = *(const bf16x8*)&at[((size_t)(b * AG + a) << 9) + (h << 6) + d8];
        } else {
#pragma unroll
            for (int j = 0; j < 8; ++j) tmp[j] = 0;
        }
        *(bf16x8*)&ah_s[a * 72 + d8] = tmp;
    }
    if (t < 64) {
        den_s[t] = den_p[((size_t)0 * 128 + bh) * 64 + t]
                 + den_p[((size_t)1 * 128 + bh) * 64 + t]
                 + den_p[((size_t)2 * 128 + bh) * 64 + t]
                 + den_p[((size_t)3 * 128 + bh) * 64 + t];
    }
    __syncthreads();
    for (int idx = t; idx < 4096; idx += 256) {     // avT[d][a] <- (sum num_p)/den
        int a = idx >> 6, d = idx & 63;
        float v = 0.f;
        if (a < AG) {
            float s = num_p[(((size_t)0 * 128 + bh) * AG + a) * 64 + d]
                    + num_p[(((size_t)1 * 128 + bh) * AG + a) * 64 + d]
                    + num_p[(((size_t)2 * 128 + bh) * AG + a) * 64 + d]
                    + num_p[(((size_t)3 * 128 + bh) * AG + a) * 64 + d];
            v = s / den_s[a];
        }
        avT[d * 72 + a] = f2bf(v);
    }
    __syncthreads();
    int r15 = lane & 15, kq = (lane >> 4) << 3;
    bf16x8 bah[4][2], bav[4][2];
#pragma unroll
    for (int nt = 0; nt < 4; ++nt)
#pragma unroll
        for (int ks = 0; ks < 2; ++ks) {
            bah[nt][ks] = *(const bf16x8*)&ah_s[(nt * 16 + r15) * 72 + ks * 32 + kq];
            bav[nt][ks] = *(const bf16x8*)&avT[(nt * 16 + r15) * 72 + ks * 32 + kq];
        }
    ushortT* psw = p_s[wid];
    int i0b = blockIdx.x * 448;
    int rbase = (lane >> 4) << 2;
    for (int tt = 0; tt < 7; ++tt) {
        int i0 = i0b + (wid * 7 + tt) * 16;
        const ushortT* qp = &qkv[(size_t)(b * Nn + i0 + r15) * 1536 + (h << 6) + kq];
        bf16x8 aq0 = *(const bf16x8*)qp;
        bf16x8 aq1 = *(const bf16x8*)(qp + 32);
        f32x4 lg[4];
#pragma unroll
        for (int nt = 0; nt < 4; ++nt) {
            lg[nt] = MFMA16(aq0, bah[nt][0], fzero4());
            lg[nt] = MFMA16(aq1, bah[nt][1], lg[nt]);
        }
        float p4[4][4];   // [nt][r]
#pragma unroll
        for (int r = 0; r < 4; ++r) {
            int i = i0 + rbase + r;
            float vals[4]; float sm = 0.f;
#pragma unroll
            for (int nt = 0; nt < 4; ++nt) {
                int a = nt * 16 + r15;
                float e = 0.f;
                if (a < AG)
                    e = __expf(lg[nt][r] + bf2f(b2[(size_t)(h * Nn + i) * AG + a]));
                vals[nt] = e; sm += e;
            }
#pragma unroll
            for (int off = 8; off >= 1; off >>= 1) sm += __shfl_xor(sm, off);
            float inv = 1.f / sm;
#pragma unroll
            for (int nt = 0; nt < 4; ++nt) p4[nt][r] = vals[nt] * inv;
        }
#pragma unroll
        for (int nt = 0; nt < 4; ++nt)
#pragma unroll
            for (int r = 0; r < 4; ++r)
                psw[(rbase + r) * 72 + nt * 16 + r15] = f2bf(p4[nt][r]);
        bf16x8 ap0 = *(const bf16x8*)&psw[r15 * 72 + kq];
        bf16x8 ap1 = *(const bf16x8*)&psw[r15 * 72 + 32 + kq];
        f32x4 ov[4];
#pragma unroll
        for (int nt = 0; nt < 4; ++nt) {
            ov[nt] = MFMA16(ap0, bav[nt][0], fzero4());
            ov[nt] = MFMA16(ap1, bav[nt][1], ov[nt]);
        }
#pragma unroll
        for (int r = 0; r < 4; ++r) {
            int i = i0 + rbase + r;
            ushortT* op = &attn[(size_t)(b * Nn + i) * C_ + (h << 6)];
#pragma unroll
            for (int nt = 0; nt < 4; ++nt)
                op[nt * 16 + r15] = f2bf(ov[nt][r]);
        }
    }
}

// ============ depthwise 3x3 conv on v, added into attn; 8 channels/thread ============
__global__ void dwc_add_v(const ushortT* __restrict__ qkv, const float* __restrict__ wT,
                          const float* __restrict__ bb, ushortT* __restrict__ attn) {
    int g = blockIdx.x * 256 + threadIdx.x;   // B*Nn*64
    int c8 = (g & 63) << 3;
    int bi = g >> 6;
    int i = bi % Nn;
    int y = i / 56, x = i % 56;
    float acc[8];
    {
        float4 b0 = *(const float4*)&bb[c8];
        float4 b1 = *(const float4*)&bb[c8 + 4];
        acc[0] = b0.x; acc[1] = b0.y; acc[2] = b0.z; acc[3] = b0.w;
        acc[4] = b1.x; acc[5] = b1.y; acc[6] = b1.z; acc[7] = b1.w;
    }
#pragma unroll
    for (int dy = -1; dy <= 1; ++dy) {
        int yy = y + dy; if (yy < 0 || yy > 55) continue;
#pragma unroll
        for (int dx = -1; dx <= 1; ++dx) {
            int xx = x + dx; if (xx < 0 || xx > 55) continue;
            const ushortT* vp = &qkv[(size_t)(bi + dy * 56 + dx) * 1536 + 1024 + c8];
            ushort4 u0 = *(const ushort4*)vp;
            ushort4 u1 = *(const ushort4*)(vp + 4);
            const float* wp = &wT[((dy + 1) * 3 + dx + 1) * 512 + c8];
            float4 w0 = *(const float4*)wp;
            float4 w1 = *(const float4*)(wp + 4);
            acc[0] += bf2f(u0.x) * w0.x; acc[1] += bf2f(u0.y) * w0.y;
            acc[2] += bf2f(u0.z) * w0.z; acc[3] += bf2f(u0.w) * w0.w;
            acc[4] += bf2f(u1.x) * w1.x; acc[5] += bf2f(u1.y) * w1.y;
            acc[6] += bf2f(u1.z) * w1.z; acc[7] += bf2f(u1.w) * w1.w;
        }
    }
    ushortT* op = &attn[(size_t)bi * C_ + c8];
    ushort4 a0 = *(const ushort4*)op;
    ushort4 a1 = *(const ushort4*)(op + 4);
    ushort4 o0 = make_ushort4(f2bf(bf2f(a0.x) + acc[0]), f2bf(bf2f(a0.y) + acc[1]),
                              f2bf(bf2f(a0.z) + acc[2]), f2bf(bf2f(a0.w) + acc[3]));
    ushort4 o1 = make_ushort4(f2bf(bf2f(a1.x) + acc[4]), f2bf(bf2f(a1.y) + acc[5]),
                              f2bf(bf2f(a1.z) + acc[6]), f2bf(bf2f(a1.w) + acc[7]));
    *(ushort4*)op = o0; *(ushort4*)(op + 4) = o1;
}

extern "C" void kernel_launch(void* const* d_in, const int* in_sizes, int n_in,
                              void* d_out, int out_size, void* d_ws, size_t ws_size,
                              hipStream_t stream) {
    const float* x      = (const float*)d_in[0];
    const float* q_w    = (const float*)d_in[3];
    const float* kv_w   = (const float*)d_in[4];
    const float* proj_w = (const float*)d_in[5];
    const float* proj_b = (const float*)d_in[6];
    const float* dwc_w  = (const float*)d_in[7];
    const float* dwc_b  = (const float*)d_in[8];
    const float* an_b   = (const float*)d_in[9];
    const float* na_b   = (const float*)d_in[10];
    const float* ah_b   = (const float*)d_in[11];
    const float* aw_b   = (const float*)d_in[12];
    const float* ha_b   = (const float*)d_in[13];
    const float* wa_b   = (const float*)d_in[14];
    float* out = (float*)d_out;

    // ---- workspace layout (219,910,144 B used; under the proven 220,682,240) ----
    char* ws = (char*)d_ws;
    ushortT* attn  = (ushortT*)(ws);                 // 51,380,224 B
    ushortT* qkv   = (ushortT*)(ws + 51380224);      // 154,140,672 B
    ushortT* Wqkv  = (ushortT*)(ws + 205520896);     // 1,572,864 B
    ushortT* Wp    = (ushortT*)(ws + 207093760);     // 524,288 B
    float*   wT    = (float*)(ws + 207618048);       // 18,432 B
    ushortT* at    = (ushortT*)(ws + 207636480);     // 802,816 B (bf16, pre-scaled)
    ushortT* b1    = (ushortT*)(ws + 208439296);     // 2,458,624 B (bf16)
    ushortT* b2    = (ushortT*)(ws + 210897920);     // 2,458,624 B (bf16)
    float*   num_p = (float*)(ws + 213356544);       // 6,422,528 B  [4][128][49][64]
    float*   den_p = (float*)(ws + 219779072);       // 131,072 B    [4][128][64]

    // 0) weight converts / repack
    cvt_weights<<<1042, 256, 0, stream>>>(q_w, kv_w, proj_w, dwc_w, Wqkv, Wp, wT);
    // 1) QKV GEMM with fused fp32->bf16 A staging  M=50176 N=1536 K=512
    gemm_f32a<<<1176, 512, 0, stream>>>(x, Wqkv, qkv, 1536, 6);
    // 2) agent tokens (pre-scaled bf16)
    agent_pool<<<784, 256, 0, stream>>>(qkv, at);
    // 3) position biases (bf16, one launch)
    bias_k<<<9604, 256, 0, stream>>>(an_b, ah_b, aw_b, na_b, ha_b, wa_b, b1, b2);
    // 4) fused agent attention — atomic-free partials, 2 blocks/CU exact
    agent_av_fused<<<dim3(4, 128), 256, 0, stream>>>(qkv, at, b1, num_p, den_p);
    // 5) q attention (sums the 4 partials during staging)
    q_attn_mfma<<<dim3(7, 128), 256, 0, stream>>>(qkv, at, num_p, den_p, b2, attn);
    // 6) depthwise conv add
    dwc_add_v<<<12544, 256, 0, stream>>>(qkv, wT, dwc_b, attn);
    // 7) output projection (bf16 MFMA, fp32 out + bias)  M=50176 N=512 K=512
    gemm256<float><<<392, 512, 0, stream>>>(attn, Wp, proj_b, out, 512, 2);
}

// Round 7
// 496.895 us; speedup vs baseline: 1.4541x; 1.0440x over previous
//
#include <hip/hip_runtime.h>
#include <math.h>

#define B_ 16
#define C_ 512
#define Nn 3136
#define HEADS 8
#define HD 64
#define AG 49
#define Mrows (B_ * Nn)   // 50176

typedef unsigned short ushortT;
typedef __attribute__((ext_vector_type(8))) short bf16x8;
typedef __attribute__((ext_vector_type(4))) float f32x4;

#define MFMA16(a, b, c) __builtin_amdgcn_mfma_f32_16x16x32_bf16((a), (b), (c), 0, 0, 0)

__device__ inline float bf2f(ushortT u) { return __uint_as_float(((unsigned)u) << 16); }
__device__ inline ushortT f2bf(float f) {
    unsigned x = __float_as_uint(f);
    unsigned r = (x + 0x7fffu + ((x >> 16) & 1u)) >> 16;   // RNE
    return (ushortT)r;
}
__device__ inline f32x4 fzero4() { f32x4 z = {0.f, 0.f, 0.f, 0.f}; return z; }

// async global->LDS, 16B per lane; lds dest = wave-uniform base + lane*16
__device__ inline void gl_lds16(const ushortT* g, ushortT* l) {
    __builtin_amdgcn_global_load_lds(
        (const __attribute__((address_space(1))) void*)g,
        (__attribute__((address_space(3))) void*)l, 16, 0, 0);
}

#define VMCNT(n) asm volatile("s_waitcnt vmcnt(" #n ")" ::: "memory")
#define BAR() __builtin_amdgcn_s_barrier()

// ============ fp32 -> bf16 elementwise (x) — standalone again (BW-bound ~50us) ======
__global__ void cvt_f2b4(const float* __restrict__ src, ushortT* __restrict__ dst, int n4) {
    int g = blockIdx.x * 256 + threadIdx.x;
    if (g >= n4) return;
    float4 v = *(const float4*)&src[(size_t)g * 4];
    ushort4 o = make_ushort4(f2bf(v.x), f2bf(v.y), f2bf(v.z), f2bf(v.w));
    *(ushort4*)&dst[(size_t)g * 4] = o;
}

// ============ all weight converts + dwc repack in ONE launch ============
__global__ void cvt_weights(const float* __restrict__ qw, const float* __restrict__ kvw,
                            const float* __restrict__ pw, const float* __restrict__ dwcw,
                            ushortT* __restrict__ Wqkv, ushortT* __restrict__ Wp,
                            float* __restrict__ wT) {
    int g = blockIdx.x * 256 + threadIdx.x;
    if (g < 196608) {
        const float* src = (g < 65536) ? &qw[(size_t)g * 4] : &kvw[(size_t)(g - 65536) * 4];
        float4 v = *(const float4*)src;
        *(ushort4*)&Wqkv[(size_t)g * 4] =
            make_ushort4(f2bf(v.x), f2bf(v.y), f2bf(v.z), f2bf(v.w));
    } else if (g < 262144) {
        float4 v = *(const float4*)&pw[(size_t)(g - 196608) * 4];
        *(ushort4*)&Wp[(size_t)(g - 196608) * 4] =
            make_ushort4(f2bf(v.x), f2bf(v.y), f2bf(v.z), f2bf(v.w));
    } else {
        int gg = g - 262144;
        if (gg < 4608) { int c = gg & 511, tap = gg >> 9; wT[gg] = dwcw[c * 9 + tap]; }
    }
}

// ============ MFMA GEMM, 128x128 tile / BK=64 / 4 waves / 64 KiB LDS ============
// RATIONALE (round 7): 64 KiB LDS -> TWO co-resident blocks per CU. Independent
// barrier groups overlap: one block's vmcnt/sync drain hides under the other's
// MFMA (m114 mechanism). Same source-swizzled DMA staging + XCD swizzle as the
// proven 256x256 kernel; accumulation order identical -> bit-identical output.
// Staging: call c covers rows c*32+(t>>3), granule t&7; src granule ^= (row&7).
// LDS[row][g] = G[row][g ^ (row&7)] (16B granules, [128][64] ushort layout).
template <typename TO>
__global__ __launch_bounds__(256, 2)
void gemm128(const ushortT* __restrict__ A, const ushortT* __restrict__ Bw,
             const float* __restrict__ bias, TO* __restrict__ out,
             int N, int nbn) {
    __shared__ __align__(16) ushortT As[2][8192];   // [buf][128 rows][64 k]
    __shared__ __align__(16) ushortT Bs[2][8192];
    const int t = threadIdx.x, lane = t & 63, wid = t >> 6;
    // XCD-chunked swizzle (gridDim.x % 8 == 0 at both call sites)
    const int chunk = (int)gridDim.x >> 3;
    const int id2 = ((int)blockIdx.x & 7) * chunk + ((int)blockIdx.x >> 3);
    const int by = id2 / nbn, bx = id2 - by * nbn;
    const int m0 = by * 128, n0 = bx * 128;
    const int wm = wid >> 1, wn = wid & 1;

    const int srow = t >> 3;                      // call-local row (0..31), +32c
    const int skg = (t & 7) ^ (srow & 7);         // (row&7)==(srow&7) for all calls
    const ushortT* gA = A + (size_t)(m0 + srow) * 512 + skg * 8;
    const ushortT* gB = Bw + (size_t)(n0 + srow) * 512 + skg * 8;
    const int dst = wid * 512;                    // ushorts; +c*2048 per call

#define ISS(bufi, ko) { \
    gl_lds16(gA + (ko),             &As[bufi][dst]); \
    gl_lds16(gA + 16384 + (ko),     &As[bufi][2048 + dst]); \
    gl_lds16(gA + 32768 + (ko),     &As[bufi][4096 + dst]); \
    gl_lds16(gA + 49152 + (ko),     &As[bufi][6144 + dst]); \
    gl_lds16(gB + (ko),             &Bs[bufi][dst]); \
    gl_lds16(gB + 16384 + (ko),     &Bs[bufi][2048 + dst]); \
    gl_lds16(gB + 32768 + (ko),     &Bs[bufi][4096 + dst]); \
    gl_lds16(gB + 49152 + (ko),     &Bs[bufi][6144 + dst]); }

    f32x4 acc[4][4];
#pragma unroll
    for (int i = 0; i < 4; ++i)
#pragma unroll
        for (int j = 0; j < 4; ++j) acc[i][j] = fzero4();

    // frag reads: row = base + frag*16 + r15; (row&7)==(r15&7)
    const int r15 = lane & 15, kq16 = lane >> 4;
    const int rA = wm * 64 + r15;
    const int rB = wn * 64 + r15;
    const int sw0 = ((kq16) ^ (r15 & 7)) << 3;
    const int sw1 = ((4 + kq16) ^ (r15 & 7)) << 3;

    ISS(0, 0);
    VMCNT(0);
    BAR();

    bf16x8 af[4][2], bf[4][2];
    for (int kt = 0; kt < 8; ++kt) {
        const ushortT* Ac = As[kt & 1];
        const ushortT* Bc = Bs[kt & 1];
        if (kt < 7) { const int nb = (kt + 1) & 1; const int ko = (kt + 1) * 64; ISS(nb, ko); }
#pragma unroll
        for (int mt = 0; mt < 4; ++mt) {
            af[mt][0] = *(const bf16x8*)&Ac[(rA + mt * 16) * 64 + sw0];
            af[mt][1] = *(const bf16x8*)&Ac[(rA + mt * 16) * 64 + sw1];
        }
#pragma unroll
        for (int nt = 0; nt < 4; ++nt) {
            bf[nt][0] = *(const bf16x8*)&Bc[(rB + nt * 16) * 64 + sw0];
            bf[nt][1] = *(const bf16x8*)&Bc[(rB + nt * 16) * 64 + sw1];
        }
        __builtin_amdgcn_s_setprio(1);
#pragma unroll
        for (int mt = 0; mt < 4; ++mt)
#pragma unroll
            for (int nt = 0; nt < 4; ++nt) {
                acc[mt][nt] = MFMA16(af[mt][0], bf[nt][0], acc[mt][nt]);
                acc[mt][nt] = MFMA16(af[mt][1], bf[nt][1], acc[mt][nt]);
            }
        __builtin_amdgcn_s_setprio(0);
        __syncthreads();   // drains vmcnt (next tile landed in buf^1) + lgkm
    }
#undef ISS

    const int cn = r15, rg = kq16 << 2;
#pragma unroll
    for (int mt = 0; mt < 4; ++mt) {
        int mrow = m0 + wm * 64 + mt * 16 + rg;
#pragma unroll
        for (int nt = 0; nt < 4; ++nt) {
            int ncol = n0 + wn * 64 + nt * 16 + cn;
            float bv = bias ? bias[ncol] : 0.f;
#pragma unroll
            for (int r = 0; r < 4; ++r) {
                float v = acc[mt][nt][r] + bv;
                if (sizeof(TO) == 2) ((ushortT*)out)[(size_t)(mrow + r) * N + ncol] = f2bf(v);
                else                 ((float*)out)[(size_t)(mrow + r) * N + ncol] = v;
            }
        }
    }
}

// ============ agent tokens: 8x8 mean pool of q -> PRE-SCALED bf16 (x0.125) ======
__global__ __launch_bounds__(256)
void agent_pool(const ushortT* __restrict__ qkv, ushortT* __restrict__ at) {
    __shared__ float red[256][9];
    int t = threadIdx.x;
    int ba = blockIdx.x;                 // 784 = 16*49
    int b = ba / AG, a = ba % AG;
    int c8 = (t & 63) << 3, qr = t >> 6;
    int p1 = a / 7, p2 = a % 7;
    float s[8] = {};
#pragma unroll
    for (int pp = 0; pp < 16; ++pp) {
        int pos = (qr << 4) + pp;
        int i = (p1 * 8 + (pos >> 3)) * 56 + p2 * 8 + (pos & 7);
        bf16x8 u = *(const bf16x8*)&qkv[(size_t)(b * Nn + i) * 1536 + c8];
#pragma unroll
        for (int j = 0; j < 8; ++j) s[j] += bf2f((ushortT)u[j]);
    }
#pragma unroll
    for (int j = 0; j < 8; ++j) red[t][j] = s[j];
    __syncthreads();
    if (t < 64) {
        ushortT* o = &at[((size_t)(b * AG + a) << 9) + (t << 3)];
#pragma unroll
        for (int j = 0; j < 8; ++j)
            o[j] = f2bf((red[t][j] + red[t + 64][j] + red[t + 128][j] + red[t + 192][j])
                        * (1.f / 512.f));
    }
}

// ============ bilinear 7->56 biases, bf16 out (b1 + b2 in one launch) ============
__device__ inline float bilin7(const float* __restrict__ p, int y, int x) {
    float fy = fminf(fmaxf(y * 0.125f - 0.4375f, 0.f), 6.f);
    float fx = fminf(fmaxf(x * 0.125f - 0.4375f, 0.f), 6.f);
    int y0 = (int)fy; float ty = fy - y0; int y1 = min(y0 + 1, 6);
    int x0 = (int)fx; float tx = fx - x0; int x1 = min(x0 + 1, 6);
    float v00 = p[y0 * 7 + x0], v01 = p[y0 * 7 + x1];
    float v10 = p[y1 * 7 + x0], v11 = p[y1 * 7 + x1];
    return (1.f - ty) * ((1.f - tx) * v00 + tx * v01) + ty * ((1.f - tx) * v10 + tx * v11);
}

__global__ void bias_k(const float* __restrict__ an, const float* __restrict__ ahb,
                       const float* __restrict__ awb, const float* __restrict__ na,
                       const float* __restrict__ hab, const float* __restrict__ wab,
                       ushortT* __restrict__ b1, ushortT* __restrict__ b2) {
    int g = blockIdx.x * 256 + threadIdx.x;
    const int NT = HEADS * AG * Nn;
    if (g < NT) {                         // b1 [h][a][i]
        int i = g % Nn; int a = (g / Nn) % AG; int h = g / (AG * Nn);
        int y = i / 56, x = i % 56;
        b1[g] = f2bf(bilin7(an + (h * AG + a) * 49, y, x)
                     + ahb[(h * AG + a) * 56 + y] + awb[(h * AG + a) * 56 + x]);
    } else {
        g -= NT; if (g >= NT) return;     // b2 [h][i][a]
        int a = g % AG; int i = (g / AG) % Nn; int h = g / (AG * Nn);
        int y = i / 56, x = i % 56;
        b2[g] = f2bf(bilin7(na + (h * AG + a) * 49, y, x)
                     + hab[(h * 56 + y) * AG + a] + wab[(h * 56 + x) * AG + a]);
    }
}

// ============ FUSED agent attention, ATOMIC-FREE partials (round-6, unchanged) ======
__global__ __launch_bounds__(256)
void agent_av_fused(const ushortT* __restrict__ qkv, const ushortT* __restrict__ at,
                    const ushortT* __restrict__ b1, float* __restrict__ num_p,
                    float* __restrict__ den_p) {
    __shared__ __align__(16) ushortT ah_s[64 * 72];
    __shared__ __align__(16) ushortT vt[64 * 72];    // vT[d][i] for current chunk
    __shared__ __align__(16) ushortT p_s[64 * 72];   // P[a][i] bf16 for current chunk
    const int t = threadIdx.x, lane = t & 63, wid = t >> 6;
    const int bx = blockIdx.x, bh = blockIdx.y, b = bh >> 3, h = bh & 7;
    const int cs = bx ? (13 + 12 * (bx - 1)) : 0;
    const int ce = cs + (bx ? 12 : 13);
    for (int idx = t; idx < 512; idx += 256) {
        int a = idx >> 3, d8 = (idx & 7) << 3;
        bf16x8 tmp;
        if (a < AG) {
            tmp = *(const bf16x8*)&at[((size_t)(b * AG + a) << 9) + (h << 6) + d8];
        } else {
#pragma unroll
            for (int j = 0; j < 8; ++j) tmp[j] = 0;
        }
        *(bf16x8*)&ah_s[a * 72 + d8] = tmp;
    }
    __syncthreads();
    const int r15 = lane & 15, kq = (lane >> 4) << 3;
    const int rbase = (lane >> 4) << 2;
    bf16x8 af[4][2];
#pragma unroll
    for (int mt = 0; mt < 4; ++mt)
#pragma unroll
        for (int ks = 0; ks < 2; ++ks)
            af[mt][ks] = *(const bf16x8*)&ah_s[(mt * 16 + r15) * 72 + ks * 32 + kq];

    f32x4 accn[4];
#pragma unroll
    for (int nt = 0; nt < 4; ++nt) accn[nt] = fzero4();
    float denl[4][4];
#pragma unroll
    for (int mt = 0; mt < 4; ++mt)
#pragma unroll
        for (int r = 0; r < 4; ++r) denl[mt][r] = 0.f;

    const int svi = t >> 2, svd = (t & 3) << 4;
    for (int cc = cs; cc < ce; ++cc) {
        const int i0 = cc * 64;
        {
            const ushortT* vp = &qkv[(size_t)(b * Nn + i0 + svi) * 1536 + 1024 + (h << 6) + svd];
            bf16x8 u0 = *(const bf16x8*)vp;
            bf16x8 u1 = *(const bf16x8*)(vp + 8);
#pragma unroll
            for (int j = 0; j < 8; ++j) {
                vt[(svd + j) * 72 + svi]     = (ushortT)u0[j];
                vt[(svd + 8 + j) * 72 + svi] = (ushortT)u1[j];
            }
        }
        {
            const int iw = i0 + wid * 16;
            const ushortT* kp = &qkv[(size_t)(b * Nn + iw + r15) * 1536 + 512 + (h << 6) + kq];
            bf16x8 bk0 = *(const bf16x8*)kp;
            bf16x8 bk1 = *(const bf16x8*)(kp + 32);
            f32x4 sacc[4];
#pragma unroll
            for (int mt = 0; mt < 4; ++mt) {
                sacc[mt] = MFMA16(af[mt][0], bk0, fzero4());
                sacc[mt] = MFMA16(af[mt][1], bk1, sacc[mt]);
            }
            const int ic = iw + r15;
#pragma unroll
            for (int mt = 0; mt < 4; ++mt)
#pragma unroll
                for (int r = 0; r < 4; ++r) {
                    int a = mt * 16 + rbase + r;
                    float e = 0.f;
                    if (a < AG)
                        e = __expf(sacc[mt][r] + bf2f(b1[(size_t)(h * AG + a) * Nn + ic]));
                    denl[mt][r] += e;
                    p_s[a * 72 + wid * 16 + r15] = f2bf(e);
                }
        }
        __syncthreads();
        {
            bf16x8 ap0 = *(const bf16x8*)&p_s[(wid * 16 + r15) * 72 + kq];
            bf16x8 ap1 = *(const bf16x8*)&p_s[(wid * 16 + r15) * 72 + 32 + kq];
#pragma unroll
            for (int nt = 0; nt < 4; ++nt) {
                bf16x8 bv0 = *(const bf16x8*)&vt[(nt * 16 + r15) * 72 + kq];
                bf16x8 bv1 = *(const bf16x8*)&vt[(nt * 16 + r15) * 72 + 32 + kq];
                accn[nt] = MFMA16(ap0, bv0, accn[nt]);
                accn[nt] = MFMA16(ap1, bv1, accn[nt]);
            }
        }
        __syncthreads();
    }
#pragma unroll
    for (int r = 0; r < 4; ++r) {
        int a = wid * 16 + rbase + r;
        if (a < AG) {
#pragma unroll
            for (int nt = 0; nt < 4; ++nt)
                num_p[(((size_t)bx * 128 + bh) * AG + a) * 64 + nt * 16 + r15] =
                    accn[nt][r];
        }
    }
    float* dsc = (float*)vt;   // safe: all vt reads drained by the loop's last barrier
#pragma unroll
    for (int mt = 0; mt < 4; ++mt)
#pragma unroll
        for (int r = 0; r < 4; ++r) {
            float s = denl[mt][r];
#pragma unroll
            for (int off = 8; off >= 1; off >>= 1) s += __shfl_xor(s, off);
            if (r15 == 0) dsc[wid * 64 + mt * 16 + rbase + r] = s;
        }
    __syncthreads();
    if (t < 64)
        den_p[((size_t)bx * 128 + bh) * 64 + t] =
            dsc[t] + dsc[64 + t] + dsc[128 + t] + dsc[192 + t];
}

// ============ fused q-attention: QK^T -> reg softmax (no max) -> P·av ============
__global__ __launch_bounds__(256)
void q_attn_mfma(const ushortT* __restrict__ qkv, const ushortT* __restrict__ at,
                 const float* __restrict__ num_p, const float* __restrict__ den_p,
                 const ushortT* __restrict__ b2, ushortT* __restrict__ attn) {
    __shared__ __align__(16) ushortT ah_s[64 * 72];
    __shared__ __align__(16) ushortT avT[64 * 72];
    __shared__ __align__(16) ushortT p_s[4][16 * 72];
    __shared__ float den_s[64];
    int t = threadIdx.x, lane = t & 63, wid = t >> 6;
    int bh = blockIdx.y, b = bh >> 3, h = bh & 7;
    for (int idx = t; idx < 512; idx += 256) {
        int a = idx >> 3, d8 = (idx & 7) << 3;
        bf16x8 tmp;
        if (a < AG) {
            tmp = *(const bf16x8*)&at[((size_t)(b * AG + a) << 9) + (h << 6) + d8];
        } else {
#pragma unroll
            for (int j = 0; j < 8; ++j) tmp[j] = 0;
        }
        *(bf16x8*)&ah_s[a * 72 + d8] = tmp;
    }
    if (t < 64) {
        den_s[t] = den_p[((size_t)0 * 128 + bh) * 64 + t]
                 + den_p[((size_t)1 * 128 + bh) * 64 + t]
                 + den_p[((size_t)2 * 128 + bh) * 64 + t]
                 + den_p[((size_t)3 * 128 + bh) * 64 + t];
    }
    __syncthreads();
    for (int idx = t; idx < 4096; idx += 256) {     // avT[d][a] <- (sum num_p)/den
        int a = idx >> 6, d = idx & 63;
        float v = 0.f;
        if (a < AG) {
            float s = num_p[(((size_t)0 * 128 + bh) * AG + a) * 64 + d]
                    + num_p[(((size_t)1 * 128 + bh) * AG + a) * 64 + d]
                    + num_p[(((size_t)2 * 128 + bh) * AG + a) * 64 + d]
                    + num_p[(((size_t)3 * 128 + bh) * AG + a) * 64 + d];
            v = s / den_s[a];
        }
        avT[d * 72 + a] = f2bf(v);
    }
    __syncthreads();
    int r15 = lane & 15, kq = (lane >> 4) << 3;
    bf16x8 bah[4][2], bav[4][2];
#pragma unroll
    for (int nt = 0; nt < 4; ++nt)
#pragma unroll
        for (int ks = 0; ks < 2; ++ks) {
            bah[nt][ks] = *(const bf16x8*)&ah_s[(nt * 16 + r15) * 72 + ks * 32 + kq];
            bav[nt][ks] = *(const bf16x8*)&avT[(nt * 16 + r15) * 72 + ks * 32 + kq];
        }
    ushortT* psw = p_s[wid];
    int i0b = blockIdx.x * 448;
    int rbase = (lane >> 4) << 2;
    for (int tt = 0; tt < 7; ++tt) {
        int i0 = i0b + (wid * 7 + tt) * 16;
        const ushortT* qp = &qkv[(size_t)(b * Nn + i0 + r15) * 1536 + (h << 6) + kq];
        bf16x8 aq0 = *(const bf16x8*)qp;
        bf16x8 aq1 = *(const bf16x8*)(qp + 32);
        f32x4 lg[4];
#pragma unroll
        for (int nt = 0; nt < 4; ++nt) {
            lg[nt] = MFMA16(aq0, bah[nt][0], fzero4());
            lg[nt] = MFMA16(aq1, bah[nt][1], lg[nt]);
        }
        float p4[4][4];   // [nt][r]
#pragma unroll
        for (int r = 0; r < 4; ++r) {
            int i = i0 + rbase + r;
            float vals[4]; float sm = 0.f;
#pragma unroll
            for (int nt = 0; nt < 4; ++nt) {
                int a = nt * 16 + r15;
                float e = 0.f;
                if (a < AG)
                    e = __expf(lg[nt][r] + bf2f(b2[(size_t)(h * Nn + i) * AG + a]));
                vals[nt] = e; sm += e;
            }
#pragma unroll
            for (int off = 8; off >= 1; off >>= 1) sm += __shfl_xor(sm, off);
            float inv = 1.f / sm;
#pragma unroll
            for (int nt = 0; nt < 4; ++nt) p4[nt][r] = vals[nt] * inv;
        }
#pragma unroll
        for (int nt = 0; nt < 4; ++nt)
#pragma unroll
            for (int r = 0; r < 4; ++r)
                psw[(rbase + r) * 72 + nt * 16 + r15] = f2bf(p4[nt][r]);
        bf16x8 ap0 = *(const bf16x8*)&psw[r15 * 72 + kq];
        bf16x8 ap1 = *(const bf16x8*)&psw[r15 * 72 + 32 + kq];
        f32x4 ov[4];
#pragma unroll
        for (int nt = 0; nt < 4; ++nt) {
            ov[nt] = MFMA16(ap0, bav[nt][0], fzero4());
            ov[nt] = MFMA16(ap1, bav[nt][1], ov[nt]);
        }
#pragma unroll
        for (int r = 0; r < 4; ++r) {
            int i = i0 + rbase + r;
            ushortT* op = &attn[(size_t)(b * Nn + i) * C_ + (h << 6)];
#pragma unroll
            for (int nt = 0; nt < 4; ++nt)
                op[nt * 16 + r15] = f2bf(ov[nt][r]);
        }
    }
}

// ============ depthwise 3x3 conv on v, added into attn; 8 channels/thread ============
__global__ void dwc_add_v(const ushortT* __restrict__ qkv, const float* __restrict__ wT,
                          const float* __restrict__ bb, ushortT* __restrict__ attn) {
    int g = blockIdx.x * 256 + threadIdx.x;   // B*Nn*64
    int c8 = (g & 63) << 3;
    int bi = g >> 6;
    int i = bi % Nn;
    int y = i / 56, x = i % 56;
    float acc[8];
    {
        float4 b0 = *(const float4*)&bb[c8];
        float4 b1 = *(const float4*)&bb[c8 + 4];
        acc[0] = b0.x; acc[1] = b0.y; acc[2] = b0.z; acc[3] = b0.w;
        acc[4] = b1.x; acc[5] = b1.y; acc[6] = b1.z; acc[7] = b1.w;
    }
#pragma unroll
    for (int dy = -1; dy <= 1; ++dy) {
        int yy = y + dy; if (yy < 0 || yy > 55) continue;
#pragma unroll
        for (int dx = -1; dx <= 1; ++dx) {
            int xx = x + dx; if (xx < 0 || xx > 55) continue;
            const ushortT* vp = &qkv[(size_t)(bi + dy * 56 + dx) * 1536 + 1024 + c8];
            ushort4 u0 = *(const ushort4*)vp;
            ushort4 u1 = *(const ushort4*)(vp + 4);
            const float* wp = &wT[((dy + 1) * 3 + dx + 1) * 512 + c8];
            float4 w0 = *(const float4*)wp;
            float4 w1 = *(const float4*)(wp + 4);
            acc[0] += bf2f(u0.x) * w0.x; acc[1] += bf2f(u0.y) * w0.y;
            acc[2] += bf2f(u0.z) * w0.z; acc[3] += bf2f(u0.w) * w0.w;
            acc[4] += bf2f(u1.x) * w1.x; acc[5] += bf2f(u1.y) * w1.y;
            acc[6] += bf2f(u1.z) * w1.z; acc[7] += bf2f(u1.w) * w1.w;
        }
    }
    ushortT* op = &attn[(size_t)bi * C_ + c8];
    ushort4 a0 = *(const ushort4*)op;
    ushort4 a1 = *(const ushort4*)(op + 4);
    ushort4 o0 = make_ushort4(f2bf(bf2f(a0.x) + acc[0]), f2bf(bf2f(a0.y) + acc[1]),
                              f2bf(bf2f(a0.z) + acc[2]), f2bf(bf2f(a0.w) + acc[3]));
    ushort4 o1 = make_ushort4(f2bf(bf2f(a1.x) + acc[4]), f2bf(bf2f(a1.y) + acc[5]),
                              f2bf(bf2f(a1.z) + acc[6]), f2bf(bf2f(a1.w) + acc[7]));
    *(ushort4*)op = o0; *(ushort4*)(op + 4) = o1;
}

extern "C" void kernel_launch(void* const* d_in, const int* in_sizes, int n_in,
                              void* d_out, int out_size, void* d_ws, size_t ws_size,
                              hipStream_t stream) {
    const float* x      = (const float*)d_in[0];
    const float* q_w    = (const float*)d_in[3];
    const float* kv_w   = (const float*)d_in[4];
    const float* proj_w = (const float*)d_in[5];
    const float* proj_b = (const float*)d_in[6];
    const float* dwc_w  = (const float*)d_in[7];
    const float* dwc_b  = (const float*)d_in[8];
    const float* an_b   = (const float*)d_in[9];
    const float* na_b   = (const float*)d_in[10];
    const float* ah_b   = (const float*)d_in[11];
    const float* aw_b   = (const float*)d_in[12];
    const float* ha_b   = (const float*)d_in[13];
    const float* wa_b   = (const float*)d_in[14];
    float* out = (float*)d_out;

    // ---- workspace layout (219,910,144 B used); R region reused: xb -> attn ----
    char* ws = (char*)d_ws;
    ushortT* R     = (ushortT*)(ws);                 // 51,380,224 B
    ushortT* qkv   = (ushortT*)(ws + 51380224);      // 154,140,672 B
    ushortT* Wqkv  = (ushortT*)(ws + 205520896);     // 1,572,864 B
    ushortT* Wp    = (ushortT*)(ws + 207093760);     // 524,288 B
    float*   wT    = (float*)(ws + 207618048);       // 18,432 B
    ushortT* at    = (ushortT*)(ws + 207636480);     // 802,816 B (bf16, pre-scaled)
    ushortT* b1    = (ushortT*)(ws + 208439296);     // 2,458,624 B (bf16)
    ushortT* b2    = (ushortT*)(ws + 210897920);     // 2,458,624 B (bf16)
    float*   num_p = (float*)(ws + 213356544);       // 6,422,528 B  [4][128][49][64]
    float*   den_p = (float*)(ws + 219779072);       // 131,072 B    [4][128][64]
    ushortT* xb    = R;           // 50176x512 bf16 (dead after QKV GEMM)
    ushortT* attn  = R;           // 50176x512 bf16

    // 0) dtype conversions / repacks
    cvt_f2b4<<<25088, 256, 0, stream>>>(x, xb, 6422528);
    cvt_weights<<<1042, 256, 0, stream>>>(q_w, kv_w, proj_w, dwc_w, Wqkv, Wp, wT);
    // 1) QKV GEMM (128x128, 2 blocks/CU)  M=50176 N=1536 K=512; grid 392x12
    gemm128<ushortT><<<4704, 256, 0, stream>>>(xb, Wqkv, nullptr, qkv, 1536, 12);
    // 2) agent tokens (pre-scaled bf16)
    agent_pool<<<784, 256, 0, stream>>>(qkv, at);
    // 3) position biases (bf16, one launch)
    bias_k<<<9604, 256, 0, stream>>>(an_b, ah_b, aw_b, na_b, ha_b, wa_b, b1, b2);
    // 4) fused agent attention — atomic-free partials
    agent_av_fused<<<dim3(4, 128), 256, 0, stream>>>(qkv, at, b1, num_p, den_p);
    // 5) q attention (sums the 4 partials during staging)
    q_attn_mfma<<<dim3(7, 128), 256, 0, stream>>>(qkv, at, num_p, den_p, b2, attn);
    // 6) depthwise conv add
    dwc_add_v<<<12544, 256, 0, stream>>>(qkv, wT, dwc_b, attn);
    // 7) output projection (128x128)  M=50176 N=512 K=512; grid 392x4
    gemm128<float><<<1568, 256, 0, stream>>>(attn, Wp, proj_b, out, 512, 4);
}